// Round 17
// baseline (581.752 us; speedup 1.0000x reference)
//
#include <hip/hip_runtime.h>

#define HW 16384   // 128*128
#define CDIM 192

typedef short bf16x8 __attribute__((ext_vector_type(8)));
typedef short short8 __attribute__((ext_vector_type(8)));
typedef short short4_t __attribute__((ext_vector_type(4)));
typedef float f32x4  __attribute__((ext_vector_type(4)));

__device__ inline void gload_lds16(const void* g, void* l) {
  __builtin_amdgcn_global_load_lds(
      (const __attribute__((address_space(1))) void*)g,
      (__attribute__((address_space(3))) void*)l, 16, 0, 0);
}

__device__ inline short to_bf16_rne(float f) {
  unsigned u = __float_as_uint(f);
  unsigned r = u + 0x7fffu + ((u >> 16) & 1u);
  return (short)(r >> 16);
}

__device__ inline float b2f(short s) {
  return __uint_as_float(((unsigned)(unsigned short)s) << 16);
}

__device__ inline void split_bf16(float a, short& hi, short& lo) {
  unsigned u = __float_as_uint(a);
  hi = (short)(u >> 16);                       // truncated high part
  float res = a - __uint_as_float(u & 0xffff0000u);
  lo = (short)(__float_as_uint(res) >> 16);    // residual; pair accurate to ~2^-17
}

// ---------------------------------------------------------------------------
__global__ __launch_bounds__(256) void k_zero(float* __restrict__ p, int n) {
  int i = blockIdx.x * 256 + threadIdx.x;
  if (i < n) p[i] = 0.f;
}

// ---------------------------------------------------------------------------
__global__ __launch_bounds__(256) void k_split_w(
    const float* __restrict__ W, short* __restrict__ hi,
    short* __restrict__ lo, int n)
{
  int i = blockIdx.x * 256 + threadIdx.x;
  if (i < n) { short h, l; split_bf16(W[i], h, l); hi[i] = h; lo[i] = l; }
}

// ---------------------------------------------------------------------------
// Staging macros for k_cmm
// ---------------------------------------------------------------------------
#define CMM_LOADB(bv, k0)                                                     \
  { _Pragma("unroll")                                                         \
    for (int kk = 0; kk < 2; ++kk) {                                          \
      const int kcg = kg0 + kk * 2;                                           \
      _Pragma("unroll")                                                       \
      for (int j = 0; j < 8; ++j)                                             \
        bv[kk][j] = xf[(size_t)((k0) + kcg * 8 + j) * HW + n0 + px];          \
    } }

#define CMM_STAGEA(k0, b)                                                     \
  { _Pragma("unroll")                                                         \
    for (int ii = 0; ii < 6; ++ii) {                                          \
      const int id = w * 6 + ii, arr = id / 12, mf = id % 12;                 \
      const short* Wp = arr ? Wlo : Whi;                                      \
      const short* g = Wp + (size_t)(m0 + mf * 16 + lr) * CDIM + (k0) + lq * 8; \
      gload_lds16(g, (arr ? Al[b] : Ah[b]) + mf * 512);                       \
    } }

// Single rne-bf16 B write (X-lo term dropped)
#define CMM_WRITEB1(bv, b)                                                    \
  { _Pragma("unroll")                                                         \
    for (int kk = 0; kk < 2; ++kk) {                                          \
      const int kcg = kg0 + kk * 2;                                           \
      short8 s8;                                                              \
      _Pragma("unroll")                                                       \
      for (int j = 0; j < 8; ++j) s8[j] = to_bf16_rne(bv[kk][j]);             \
      *(short8*)&Bh[b][(kcg * 128 + px) * 8] = s8;                            \
    } }

// A+B staging for the proj path (all gload_lds, both operands)
#define CMM_STAGE_PROJ(k0, b)                                                 \
  { _Pragma("unroll")                                                         \
    for (int ii = 0; ii < 6; ++ii) {                                          \
      const int id = w * 6 + ii, arr = id / 12, mf = id % 12;                 \
      const short* Wp = arr ? Wlo : Whi;                                      \
      const short* g = Wp + (size_t)(m0 + mf * 16 + lr) * CDIM + (k0) + lq * 8; \
      gload_lds16(g, (arr ? Al[b] : Ah[b]) + mf * 512);                       \
    }                                                                         \
    _Pragma("unroll")                                                         \
    for (int ii = 0; ii < 4; ++ii) {                                          \
      const int id = w * 4 + ii, arr = id >> 3, sub = id & 7;                 \
      const int kc = sub >> 1, half = sub & 1;                                \
      const short* src = arr ? xl : xh;                                       \
      const short* g = src + ((size_t)((k0) / 8 + kc) * HW + n0 + half * 64 + lane) * 8; \
      gload_lds16(g, (arr ? Bl[b] : Bh[b]) + (kc * 128 + half * 64) * 8);     \
    } }

// ---------------------------------------------------------------------------
// MFMA 1x1-conv GEMM.  (unchanged from round 16: the measured optimum)
// ---------------------------------------------------------------------------
template <bool SPLITX>
__global__ __launch_bounds__(256) void k_cmm(
    const float* __restrict__ Xf,
    const short* __restrict__ Xhi, const short* __restrict__ Xlo,
    const short* __restrict__ Whi, const short* __restrict__ Wlo,
    const float* __restrict__ bias, void* __restrict__ Outv, int Mtot)
{
  __shared__ short Ah[2][6144], Al[2][6144], Bh[2][4096], Bl[2][4096];
  const int t = threadIdx.x, lane = t & 63, w = t >> 6;
  const int lr = lane & 15, lq = lane >> 4;

  int bb, m0, n0;
  if constexpr (SPLITX) {
    const int flat = blockIdx.x;
    const int g = (flat & 7) * (gridDim.x >> 3) + (flat >> 3);
    bb = g / 384;
    const int rem = g % 384;
    m0 = (rem % 3) * 192;          // m fastest: trio shares X B-tile in L2
    n0 = (rem / 3) * 128;
  } else {
    bb = blockIdx.z; m0 = blockIdx.y * 192; n0 = blockIdx.x * 128;
  }

  const float* xf = nullptr;
  const short* xh = nullptr;
  const short* xl = nullptr;
  if constexpr (SPLITX) {
    xf = Xf + (size_t)bb * CDIM * HW;
  } else {
    xh = Xhi + (size_t)bb * 24 * HW * 8;
    xl = Xlo + (size_t)bb * 24 * HW * 8;
  }

  f32x4 acc[3][8] = {};

  if constexpr (SPLITX) {
    const int px = t & 127, kg0 = t >> 7;
    float bv[2][8];
    CMM_LOADB(bv, 0);
    CMM_STAGEA(0, 0);
    asm volatile("s_waitcnt vmcnt(6)" ::: "memory");   // B(0) regs ready
    __builtin_amdgcn_sched_barrier(0);
    CMM_WRITEB1(bv, 0);

    #pragma unroll
    for (int s = 0; s < 6; ++s) {
      const int cur = s & 1;
      asm volatile("s_waitcnt vmcnt(0) lgkmcnt(0)" ::: "memory");
      __builtin_amdgcn_s_barrier();
      __builtin_amdgcn_sched_barrier(0);

      if (s < 5) { CMM_LOADB(bv, (s + 1) << 5); }   // issue X loads first: max headroom
      bf16x8 ahf[3], alf[3];
      #pragma unroll
      for (int mi = 0; mi < 3; ++mi) {
        ahf[mi] = *(const bf16x8*)&Ah[cur][(w * 3 + mi) * 512 + lane * 8];
        alf[mi] = *(const bf16x8*)&Al[cur][(w * 3 + mi) * 512 + lane * 8];
      }
      if (s < 5) { CMM_STAGEA((s + 1) << 5, cur ^ 1); }
      __builtin_amdgcn_sched_barrier(0);

      __builtin_amdgcn_s_setprio(1);
      #pragma unroll
      for (int j = 0; j < 8; ++j) {
        bf16x8 bsf = *(const bf16x8*)&Bh[cur][(lq * 128 + j * 16 + lr) * 8];
        #pragma unroll
        for (int mi = 0; mi < 3; ++mi) {
          acc[mi][j] = __builtin_amdgcn_mfma_f32_16x16x32_bf16(ahf[mi], bsf, acc[mi][j], 0, 0, 0);
          acc[mi][j] = __builtin_amdgcn_mfma_f32_16x16x32_bf16(alf[mi], bsf, acc[mi][j], 0, 0, 0);
        }
      }
      __builtin_amdgcn_s_setprio(0);
      if (s < 5) {
        __builtin_amdgcn_sched_barrier(0);
        asm volatile("s_waitcnt vmcnt(6)" ::: "memory");  // B(s+1) regs landed; A(s+1) flying
        __builtin_amdgcn_sched_barrier(0);
        CMM_WRITEB1(bv, cur ^ 1);
      }
    }
  } else {
    CMM_STAGE_PROJ(0, 0);
    for (int s = 0; s < 6; ++s) {
      const int cur = s & 1;
      asm volatile("s_waitcnt vmcnt(0) lgkmcnt(0)" ::: "memory");
      __builtin_amdgcn_s_barrier();
      __builtin_amdgcn_sched_barrier(0);

      bf16x8 ahf[3], alf[3];
      #pragma unroll
      for (int mi = 0; mi < 3; ++mi) {
        ahf[mi] = *(const bf16x8*)&Ah[cur][(w * 3 + mi) * 512 + lane * 8];
        alf[mi] = *(const bf16x8*)&Al[cur][(w * 3 + mi) * 512 + lane * 8];
      }
      if (s < 5) {
        __builtin_amdgcn_sched_barrier(0);
        CMM_STAGE_PROJ((s + 1) << 5, cur ^ 1);   // 10 gload_lds fly under MFMA
        __builtin_amdgcn_sched_barrier(0);
      }
      __builtin_amdgcn_s_setprio(1);
      #pragma unroll
      for (int j = 0; j < 8; ++j) {
        bf16x8 bhf = *(const bf16x8*)&Bh[cur][(lq * 128 + j * 16 + lr) * 8];
        bf16x8 blf = *(const bf16x8*)&Bl[cur][(lq * 128 + j * 16 + lr) * 8];
        #pragma unroll
        for (int mi = 0; mi < 3; ++mi) {
          acc[mi][j] = __builtin_amdgcn_mfma_f32_16x16x32_bf16(ahf[mi], bhf, acc[mi][j], 0, 0, 0);
          acc[mi][j] = __builtin_amdgcn_mfma_f32_16x16x32_bf16(ahf[mi], blf, acc[mi][j], 0, 0, 0);
          acc[mi][j] = __builtin_amdgcn_mfma_f32_16x16x32_bf16(alf[mi], bhf, acc[mi][j], 0, 0, 0);
        }
      }
      __builtin_amdgcn_s_setprio(0);
    }
  }

  #pragma unroll
  for (int mi = 0; mi < 3; ++mi) {
    #pragma unroll
    for (int r = 0; r < 4; ++r) {
      const int m = m0 + (w * 3 + mi) * 16 + lq * 4 + r;
      const float bv2 = bias[m];
      const size_t rowo = ((size_t)bb * Mtot + m) * HW + n0;
      #pragma unroll
      for (int j = 0; j < 8; ++j) {
        const int n = j * 16 + lr;
        if constexpr (SPLITX) {
          ((short*)Outv)[rowo + n] = to_bf16_rne(acc[mi][j][r] + bv2);
        } else {
          ((float*)Outv)[rowo + n] = acc[mi][j][r] + bv2;
        }
      }
    }
  }
}

// ---------------------------------------------------------------------------
// Depthwise 3x3 + bias + to_heads + norm.  (unchanged from round 11)
// ---------------------------------------------------------------------------
__global__ __launch_bounds__(256) void k_dw(
    const short* __restrict__ tmp,
    const float* __restrict__ dww, const float* __restrict__ dwb,
    short* __restrict__ Qb, short* __restrict__ Kb,
    short* __restrict__ Vt, int b0)
{
  __shared__ short img[16384];        // 128x128 bf16 = 32KB
  __shared__ short dwout[16 * 1040];  // padded rows: bank-conflict-free
  __shared__ float sums[16][64];
  __shared__ float rednorm[16];

  const int gc = blockIdx.x, lb = blockIdx.y, b = b0 + lb;
  const int sel = gc / CDIM, chl = gc % CDIM;
  const int head = chl / 48, c = chl % 48;
  const short* gimg = tmp + ((size_t)lb * 576 + gc) * HW;
  const int t = threadIdx.x;

  #pragma unroll
  for (int cch = 0; cch < 8; ++cch)
    gload_lds16(gimg + cch * 2048 + t * 8, img + cch * 2048 + t * 8);

  float wgt[9];
  #pragma unroll
  for (int i = 0; i < 9; ++i) wgt[i] = dww[gc * 9 + i];
  const float bias = dwb[gc];

  asm volatile("s_waitcnt vmcnt(0)" ::: "memory");
  __syncthreads();

  const int fy = (t >> 4) & 3;
  float sqp[4] = {0.f, 0.f, 0.f, 0.f};

  for (int i = 0; i < 8; ++i) {
    const int p8 = i * 2048 + t * 8;
    const int h = p8 >> 7, w0 = p8 & 127;
    float win[3][10];
    #pragma unroll
    for (int dy = 0; dy < 3; ++dy) {
      const int r = h + dy - 1;
      if (r < 0 || r > 127) {
        #pragma unroll
        for (int q = 0; q < 10; ++q) win[dy][q] = 0.f;
      } else {
        const short* rp = img + r * 128 + w0;
        short8 c8 = *(const short8*)rp;
        win[dy][0] = (w0 > 0) ? b2f(rp[-1]) : 0.f;
        #pragma unroll
        for (int q = 0; q < 8; ++q) win[dy][1 + q] = b2f(c8[q]);
        win[dy][9] = (w0 < 120) ? b2f(rp[8]) : 0.f;
      }
    }
    const int na = (h >> 2) * 32 + (w0 >> 2);
    #pragma unroll
    for (int fx = 0; fx < 4; ++fx) {
      float a0 = bias, a1 = bias;
      #pragma unroll
      for (int dy = 0; dy < 3; ++dy)
        #pragma unroll
        for (int dx = 0; dx < 3; ++dx) {
          a0 = fmaf(win[dy][fx + dx], wgt[dy * 3 + dx], a0);
          a1 = fmaf(win[dy][4 + fx + dx], wgt[dy * 3 + dx], a1);
        }
      sqp[fx] = fmaf(a0, a0, sqp[fx]);
      sqp[fx] = fmaf(a1, a1, sqp[fx]);
      *(unsigned*)&dwout[(fx * 4 + fy) * 1040 + na] =
          ((unsigned)(unsigned short)to_bf16_rne(a1) << 16) |
          (unsigned short)to_bf16_rne(a0);
    }
  }

  if (sel < 2) {
    const int slot = (t & 15) | ((t >> 6) << 4);
    #pragma unroll
    for (int fx = 0; fx < 4; ++fx) sums[fx * 4 + fy][slot] = sqp[fx];
    __syncthreads();
    const int row = t >> 4, i16 = t & 15;
    float v = sums[row][i16] + sums[row][i16 + 16] + sums[row][i16 + 32] + sums[row][i16 + 48];
    __syncthreads();
    sums[row][i16] = v;
    __syncthreads();
    if (t < 16) {
      float s = 0.f;
      #pragma unroll
      for (int j = 0; j < 16; ++j) s += sums[t][j];
      rednorm[t] = fmaxf(sqrtf(s), 1e-12f);
    }
  } else {
    __syncthreads();
  }
  __syncthreads();

  if (sel == 2) {
    #pragma unroll
    for (int j = 0; j < 4; ++j) {
      const int n = t + j * 256;
      short8 v0, v1;
      #pragma unroll
      for (int rr = 0; rr < 8; ++rr) v0[rr] = dwout[rr * 1040 + n];
      #pragma unroll
      for (int rr = 0; rr < 8; ++rr) v1[rr] = dwout[(rr + 8) * 1040 + n];
      const size_t o = ((size_t)(b * 4 + head) * 1024 + n) * 768 + c * 16;
      *(short8*)&Vt[o] = v0;
      *(short8*)&Vt[o + 8] = v1;
    }
    return;
  }

  short* dst = (sel == 0) ? Qb : Kb;
  #pragma unroll
  for (int rr = 0; rr < 16; ++rr) {
    const float inv = 1.0f / rednorm[rr];
    const size_t rowoff = ((size_t)(b * 4 + head) * 768 + c * 16 + rr) * 1024;
    #pragma unroll
    for (int j = 0; j < 2; ++j) {
      const int n2 = j * 512 + t * 2;
      const unsigned pk = *(const unsigned*)&dwout[rr * 1040 + n2];
      const float v0 = b2f((short)(pk & 0xffffu)) * inv;
      const float v1 = b2f((short)(pk >> 16)) * inv;
      *(unsigned*)&dst[rowoff + n2] =
          ((unsigned)(unsigned short)to_bf16_rne(v1) << 16) | (unsigned short)to_bf16_rne(v0);
    }
  }
}

// ---------------------------------------------------------------------------
// E = exp(Q*K^T * temp).  192x256 tile, 512 threads (8 waves 2m x 4n).
// NEW: 2-buffer (2x28KB=56KB) single-barrier pipeline -> 2 blocks/CU
// (was 3x28KB=84KB -> 1 block/CU, 384 blocks = 1.5 sequential rounds with a
// half-idle tail).  Round-6-validated structure: top vmcnt(0)+barrier ->
// frag reads -> stage(s+1) into buf^1 -> lgkmcnt(0) -> MFMA.  Hazard: buf^1
// was last read at step s-1, and those ds_reads completed before MFMA(s-1)
// which precedes the top barrier of step s.
// ---------------------------------------------------------------------------
__global__ __launch_bounds__(512) void k_qk(
    const short* __restrict__ Qb, const short* __restrict__ Kbf,
    const float* __restrict__ temp,
    short* __restrict__ E, float* __restrict__ Sums)
{
  __shared__ short lds[2][14336];   // 2 x 28KB
  const int t = threadIdx.x, lane = t & 63, w = t >> 6;
  const int lr = lane & 15, lq = lane >> 4;

  const int flat = blockIdx.x;
  const int g = (flat & 7) * 48 + (flat >> 3);     // bijection on [0,384)
  const int bh = g / 12, tile = g % 12;
  const int m0 = (tile / 3) * 192, n0 = (tile % 3) * 256;
  const size_t base = (size_t)bh * 768 * 1024;

  f32x4 acc[6][4] = {};
  const int wm = (w >> 2) * 6, wn = (w & 3) * 4;

  const short* gsrc[4]; size_t goff[4]; int gdst[4]; bool gok[4];
  #pragma unroll
  for (int ii = 0; ii < 4; ++ii) {
    const int id = w * 4 + ii;                     // 0..31; 28..31 unused
    gok[ii] = (id < 28);
    const bool isq = (id < 12);
    gsrc[ii] = isq ? Qb : Kbf;
    const int row = isq ? (m0 + id * 16) : (n0 + (id - 12) * 16);
    goff[ii] = base + (size_t)(row + lr) * 1024 + lq * 8;
    gdst[ii] = (id < 28 ? id : 0) * 512;
  }
  #define QK_STAGE(buf, k0)                                                   \
    { _Pragma("unroll")                                                       \
      for (int ii = 0; ii < 4; ++ii)                                          \
        if (gok[ii]) gload_lds16(gsrc[ii] + goff[ii] + (k0), &lds[buf][gdst[ii]]); }

  QK_STAGE(0, 0);

  for (int step = 0; step < 32; ++step) {
    const int cur = step & 1;
    asm volatile("s_waitcnt vmcnt(0)" ::: "memory");
    __builtin_amdgcn_s_barrier();
    __builtin_amdgcn_sched_barrier(0);

    bf16x8 ah[6], bf_[4];
    #pragma unroll
    for (int i = 0; i < 6; ++i)
      ah[i] = *(const bf16x8*)&lds[cur][(wm + i) * 512 + lane * 8];
    #pragma unroll
    for (int j = 0; j < 4; ++j)
      bf_[j] = *(const bf16x8*)&lds[cur][(12 + wn + j) * 512 + lane * 8];

    if (step < 31) QK_STAGE(cur ^ 1, (step + 1) << 5);

    asm volatile("s_waitcnt lgkmcnt(0)" ::: "memory");
    __builtin_amdgcn_sched_barrier(0);
    __builtin_amdgcn_s_setprio(1);
    #pragma unroll
    for (int i = 0; i < 6; ++i)
      #pragma unroll
      for (int j = 0; j < 4; ++j)
        acc[i][j] = __builtin_amdgcn_mfma_f32_16x16x32_bf16(ah[i], bf_[j], acc[i][j], 0, 0, 0);
    __builtin_amdgcn_s_setprio(0);
    __builtin_amdgcn_sched_barrier(0);
  }
  #undef QK_STAGE

  const float tp = temp[bh & 3];
  float* Srow = Sums + bh * 768;
  short* Ep = E + (size_t)bh * 768 * 768;
  #pragma unroll
  for (int i = 0; i < 6; ++i) {
    #pragma unroll
    for (int r = 0; r < 4; ++r) {
      const int m = m0 + (w >> 2) * 96 + i * 16 + lq * 4 + r;
      short* erow = Ep + (size_t)m * 768 + n0 + (w & 3) * 64;
      float rs = 0.f;
      #pragma unroll
      for (int j = 0; j < 4; ++j) {
        const float e = expf(acc[i][j][r] * tp);
        rs += e;
        erow[j * 16 + lr] = to_bf16_rne(e);
      }
      rs += __shfl_xor(rs, 1);
      rs += __shfl_xor(rs, 2);
      rs += __shfl_xor(rs, 4);
      rs += __shfl_xor(rs, 8);
      if (lr == 0) atomicAdd(&Srow[m], rs);
    }
  }
}

// ---------------------------------------------------------------------------
// O = (E * V) / (sum+1).  256x256 tile, 512 threads.
// NEW: 2-buffer (2x32KB=64KB) single-barrier pipeline -> 2 blocks/CU
// (was 3x32KB=96KB -> 1 block/CU with a 1.5-round grid tail).
// Epilogue unchanged: stages a contiguous 64KB output chunk across both
// buffers, short8 coalesced stores.
// ---------------------------------------------------------------------------
__global__ __launch_bounds__(512) void k_av(
    const short* __restrict__ Ebf, const short* __restrict__ Vtb,
    const float* __restrict__ Sums,
    short* __restrict__ Phi, short* __restrict__ Plo)
{
  __shared__ short lds[2][16384];   // 2 x 32KB
  const int t = threadIdx.x, lane = t & 63, w = t >> 6;
  const int lr = lane & 15, lq = lane >> 4;

  const int flat = blockIdx.x;
  const int g = (flat & 7) * 48 + (flat >> 3);     // bijection on [0,384)
  const int bh = g / 12, tile = g % 12;
  const int m0 = (tile / 4) * 256, n0 = (tile % 4) * 256;
  const int head = bh & 3, b = bh >> 2;
  const short* Sp = Ebf + (size_t)bh * 768 * 768;
  const short* Vp = Vtb + (size_t)bh * 1024 * 768;

  f32x4 acc[8][4] = {};
  const int wm = (w >> 2) * 8, wn = (w & 3) * 4;

  const short* gsrc[4]; size_t goff[4]; int gdst[4];
  #pragma unroll
  for (int ii = 0; ii < 4; ++ii) {
    const int id = w * 4 + ii;                     // 0..31
    const int arr = id >> 4, s = id & 15;
    gsrc[ii] = arr ? Vp : Sp;
    const int row = (arr ? n0 : m0) + s * 16;
    goff[ii] = (size_t)(row + lr) * 768 + lq * 8;
    gdst[ii] = id * 512;
  }
  #define AV_STAGE(buf, k0)                                                   \
    { _Pragma("unroll")                                                       \
      for (int ii = 0; ii < 4; ++ii)                                          \
        gload_lds16(gsrc[ii] + goff[ii] + (k0), &lds[buf][gdst[ii]]); }

  AV_STAGE(0, 0);

  for (int step = 0; step < 24; ++step) {
    const int cur = step & 1;
    asm volatile("s_waitcnt vmcnt(0)" ::: "memory");
    __builtin_amdgcn_s_barrier();
    __builtin_amdgcn_sched_barrier(0);

    bf16x8 ea[8], vb[4];
    #pragma unroll
    for (int i = 0; i < 8; ++i)
      ea[i] = *(const bf16x8*)&lds[cur][(wm + i) * 512 + lane * 8];
    #pragma unroll
    for (int j = 0; j < 4; ++j)
      vb[j] = *(const bf16x8*)&lds[cur][(16 + wn + j) * 512 + lane * 8];

    if (step < 23) AV_STAGE(cur ^ 1, (step + 1) << 5);

    asm volatile("s_waitcnt lgkmcnt(0)" ::: "memory");
    __builtin_amdgcn_sched_barrier(0);
    __builtin_amdgcn_s_setprio(1);
    #pragma unroll
    for (int i = 0; i < 8; ++i)
      #pragma unroll
      for (int j = 0; j < 4; ++j)
        acc[i][j] = __builtin_amdgcn_mfma_f32_16x16x32_bf16(ea[i], vb[j], acc[i][j], 0, 0, 0);
    __builtin_amdgcn_s_setprio(0);
    __builtin_amdgcn_sched_barrier(0);
  }
  #undef AV_STAGE

  // ---- scale by 1/(sum+1) in-register ----
  const float* Srow = Sums + bh * 768;
  float invv[8][4];
  #pragma unroll
  for (int i = 0; i < 8; ++i)
    #pragma unroll
    for (int r = 0; r < 4; ++r) {
      const int d = m0 + (w >> 2) * 128 + i * 16 + lq * 4 + r;
      invv[i][r] = 1.0f / (Srow[d] + 1.0f);
    }
  #pragma unroll
  for (int i = 0; i < 8; ++i)
    #pragma unroll
    for (int j = 0; j < 4; ++j)
      #pragma unroll
      for (int r = 0; r < 4; ++r)
        acc[i][j][r] *= invv[i][r];

  // ---- LDS-staged coalesced epilogue: 4 passes of one 64KB chunk each ----
  short* stg = &lds[0][0];                         // 32768 shorts = 64KB
  const int kcp0 = head * 6 + (m0 >> 7);
  const int myc = w >> 2;

  #pragma unroll
  for (int a = 0; a < 2; ++a) {
    #pragma unroll
    for (int c = 0; c < 2; ++c) {
      __syncthreads();   // protect vs prior reads of stg
      if (myc == c) {
        #pragma unroll
        for (int j = 0; j < 4; ++j) {
          const int nl = (w & 3) * 64 + j * 16 + lr;
          #pragma unroll
          for (int r = 0; r < 4; ++r) {
            short8 s8;
            #pragma unroll
            for (int i = 0; i < 8; ++i) {
              const float v = acc[i][j][r];
              const unsigned u = __float_as_uint(v);
              if (a == 0) {
                s8[i] = (short)(u >> 16);
              } else {
                const float res = v - __uint_as_float(u & 0xffff0000u);
                s8[i] = (short)(__float_as_uint(res) >> 16);
              }
            }
            const int loff = (((nl >> 5) * 4 + r) * 128 + (nl & 31) * 4 + lq) * 8;
            *(short8*)&stg[loff] = s8;
          }
        }
      }
      __syncthreads();
      short* dst = (a ? Plo : Phi) +
                   ((size_t)(b * 24 + kcp0 + c) * HW + n0 * 16) * 8;
      #pragma unroll
      for (int it = 0; it < 8; ++it) {
        const int idx = it * 4096 + t * 8;
        *(short8*)&dst[idx] = *(const short8*)&stg[idx];
      }
    }
  }
}

// ---------------------------------------------------------------------------
extern "C" void kernel_launch(void* const* d_in, const int* in_sizes, int n_in,
                              void* d_out, int out_size, void* d_ws, size_t ws_size,
                              hipStream_t stream) {
  const float* x      = (const float*)d_in[0];
  const float* qkv_w  = (const float*)d_in[1];
  const float* qkv_b  = (const float*)d_in[2];
  const float* dw_w   = (const float*)d_in[3];
  const float* dw_b   = (const float*)d_in[4];
  const float* proj_w = (const float*)d_in[5];
  const float* proj_b = (const float*)d_in[6];
  const float* temp   = (const float*)d_in[7];
  float* out = (float*)d_out;

  float* F = (float*)d_ws;
  const size_t M25 = (size_t)8 * CDIM * HW;      // 25,165,824 elements
  short* Qb  = (short*)F;                         // [0, 50.3M)
  short* Plo = Qb + M25;                          // [50.3, 100.7M)
  short* Kb  = (short*)(F + M25);                 // [100.7, 151M)
  short* Vt  = Kb + M25;                          // [151, 201.3M)
  short* Ebf = (short*)(F + 2 * M25);             // [201.3, 239M)  (37.7MB)
  short* Phi = Qb;                                // alias Q (dead after qk)

  // tmpf (BF16) aliases the Ebf region onward: dead before k_qk writes E.
  short* tmpf = Ebf;
  const size_t ebfBytes  = (size_t)32 * 768 * 768 * 2;       // 37.75 MB
  const size_t baseBytes = 2 * M25 * 4;                      // 201.3 MB
  const size_t wsTailBytes = 294912 * 2 + 32 * 768 * 4 + 256; // weights+Sums
  int bpi = 2;
  for (int cand = 8; cand >= 2; cand >>= 1) {
    const size_t tmpfBytes = (size_t)cand * 576 * HW * 2;
    const size_t need = baseBytes + (tmpfBytes > ebfBytes ? tmpfBytes : ebfBytes)
                      + wsTailBytes;
    if (ws_size >= need) { bpi = cand; break; }
  }
  const size_t tmpfBytes = (size_t)bpi * 576 * HW * 2;
  short* WS = (short*)((char*)d_ws + baseBytes +
                       (tmpfBytes > ebfBytes ? tmpfBytes : ebfBytes));
  short* Wq_hi = WS;             // 576*192
  short* Wq_lo = WS + 110592;
  short* Wp_hi = WS + 221184;    // 192*192
  short* Wp_lo = WS + 258048;
  float* Sums  = (float*)(WS + 294912);           // 32*768 floats

  k_split_w<<<dim3(432), 256, 0, stream>>>(qkv_w, Wq_hi, Wq_lo, 110592);
  k_split_w<<<dim3(144), 256, 0, stream>>>(proj_w, Wp_hi, Wp_lo, 36864);
  k_zero<<<dim3(96), 256, 0, stream>>>(Sums, 32 * 768);

  for (int b0 = 0; b0 < 8; b0 += bpi) {
    k_cmm<true><<<dim3(384 * bpi), 256, 0, stream>>>(
        x + (size_t)b0 * CDIM * HW, nullptr, nullptr,
        Wq_hi, Wq_lo, qkv_b, tmpf, 576);
    k_dw<<<dim3(576, bpi), 256, 0, stream>>>(
        tmpf, dw_w, dw_b, Qb, Kb, Vt, b0);
  }

  k_qk<<<dim3(384), 512, 0, stream>>>(Qb, Kb, temp, Ebf, Sums);
  k_av<<<dim3(384), 512, 0, stream>>>(Ebf, Vt, Sums, Phi, Plo);
  k_cmm<false><<<dim3(128, 1, 8), 256, 0, stream>>>(
      nullptr, Phi, Plo, Wp_hi, Wp_lo, proj_b, out, 192);
}

// Round 18
// 556.275 us; speedup vs baseline: 1.0458x; 1.0458x over previous
//
#include <hip/hip_runtime.h>

#define HW 16384   // 128*128
#define CDIM 192

typedef short bf16x8 __attribute__((ext_vector_type(8)));
typedef short short8 __attribute__((ext_vector_type(8)));
typedef short short4_t __attribute__((ext_vector_type(4)));
typedef float f32x4  __attribute__((ext_vector_type(4)));

__device__ inline void gload_lds16(const void* g, void* l) {
  __builtin_amdgcn_global_load_lds(
      (const __attribute__((address_space(1))) void*)g,
      (__attribute__((address_space(3))) void*)l, 16, 0, 0);
}

__device__ inline short to_bf16_rne(float f) {
  unsigned u = __float_as_uint(f);
  unsigned r = u + 0x7fffu + ((u >> 16) & 1u);
  return (short)(r >> 16);
}

__device__ inline float b2f(short s) {
  return __uint_as_float(((unsigned)(unsigned short)s) << 16);
}

__device__ inline void split_bf16(float a, short& hi, short& lo) {
  unsigned u = __float_as_uint(a);
  hi = (short)(u >> 16);                       // truncated high part
  float res = a - __uint_as_float(u & 0xffff0000u);
  lo = (short)(__float_as_uint(res) >> 16);    // residual; pair accurate to ~2^-17
}

// ---------------------------------------------------------------------------
__global__ __launch_bounds__(256) void k_zero(float* __restrict__ p, int n) {
  int i = blockIdx.x * 256 + threadIdx.x;
  if (i < n) p[i] = 0.f;
}

// ---------------------------------------------------------------------------
__global__ __launch_bounds__(256) void k_split_w(
    const float* __restrict__ W, short* __restrict__ hi,
    short* __restrict__ lo, int n)
{
  int i = blockIdx.x * 256 + threadIdx.x;
  if (i < n) { short h, l; split_bf16(W[i], h, l); hi[i] = h; lo[i] = l; }
}

// ---------------------------------------------------------------------------
// Staging macros for k_cmm
// ---------------------------------------------------------------------------
#define CMM_LOADB(bv, k0)                                                     \
  { _Pragma("unroll")                                                         \
    for (int kk = 0; kk < 2; ++kk) {                                          \
      const int kcg = kg0 + kk * 2;                                           \
      _Pragma("unroll")                                                       \
      for (int j = 0; j < 8; ++j)                                             \
        bv[kk][j] = xf[(size_t)((k0) + kcg * 8 + j) * HW + n0 + px];          \
    } }

#define CMM_STAGEA(k0, b)                                                     \
  { _Pragma("unroll")                                                         \
    for (int ii = 0; ii < 6; ++ii) {                                          \
      const int id = w * 6 + ii, arr = id / 12, mf = id % 12;                 \
      const short* Wp = arr ? Wlo : Whi;                                      \
      const short* g = Wp + (size_t)(m0 + mf * 16 + lr) * CDIM + (k0) + lq * 8; \
      gload_lds16(g, (arr ? Al[b] : Ah[b]) + mf * 512);                       \
    } }

// Single rne-bf16 B write (X-lo term dropped)
#define CMM_WRITEB1(bv, b)                                                    \
  { _Pragma("unroll")                                                         \
    for (int kk = 0; kk < 2; ++kk) {                                          \
      const int kcg = kg0 + kk * 2;                                           \
      short8 s8;                                                              \
      _Pragma("unroll")                                                       \
      for (int j = 0; j < 8; ++j) s8[j] = to_bf16_rne(bv[kk][j]);             \
      *(short8*)&Bh[b][(kcg * 128 + px) * 8] = s8;                            \
    } }

// A+B staging for the proj path (all gload_lds, both operands)
#define CMM_STAGE_PROJ(k0, b)                                                 \
  { _Pragma("unroll")                                                         \
    for (int ii = 0; ii < 6; ++ii) {                                          \
      const int id = w * 6 + ii, arr = id / 12, mf = id % 12;                 \
      const short* Wp = arr ? Wlo : Whi;                                      \
      const short* g = Wp + (size_t)(m0 + mf * 16 + lr) * CDIM + (k0) + lq * 8; \
      gload_lds16(g, (arr ? Al[b] : Ah[b]) + mf * 512);                       \
    }                                                                         \
    _Pragma("unroll")                                                         \
    for (int ii = 0; ii < 4; ++ii) {                                          \
      const int id = w * 4 + ii, arr = id >> 3, sub = id & 7;                 \
      const int kc = sub >> 1, half = sub & 1;                                \
      const short* src = arr ? xl : xh;                                       \
      const short* g = src + ((size_t)((k0) / 8 + kc) * HW + n0 + half * 64 + lane) * 8; \
      gload_lds16(g, (arr ? Bl[b] : Bh[b]) + (kc * 128 + half * 64) * 8);     \
    } }

// ---------------------------------------------------------------------------
// MFMA 1x1-conv GEMM.  (round-16 measured optimum, unchanged)
// SPLITX=true: round-12 schedule + X single rne-bf16 (134us, VGPR 112,
//   conflicts 0, occ 20%).  SPLITX=false: 2-buffer pipelined proj.
// ---------------------------------------------------------------------------
template <bool SPLITX>
__global__ __launch_bounds__(256) void k_cmm(
    const float* __restrict__ Xf,
    const short* __restrict__ Xhi, const short* __restrict__ Xlo,
    const short* __restrict__ Whi, const short* __restrict__ Wlo,
    const float* __restrict__ bias, void* __restrict__ Outv, int Mtot)
{
  __shared__ short Ah[2][6144], Al[2][6144], Bh[2][4096], Bl[2][4096];
  const int t = threadIdx.x, lane = t & 63, w = t >> 6;
  const int lr = lane & 15, lq = lane >> 4;

  int bb, m0, n0;
  if constexpr (SPLITX) {
    const int flat = blockIdx.x;
    const int g = (flat & 7) * (gridDim.x >> 3) + (flat >> 3);
    bb = g / 384;
    const int rem = g % 384;
    m0 = (rem % 3) * 192;          // m fastest: trio shares X B-tile in L2
    n0 = (rem / 3) * 128;
  } else {
    bb = blockIdx.z; m0 = blockIdx.y * 192; n0 = blockIdx.x * 128;
  }

  const float* xf = nullptr;
  const short* xh = nullptr;
  const short* xl = nullptr;
  if constexpr (SPLITX) {
    xf = Xf + (size_t)bb * CDIM * HW;
  } else {
    xh = Xhi + (size_t)bb * 24 * HW * 8;
    xl = Xlo + (size_t)bb * 24 * HW * 8;
  }

  f32x4 acc[3][8] = {};

  if constexpr (SPLITX) {
    const int px = t & 127, kg0 = t >> 7;
    float bv[2][8];
    CMM_LOADB(bv, 0);
    CMM_STAGEA(0, 0);
    asm volatile("s_waitcnt vmcnt(6)" ::: "memory");   // B(0) regs ready
    __builtin_amdgcn_sched_barrier(0);
    CMM_WRITEB1(bv, 0);

    #pragma unroll
    for (int s = 0; s < 6; ++s) {
      const int cur = s & 1;
      asm volatile("s_waitcnt vmcnt(0) lgkmcnt(0)" ::: "memory");
      __builtin_amdgcn_s_barrier();
      __builtin_amdgcn_sched_barrier(0);

      if (s < 5) { CMM_LOADB(bv, (s + 1) << 5); }   // issue X loads first: max headroom
      bf16x8 ahf[3], alf[3];
      #pragma unroll
      for (int mi = 0; mi < 3; ++mi) {
        ahf[mi] = *(const bf16x8*)&Ah[cur][(w * 3 + mi) * 512 + lane * 8];
        alf[mi] = *(const bf16x8*)&Al[cur][(w * 3 + mi) * 512 + lane * 8];
      }
      if (s < 5) { CMM_STAGEA((s + 1) << 5, cur ^ 1); }
      __builtin_amdgcn_sched_barrier(0);

      __builtin_amdgcn_s_setprio(1);
      #pragma unroll
      for (int j = 0; j < 8; ++j) {
        bf16x8 bsf = *(const bf16x8*)&Bh[cur][(lq * 128 + j * 16 + lr) * 8];
        #pragma unroll
        for (int mi = 0; mi < 3; ++mi) {
          acc[mi][j] = __builtin_amdgcn_mfma_f32_16x16x32_bf16(ahf[mi], bsf, acc[mi][j], 0, 0, 0);
          acc[mi][j] = __builtin_amdgcn_mfma_f32_16x16x32_bf16(alf[mi], bsf, acc[mi][j], 0, 0, 0);
        }
      }
      __builtin_amdgcn_s_setprio(0);
      if (s < 5) {
        __builtin_amdgcn_sched_barrier(0);
        asm volatile("s_waitcnt vmcnt(6)" ::: "memory");  // B(s+1) regs landed; A(s+1) flying
        __builtin_amdgcn_sched_barrier(0);
        CMM_WRITEB1(bv, cur ^ 1);
      }
    }
  } else {
    CMM_STAGE_PROJ(0, 0);
    for (int s = 0; s < 6; ++s) {
      const int cur = s & 1;
      asm volatile("s_waitcnt vmcnt(0) lgkmcnt(0)" ::: "memory");
      __builtin_amdgcn_s_barrier();
      __builtin_amdgcn_sched_barrier(0);

      bf16x8 ahf[3], alf[3];
      #pragma unroll
      for (int mi = 0; mi < 3; ++mi) {
        ahf[mi] = *(const bf16x8*)&Ah[cur][(w * 3 + mi) * 512 + lane * 8];
        alf[mi] = *(const bf16x8*)&Al[cur][(w * 3 + mi) * 512 + lane * 8];
      }
      if (s < 5) {
        __builtin_amdgcn_sched_barrier(0);
        CMM_STAGE_PROJ((s + 1) << 5, cur ^ 1);   // 10 gload_lds fly under MFMA
        __builtin_amdgcn_sched_barrier(0);
      }
      __builtin_amdgcn_s_setprio(1);
      #pragma unroll
      for (int j = 0; j < 8; ++j) {
        bf16x8 bhf = *(const bf16x8*)&Bh[cur][(lq * 128 + j * 16 + lr) * 8];
        bf16x8 blf = *(const bf16x8*)&Bl[cur][(lq * 128 + j * 16 + lr) * 8];
        #pragma unroll
        for (int mi = 0; mi < 3; ++mi) {
          acc[mi][j] = __builtin_amdgcn_mfma_f32_16x16x32_bf16(ahf[mi], bhf, acc[mi][j], 0, 0, 0);
          acc[mi][j] = __builtin_amdgcn_mfma_f32_16x16x32_bf16(ahf[mi], blf, acc[mi][j], 0, 0, 0);
          acc[mi][j] = __builtin_amdgcn_mfma_f32_16x16x32_bf16(alf[mi], bhf, acc[mi][j], 0, 0, 0);
        }
      }
      __builtin_amdgcn_s_setprio(0);
    }
  }

  #pragma unroll
  for (int mi = 0; mi < 3; ++mi) {
    #pragma unroll
    for (int r = 0; r < 4; ++r) {
      const int m = m0 + (w * 3 + mi) * 16 + lq * 4 + r;
      const float bv2 = bias[m];
      const size_t rowo = ((size_t)bb * Mtot + m) * HW + n0;
      #pragma unroll
      for (int j = 0; j < 8; ++j) {
        const int n = j * 16 + lr;
        if constexpr (SPLITX) {
          ((short*)Outv)[rowo + n] = to_bf16_rne(acc[mi][j][r] + bv2);
        } else {
          ((float*)Outv)[rowo + n] = acc[mi][j][r] + bv2;
        }
      }
    }
  }
}

// ---------------------------------------------------------------------------
// Depthwise 3x3 + bias + to_heads + norm.  (round-11 config, unchanged)
// ---------------------------------------------------------------------------
__global__ __launch_bounds__(256) void k_dw(
    const short* __restrict__ tmp,
    const float* __restrict__ dww, const float* __restrict__ dwb,
    short* __restrict__ Qb, short* __restrict__ Kb,
    short* __restrict__ Vt, int b0)
{
  __shared__ short img[16384];        // 128x128 bf16 = 32KB
  __shared__ short dwout[16 * 1040];  // padded rows: bank-conflict-free
  __shared__ float sums[16][64];
  __shared__ float rednorm[16];

  const int gc = blockIdx.x, lb = blockIdx.y, b = b0 + lb;
  const int sel = gc / CDIM, chl = gc % CDIM;
  const int head = chl / 48, c = chl % 48;
  const short* gimg = tmp + ((size_t)lb * 576 + gc) * HW;
  const int t = threadIdx.x;

  #pragma unroll
  for (int cch = 0; cch < 8; ++cch)
    gload_lds16(gimg + cch * 2048 + t * 8, img + cch * 2048 + t * 8);

  float wgt[9];
  #pragma unroll
  for (int i = 0; i < 9; ++i) wgt[i] = dww[gc * 9 + i];
  const float bias = dwb[gc];

  asm volatile("s_waitcnt vmcnt(0)" ::: "memory");
  __syncthreads();

  const int fy = (t >> 4) & 3;
  float sqp[4] = {0.f, 0.f, 0.f, 0.f};

  for (int i = 0; i < 8; ++i) {
    const int p8 = i * 2048 + t * 8;
    const int h = p8 >> 7, w0 = p8 & 127;
    float win[3][10];
    #pragma unroll
    for (int dy = 0; dy < 3; ++dy) {
      const int r = h + dy - 1;
      if (r < 0 || r > 127) {
        #pragma unroll
        for (int q = 0; q < 10; ++q) win[dy][q] = 0.f;
      } else {
        const short* rp = img + r * 128 + w0;
        short8 c8 = *(const short8*)rp;
        win[dy][0] = (w0 > 0) ? b2f(rp[-1]) : 0.f;
        #pragma unroll
        for (int q = 0; q < 8; ++q) win[dy][1 + q] = b2f(c8[q]);
        win[dy][9] = (w0 < 120) ? b2f(rp[8]) : 0.f;
      }
    }
    const int na = (h >> 2) * 32 + (w0 >> 2);
    #pragma unroll
    for (int fx = 0; fx < 4; ++fx) {
      float a0 = bias, a1 = bias;
      #pragma unroll
      for (int dy = 0; dy < 3; ++dy)
        #pragma unroll
        for (int dx = 0; dx < 3; ++dx) {
          a0 = fmaf(win[dy][fx + dx], wgt[dy * 3 + dx], a0);
          a1 = fmaf(win[dy][4 + fx + dx], wgt[dy * 3 + dx], a1);
        }
      sqp[fx] = fmaf(a0, a0, sqp[fx]);
      sqp[fx] = fmaf(a1, a1, sqp[fx]);
      *(unsigned*)&dwout[(fx * 4 + fy) * 1040 + na] =
          ((unsigned)(unsigned short)to_bf16_rne(a1) << 16) |
          (unsigned short)to_bf16_rne(a0);
    }
  }

  if (sel < 2) {
    const int slot = (t & 15) | ((t >> 6) << 4);
    #pragma unroll
    for (int fx = 0; fx < 4; ++fx) sums[fx * 4 + fy][slot] = sqp[fx];
    __syncthreads();
    const int row = t >> 4, i16 = t & 15;
    float v = sums[row][i16] + sums[row][i16 + 16] + sums[row][i16 + 32] + sums[row][i16 + 48];
    __syncthreads();
    sums[row][i16] = v;
    __syncthreads();
    if (t < 16) {
      float s = 0.f;
      #pragma unroll
      for (int j = 0; j < 16; ++j) s += sums[t][j];
      rednorm[t] = fmaxf(sqrtf(s), 1e-12f);
    }
  } else {
    __syncthreads();
  }
  __syncthreads();

  if (sel == 2) {
    #pragma unroll
    for (int j = 0; j < 4; ++j) {
      const int n = t + j * 256;
      short8 v0, v1;
      #pragma unroll
      for (int rr = 0; rr < 8; ++rr) v0[rr] = dwout[rr * 1040 + n];
      #pragma unroll
      for (int rr = 0; rr < 8; ++rr) v1[rr] = dwout[(rr + 8) * 1040 + n];
      const size_t o = ((size_t)(b * 4 + head) * 1024 + n) * 768 + c * 16;
      *(short8*)&Vt[o] = v0;
      *(short8*)&Vt[o + 8] = v1;
    }
    return;
  }

  short* dst = (sel == 0) ? Qb : Kb;
  #pragma unroll
  for (int rr = 0; rr < 16; ++rr) {
    const float inv = 1.0f / rednorm[rr];
    const size_t rowoff = ((size_t)(b * 4 + head) * 768 + c * 16 + rr) * 1024;
    #pragma unroll
    for (int j = 0; j < 2; ++j) {
      const int n2 = j * 512 + t * 2;
      const unsigned pk = *(const unsigned*)&dwout[rr * 1040 + n2];
      const float v0 = b2f((short)(pk & 0xffffu)) * inv;
      const float v1 = b2f((short)(pk >> 16)) * inv;
      *(unsigned*)&dst[rowoff + n2] =
          ((unsigned)(unsigned short)to_bf16_rne(v1) << 16) | (unsigned short)to_bf16_rne(v0);
    }
  }
}

// ---------------------------------------------------------------------------
// E = exp(Q*K^T * temp).  192x256 tile, 512 threads (8 waves 2m x 4n).
// 3-buffer counted-vmcnt pipeline (vmcnt(4) steady, 0 only last step),
// single barrier per step — the measured optimum (R17's 2-buffer variant
// regressed: the exposed vmcnt(0) drain cost more than 2-blocks/CU TLP won).
// LDS slabs (1KB = 16 rows x 32 k): Q[0..11], K[12..27].  3 x 28KB = 84KB.
// ---------------------------------------------------------------------------
__global__ __launch_bounds__(512) void k_qk(
    const short* __restrict__ Qb, const short* __restrict__ Kbf,
    const float* __restrict__ temp,
    short* __restrict__ E, float* __restrict__ Sums)
{
  __shared__ short lds[3][14336];   // 3 x 28KB
  const int t = threadIdx.x, lane = t & 63, w = t >> 6;
  const int lr = lane & 15, lq = lane >> 4;

  const int flat = blockIdx.x;
  const int g = (flat & 7) * 48 + (flat >> 3);     // bijection on [0,384)
  const int bh = g / 12, tile = g % 12;
  const int m0 = (tile / 3) * 192, n0 = (tile % 3) * 256;
  const size_t base = (size_t)bh * 768 * 1024;

  f32x4 acc[6][4] = {};
  const int wm = (w >> 2) * 6, wn = (w & 3) * 4;

  const short* gsrc[4]; size_t goff[4]; int gdst[4]; bool gok[4];
  #pragma unroll
  for (int ii = 0; ii < 4; ++ii) {
    const int id = w * 4 + ii;                     // 0..31; 28..31 unused
    gok[ii] = (id < 28);
    const bool isq = (id < 12);
    gsrc[ii] = isq ? Qb : Kbf;
    const int row = isq ? (m0 + id * 16) : (n0 + (id - 12) * 16);
    goff[ii] = base + (size_t)(row + lr) * 1024 + lq * 8;
    gdst[ii] = (id < 28 ? id : 0) * 512;
  }
  #define QK_STAGE(buf, k0)                                                   \
    { _Pragma("unroll")                                                       \
      for (int ii = 0; ii < 4; ++ii)                                          \
        if (gok[ii]) gload_lds16(gsrc[ii] + goff[ii] + (k0), &lds[buf][gdst[ii]]); }

  QK_STAGE(0, 0);
  QK_STAGE(1, 32);

  for (int step = 0; step < 32; ++step) {
    const int cur = step % 3;
    if (step == 31) { asm volatile("s_waitcnt vmcnt(0)" ::: "memory"); }
    else            { asm volatile("s_waitcnt vmcnt(4)" ::: "memory"); }
    __builtin_amdgcn_s_barrier();
    __builtin_amdgcn_sched_barrier(0);

    bf16x8 ah[6], bf_[4];
    #pragma unroll
    for (int i = 0; i < 6; ++i)
      ah[i] = *(const bf16x8*)&lds[cur][(wm + i) * 512 + lane * 8];
    #pragma unroll
    for (int j = 0; j < 4; ++j)
      bf_[j] = *(const bf16x8*)&lds[cur][(12 + wn + j) * 512 + lane * 8];

    if (step < 30) QK_STAGE((step + 2) % 3, (step + 2) << 5);

    asm volatile("s_waitcnt lgkmcnt(0)" ::: "memory");
    __builtin_amdgcn_sched_barrier(0);
    __builtin_amdgcn_s_setprio(1);
    #pragma unroll
    for (int i = 0; i < 6; ++i)
      #pragma unroll
      for (int j = 0; j < 4; ++j)
        acc[i][j] = __builtin_amdgcn_mfma_f32_16x16x32_bf16(ah[i], bf_[j], acc[i][j], 0, 0, 0);
    __builtin_amdgcn_s_setprio(0);
    __builtin_amdgcn_sched_barrier(0);
  }
  #undef QK_STAGE

  const float tp = temp[bh & 3];
  float* Srow = Sums + bh * 768;
  short* Ep = E + (size_t)bh * 768 * 768;
  #pragma unroll
  for (int i = 0; i < 6; ++i) {
    #pragma unroll
    for (int r = 0; r < 4; ++r) {
      const int m = m0 + (w >> 2) * 96 + i * 16 + lq * 4 + r;
      short* erow = Ep + (size_t)m * 768 + n0 + (w & 3) * 64;
      float rs = 0.f;
      #pragma unroll
      for (int j = 0; j < 4; ++j) {
        const float e = expf(acc[i][j][r] * tp);
        rs += e;
        erow[j * 16 + lr] = to_bf16_rne(e);
      }
      rs += __shfl_xor(rs, 1);
      rs += __shfl_xor(rs, 2);
      rs += __shfl_xor(rs, 4);
      rs += __shfl_xor(rs, 8);
      if (lr == 0) atomicAdd(&Srow[m], rs);
    }
  }
}

// ---------------------------------------------------------------------------
// O = (E * V) / (sum+1).  256x256 tile, 512 threads.
// 3-buffer counted-vmcnt pipeline (vmcnt(4) steady), single barrier/step.
// Epilogue: 4 passes (hi/lo x 2 kcp-chunks) staging a contiguous 64KB output
// chunk in lds[0..1], short8 coalesced stores.
// ---------------------------------------------------------------------------
__global__ __launch_bounds__(512) void k_av(
    const short* __restrict__ Ebf, const short* __restrict__ Vtb,
    const float* __restrict__ Sums,
    short* __restrict__ Phi, short* __restrict__ Plo)
{
  __shared__ short lds[3][16384];   // 3 x 32KB
  const int t = threadIdx.x, lane = t & 63, w = t >> 6;
  const int lr = lane & 15, lq = lane >> 4;

  const int flat = blockIdx.x;
  const int g = (flat & 7) * 48 + (flat >> 3);     // bijection on [0,384)
  const int bh = g / 12, tile = g % 12;
  const int m0 = (tile / 4) * 256, n0 = (tile % 4) * 256;
  const int head = bh & 3, b = bh >> 2;
  const short* Sp = Ebf + (size_t)bh * 768 * 768;
  const short* Vp = Vtb + (size_t)bh * 1024 * 768;

  f32x4 acc[8][4] = {};
  const int wm = (w >> 2) * 8, wn = (w & 3) * 4;

  const short* gsrc[4]; size_t goff[4]; int gdst[4];
  #pragma unroll
  for (int ii = 0; ii < 4; ++ii) {
    const int id = w * 4 + ii;                     // 0..31
    const int arr = id >> 4, s = id & 15;
    gsrc[ii] = arr ? Vp : Sp;
    const int row = (arr ? n0 : m0) + s * 16;
    goff[ii] = (size_t)(row + lr) * 768 + lq * 8;
    gdst[ii] = id * 512;
  }
  #define AV_STAGE(buf, k0)                                                   \
    { _Pragma("unroll")                                                       \
      for (int ii = 0; ii < 4; ++ii)                                          \
        gload_lds16(gsrc[ii] + goff[ii] + (k0), &lds[buf][gdst[ii]]); }

  AV_STAGE(0, 0);
  AV_STAGE(1, 32);

  for (int step = 0; step < 24; ++step) {
    const int cur = step % 3;
    if (step == 23) { asm volatile("s_waitcnt vmcnt(0)" ::: "memory"); }
    else            { asm volatile("s_waitcnt vmcnt(4)" ::: "memory"); }
    __builtin_amdgcn_s_barrier();
    __builtin_amdgcn_sched_barrier(0);

    bf16x8 ea[8], vb[4];
    #pragma unroll
    for (int i = 0; i < 8; ++i)
      ea[i] = *(const bf16x8*)&lds[cur][(wm + i) * 512 + lane * 8];
    #pragma unroll
    for (int j = 0; j < 4; ++j)
      vb[j] = *(const bf16x8*)&lds[cur][(16 + wn + j) * 512 + lane * 8];

    if (step < 22) AV_STAGE((step + 2) % 3, (step + 2) << 5);

    asm volatile("s_waitcnt lgkmcnt(0)" ::: "memory");
    __builtin_amdgcn_sched_barrier(0);
    __builtin_amdgcn_s_setprio(1);
    #pragma unroll
    for (int i = 0; i < 8; ++i)
      #pragma unroll
      for (int j = 0; j < 4; ++j)
        acc[i][j] = __builtin_amdgcn_mfma_f32_16x16x32_bf16(ea[i], vb[j], acc[i][j], 0, 0, 0);
    __builtin_amdgcn_s_setprio(0);
    __builtin_amdgcn_sched_barrier(0);
  }
  #undef AV_STAGE

  // ---- scale by 1/(sum+1) in-register ----
  const float* Srow = Sums + bh * 768;
  float invv[8][4];
  #pragma unroll
  for (int i = 0; i < 8; ++i)
    #pragma unroll
    for (int r = 0; r < 4; ++r) {
      const int d = m0 + (w >> 2) * 128 + i * 16 + lq * 4 + r;
      invv[i][r] = 1.0f / (Srow[d] + 1.0f);
    }
  #pragma unroll
  for (int i = 0; i < 8; ++i)
    #pragma unroll
    for (int j = 0; j < 4; ++j)
      #pragma unroll
      for (int r = 0; r < 4; ++r)
        acc[i][j][r] *= invv[i][r];

  // ---- LDS-staged coalesced epilogue: 4 passes of one 64KB chunk each ----
  short* stg = &lds[0][0];                         // 32768 shorts = 64KB
  const int kcp0 = head * 6 + (m0 >> 7);
  const int myc = w >> 2;

  #pragma unroll
  for (int a = 0; a < 2; ++a) {
    #pragma unroll
    for (int c = 0; c < 2; ++c) {
      __syncthreads();   // protect vs prior reads of stg
      if (myc == c) {
        #pragma unroll
        for (int j = 0; j < 4; ++j) {
          const int nl = (w & 3) * 64 + j * 16 + lr;
          #pragma unroll
          for (int r = 0; r < 4; ++r) {
            short8 s8;
            #pragma unroll
            for (int i = 0; i < 8; ++i) {
              const float v = acc[i][j][r];
              const unsigned u = __float_as_uint(v);
              if (a == 0) {
                s8[i] = (short)(u >> 16);
              } else {
                const float res = v - __uint_as_float(u & 0xffff0000u);
                s8[i] = (short)(__float_as_uint(res) >> 16);
              }
            }
            const int loff = (((nl >> 5) * 4 + r) * 128 + (nl & 31) * 4 + lq) * 8;
            *(short8*)&stg[loff] = s8;
          }
        }
      }
      __syncthreads();
      short* dst = (a ? Plo : Phi) +
                   ((size_t)(b * 24 + kcp0 + c) * HW + n0 * 16) * 8;
      #pragma unroll
      for (int it = 0; it < 8; ++it) {
        const int idx = it * 4096 + t * 8;
        *(short8*)&dst[idx] = *(const short8*)&stg[idx];
      }
    }
  }
}

// ---------------------------------------------------------------------------
extern "C" void kernel_launch(void* const* d_in, const int* in_sizes, int n_in,
                              void* d_out, int out_size, void* d_ws, size_t ws_size,
                              hipStream_t stream) {
  const float* x      = (const float*)d_in[0];
  const float* qkv_w  = (const float*)d_in[1];
  const float* qkv_b  = (const float*)d_in[2];
  const float* dw_w   = (const float*)d_in[3];
  const float* dw_b   = (const float*)d_in[4];
  const float* proj_w = (const float*)d_in[5];
  const float* proj_b = (const float*)d_in[6];
  const float* temp   = (const float*)d_in[7];
  float* out = (float*)d_out;

  float* F = (float*)d_ws;
  const size_t M25 = (size_t)8 * CDIM * HW;      // 25,165,824 elements
  short* Qb  = (short*)F;                         // [0, 50.3M)
  short* Plo = Qb + M25;                          // [50.3, 100.7M)
  short* Kb  = (short*)(F + M25);                 // [100.7, 151M)
  short* Vt  = Kb + M25;                          // [151, 201.3M)
  short* Ebf = (short*)(F + 2 * M25);             // [201.3, 239M)  (37.7MB)
  short* Phi = Qb;                                // alias Q (dead after qk)

  // tmpf (BF16) aliases the Ebf region onward: dead before k_qk writes E.
  short* tmpf = Ebf;
  const size_t ebfBytes  = (size_t)32 * 768 * 768 * 2;       // 37.75 MB
  const size_t baseBytes = 2 * M25 * 4;                      // 201.3 MB
  const size_t wsTailBytes = 294912 * 2 + 32 * 768 * 4 + 256; // weights+Sums
  int bpi = 2;
  for (int cand = 8; cand >= 2; cand >>= 1) {
    const size_t tmpfBytes = (size_t)cand * 576 * HW * 2;
    const size_t need = baseBytes + (tmpfBytes > ebfBytes ? tmpfBytes : ebfBytes)
                      + wsTailBytes;
    if (ws_size >= need) { bpi = cand; break; }
  }
  const size_t tmpfBytes = (size_t)bpi * 576 * HW * 2;
  short* WS = (short*)((char*)d_ws + baseBytes +
                       (tmpfBytes > ebfBytes ? tmpfBytes : ebfBytes));
  short* Wq_hi = WS;             // 576*192
  short* Wq_lo = WS + 110592;
  short* Wp_hi = WS + 221184;    // 192*192
  short* Wp_lo = WS + 258048;
  float* Sums  = (float*)(WS + 294912);           // 32*768 floats

  k_split_w<<<dim3(432), 256, 0, stream>>>(qkv_w, Wq_hi, Wq_lo, 110592);
  k_split_w<<<dim3(144), 256, 0, stream>>>(proj_w, Wp_hi, Wp_lo, 36864);
  k_zero<<<dim3(96), 256, 0, stream>>>(Sums, 32 * 768);

  for (int b0 = 0; b0 < 8; b0 += bpi) {
    k_cmm<true><<<dim3(384 * bpi), 256, 0, stream>>>(
        x + (size_t)b0 * CDIM * HW, nullptr, nullptr,
        Wq_hi, Wq_lo, qkv_b, tmpf, 576);
    k_dw<<<dim3(576, bpi), 256, 0, stream>>>(
        tmpf, dw_w, dw_b, Qb, Kb, Vt, b0);
  }

  k_qk<<<dim3(384), 512, 0, stream>>>(Qb, Kb, temp, Ebf, Sums);
  k_av<<<dim3(384), 512, 0, stream>>>(Ebf, Vt, Sums, Phi, Plo);
  k_cmm<false><<<dim3(128, 1, 8), 256, 0, stream>>>(
      nullptr, Phi, Plo, Wp_hi, Wp_lo, proj_b, out, 192);
}

// Round 19
// 540.100 us; speedup vs baseline: 1.0771x; 1.0299x over previous
//
#include <hip/hip_runtime.h>

#define HW 16384   // 128*128
#define CDIM 192

typedef short bf16x8 __attribute__((ext_vector_type(8)));
typedef short short8 __attribute__((ext_vector_type(8)));
typedef short short4_t __attribute__((ext_vector_type(4)));
typedef float f32x4  __attribute__((ext_vector_type(4)));

__device__ inline void gload_lds16(const void* g, void* l) {
  __builtin_amdgcn_global_load_lds(
      (const __attribute__((address_space(1))) void*)g,
      (__attribute__((address_space(3))) void*)l, 16, 0, 0);
}

__device__ inline short to_bf16_rne(float f) {
  unsigned u = __float_as_uint(f);
  unsigned r = u + 0x7fffu + ((u >> 16) & 1u);
  return (short)(r >> 16);
}

__device__ inline float b2f(short s) {
  return __uint_as_float(((unsigned)(unsigned short)s) << 16);
}

__device__ inline void split_bf16(float a, short& hi, short& lo) {
  unsigned u = __float_as_uint(a);
  hi = (short)(u >> 16);                       // truncated high part
  float res = a - __uint_as_float(u & 0xffff0000u);
  lo = (short)(__float_as_uint(res) >> 16);    // residual; pair accurate to ~2^-17
}

// ---------------------------------------------------------------------------
__global__ __launch_bounds__(256) void k_zero(float* __restrict__ p, int n) {
  int i = blockIdx.x * 256 + threadIdx.x;
  if (i < n) p[i] = 0.f;
}

// ---------------------------------------------------------------------------
__global__ __launch_bounds__(256) void k_split_w(
    const float* __restrict__ W, short* __restrict__ hi,
    short* __restrict__ lo, int n)
{
  int i = blockIdx.x * 256 + threadIdx.x;
  if (i < n) { short h, l; split_bf16(W[i], h, l); hi[i] = h; lo[i] = l; }
}

// ---------------------------------------------------------------------------
// Staging macros for k_cmm
// ---------------------------------------------------------------------------
#define CMM_LOADB(bv, k0)                                                     \
  { _Pragma("unroll")                                                         \
    for (int kk = 0; kk < 2; ++kk) {                                          \
      const int kcg = kg0 + kk * 2;                                           \
      _Pragma("unroll")                                                       \
      for (int j = 0; j < 8; ++j)                                             \
        bv[kk][j] = xf[(size_t)((k0) + kcg * 8 + j) * HW + n0 + px];          \
    } }

// W hi-only staging for the qkv path (W-lo dropped): 12 frags, 3 per wave
#define CMM_STAGEA1(k0, b)                                                    \
  { _Pragma("unroll")                                                         \
    for (int ii = 0; ii < 3; ++ii) {                                          \
      const int mf = w * 3 + ii;                 /* 0..11 */                  \
      const short* g = Whi + (size_t)(m0 + mf * 16 + lr) * CDIM + (k0) + lq * 8; \
      gload_lds16(g, Ah[b] + mf * 512);                                       \
    } }

// Single rne-bf16 B write (X-lo term dropped)
#define CMM_WRITEB1(bv, b)                                                    \
  { _Pragma("unroll")                                                         \
    for (int kk = 0; kk < 2; ++kk) {                                          \
      const int kcg = kg0 + kk * 2;                                           \
      short8 s8;                                                              \
      _Pragma("unroll")                                                       \
      for (int j = 0; j < 8; ++j) s8[j] = to_bf16_rne(bv[kk][j]);             \
      *(short8*)&Bh[b][(kcg * 128 + px) * 8] = s8;                            \
    } }

// A+B staging for the proj path (all gload_lds, both operands, hi/lo kept)
#define CMM_STAGE_PROJ(k0, b)                                                 \
  { _Pragma("unroll")                                                         \
    for (int ii = 0; ii < 6; ++ii) {                                          \
      const int id = w * 6 + ii, arr = id / 12, mf = id % 12;                 \
      const short* Wp = arr ? Wlo : Whi;                                      \
      const short* g = Wp + (size_t)(m0 + mf * 16 + lr) * CDIM + (k0) + lq * 8; \
      gload_lds16(g, (arr ? Al[b] : Ah[b]) + mf * 512);                       \
    }                                                                         \
    _Pragma("unroll")                                                         \
    for (int ii = 0; ii < 4; ++ii) {                                          \
      const int id = w * 4 + ii, arr = id >> 3, sub = id & 7;                 \
      const int kc = sub >> 1, half = sub & 1;                                \
      const short* src = arr ? xl : xh;                                       \
      const short* g = src + ((size_t)((k0) / 8 + kc) * HW + n0 + half * 64 + lane) * 8; \
      gload_lds16(g, (arr ? Bl[b] : Bh[b]) + (kc * 128 + half * 64) * 8);     \
    } }

// ---------------------------------------------------------------------------
// MFMA 1x1-conv GEMM.
// SPLITX=true (qkv path): round-12 schedule, NOW fully single-bf16 operands
//   (W-lo dropped — 4th precision-axis step; prior three were bit-identical
//   absmax).  24 MFMA/step (was 48), A staging 3 gload_lds (was 6), Al/Bl
//   eliminated -> LDS 40KB -> up to 4 blocks/CU (VGPR 112 < 128 cap at 16
//   waves/CU) doubling the TLP that hides the per-step vmcnt(0) drain.
//   Queue: top vmcnt(0)+lgkm(0); mid vmcnt(3) (B(s+1) landed, A(s+1) flying).
// SPLITX=false (proj path): 2-buffer pipelined, full hi/lo precision kept
//   (P/W-lo feed the final fp32 output directly — no rounding headroom).
// ---------------------------------------------------------------------------
template <bool SPLITX>
__global__ __launch_bounds__(256) void k_cmm(
    const float* __restrict__ Xf,
    const short* __restrict__ Xhi, const short* __restrict__ Xlo,
    const short* __restrict__ Whi, const short* __restrict__ Wlo,
    const float* __restrict__ bias, void* __restrict__ Outv, int Mtot)
{
  __shared__ short Ah[2][6144], Al[2][6144], Bh[2][4096], Bl[2][4096];
  const int t = threadIdx.x, lane = t & 63, w = t >> 6;
  const int lr = lane & 15, lq = lane >> 4;

  int bb, m0, n0;
  if constexpr (SPLITX) {
    const int flat = blockIdx.x;
    const int g = (flat & 7) * (gridDim.x >> 3) + (flat >> 3);
    bb = g / 384;
    const int rem = g % 384;
    m0 = (rem % 3) * 192;          // m fastest: trio shares X B-tile in L2
    n0 = (rem / 3) * 128;
  } else {
    bb = blockIdx.z; m0 = blockIdx.y * 192; n0 = blockIdx.x * 128;
  }

  const float* xf = nullptr;
  const short* xh = nullptr;
  const short* xl = nullptr;
  if constexpr (SPLITX) {
    xf = Xf + (size_t)bb * CDIM * HW;
  } else {
    xh = Xhi + (size_t)bb * 24 * HW * 8;
    xl = Xlo + (size_t)bb * 24 * HW * 8;
  }

  f32x4 acc[3][8] = {};

  if constexpr (SPLITX) {
    const int px = t & 127, kg0 = t >> 7;
    float bv[2][8];
    CMM_LOADB(bv, 0);
    CMM_STAGEA1(0, 0);
    asm volatile("s_waitcnt vmcnt(3)" ::: "memory");   // B(0) regs ready, A(0) flying
    __builtin_amdgcn_sched_barrier(0);
    CMM_WRITEB1(bv, 0);

    #pragma unroll
    for (int s = 0; s < 6; ++s) {
      const int cur = s & 1;
      asm volatile("s_waitcnt vmcnt(0) lgkmcnt(0)" ::: "memory");
      __builtin_amdgcn_s_barrier();
      __builtin_amdgcn_sched_barrier(0);

      if (s < 5) { CMM_LOADB(bv, (s + 1) << 5); }   // issue X loads first: max headroom
      bf16x8 ahf[3];
      #pragma unroll
      for (int mi = 0; mi < 3; ++mi)
        ahf[mi] = *(const bf16x8*)&Ah[cur][(w * 3 + mi) * 512 + lane * 8];
      if (s < 5) { CMM_STAGEA1((s + 1) << 5, cur ^ 1); }
      __builtin_amdgcn_sched_barrier(0);

      __builtin_amdgcn_s_setprio(1);
      #pragma unroll
      for (int j = 0; j < 8; ++j) {
        bf16x8 bsf = *(const bf16x8*)&Bh[cur][(lq * 128 + j * 16 + lr) * 8];
        #pragma unroll
        for (int mi = 0; mi < 3; ++mi)
          acc[mi][j] = __builtin_amdgcn_mfma_f32_16x16x32_bf16(ahf[mi], bsf, acc[mi][j], 0, 0, 0);
      }
      __builtin_amdgcn_s_setprio(0);
      if (s < 5) {
        __builtin_amdgcn_sched_barrier(0);
        asm volatile("s_waitcnt vmcnt(3)" ::: "memory");  // B(s+1) regs landed; A(s+1) flying
        __builtin_amdgcn_sched_barrier(0);
        CMM_WRITEB1(bv, cur ^ 1);
      }
    }
  } else {
    CMM_STAGE_PROJ(0, 0);
    for (int s = 0; s < 6; ++s) {
      const int cur = s & 1;
      asm volatile("s_waitcnt vmcnt(0) lgkmcnt(0)" ::: "memory");
      __builtin_amdgcn_s_barrier();
      __builtin_amdgcn_sched_barrier(0);

      bf16x8 ahf[3], alf[3];
      #pragma unroll
      for (int mi = 0; mi < 3; ++mi) {
        ahf[mi] = *(const bf16x8*)&Ah[cur][(w * 3 + mi) * 512 + lane * 8];
        alf[mi] = *(const bf16x8*)&Al[cur][(w * 3 + mi) * 512 + lane * 8];
      }
      if (s < 5) {
        __builtin_amdgcn_sched_barrier(0);
        CMM_STAGE_PROJ((s + 1) << 5, cur ^ 1);   // 10 gload_lds fly under MFMA
        __builtin_amdgcn_sched_barrier(0);
      }
      __builtin_amdgcn_s_setprio(1);
      #pragma unroll
      for (int j = 0; j < 8; ++j) {
        bf16x8 bhf = *(const bf16x8*)&Bh[cur][(lq * 128 + j * 16 + lr) * 8];
        bf16x8 blf = *(const bf16x8*)&Bl[cur][(lq * 128 + j * 16 + lr) * 8];
        #pragma unroll
        for (int mi = 0; mi < 3; ++mi) {
          acc[mi][j] = __builtin_amdgcn_mfma_f32_16x16x32_bf16(ahf[mi], bhf, acc[mi][j], 0, 0, 0);
          acc[mi][j] = __builtin_amdgcn_mfma_f32_16x16x32_bf16(ahf[mi], blf, acc[mi][j], 0, 0, 0);
          acc[mi][j] = __builtin_amdgcn_mfma_f32_16x16x32_bf16(alf[mi], bhf, acc[mi][j], 0, 0, 0);
        }
      }
      __builtin_amdgcn_s_setprio(0);
    }
  }

  #pragma unroll
  for (int mi = 0; mi < 3; ++mi) {
    #pragma unroll
    for (int r = 0; r < 4; ++r) {
      const int m = m0 + (w * 3 + mi) * 16 + lq * 4 + r;
      const float bv2 = bias[m];
      const size_t rowo = ((size_t)bb * Mtot + m) * HW + n0;
      #pragma unroll
      for (int j = 0; j < 8; ++j) {
        const int n = j * 16 + lr;
        if constexpr (SPLITX) {
          ((short*)Outv)[rowo + n] = to_bf16_rne(acc[mi][j][r] + bv2);
        } else {
          ((float*)Outv)[rowo + n] = acc[mi][j][r] + bv2;
        }
      }
    }
  }
}

// ---------------------------------------------------------------------------
// Depthwise 3x3 + bias + to_heads + norm.  (round-11 config, unchanged)
// ---------------------------------------------------------------------------
__global__ __launch_bounds__(256) void k_dw(
    const short* __restrict__ tmp,
    const float* __restrict__ dww, const float* __restrict__ dwb,
    short* __restrict__ Qb, short* __restrict__ Kb,
    short* __restrict__ Vt, int b0)
{
  __shared__ short img[16384];        // 128x128 bf16 = 32KB
  __shared__ short dwout[16 * 1040];  // padded rows: bank-conflict-free
  __shared__ float sums[16][64];
  __shared__ float rednorm[16];

  const int gc = blockIdx.x, lb = blockIdx.y, b = b0 + lb;
  const int sel = gc / CDIM, chl = gc % CDIM;
  const int head = chl / 48, c = chl % 48;
  const short* gimg = tmp + ((size_t)lb * 576 + gc) * HW;
  const int t = threadIdx.x;

  #pragma unroll
  for (int cch = 0; cch < 8; ++cch)
    gload_lds16(gimg + cch * 2048 + t * 8, img + cch * 2048 + t * 8);

  float wgt[9];
  #pragma unroll
  for (int i = 0; i < 9; ++i) wgt[i] = dww[gc * 9 + i];
  const float bias = dwb[gc];

  asm volatile("s_waitcnt vmcnt(0)" ::: "memory");
  __syncthreads();

  const int fy = (t >> 4) & 3;
  float sqp[4] = {0.f, 0.f, 0.f, 0.f};

  for (int i = 0; i < 8; ++i) {
    const int p8 = i * 2048 + t * 8;
    const int h = p8 >> 7, w0 = p8 & 127;
    float win[3][10];
    #pragma unroll
    for (int dy = 0; dy < 3; ++dy) {
      const int r = h + dy - 1;
      if (r < 0 || r > 127) {
        #pragma unroll
        for (int q = 0; q < 10; ++q) win[dy][q] = 0.f;
      } else {
        const short* rp = img + r * 128 + w0;
        short8 c8 = *(const short8*)rp;
        win[dy][0] = (w0 > 0) ? b2f(rp[-1]) : 0.f;
        #pragma unroll
        for (int q = 0; q < 8; ++q) win[dy][1 + q] = b2f(c8[q]);
        win[dy][9] = (w0 < 120) ? b2f(rp[8]) : 0.f;
      }
    }
    const int na = (h >> 2) * 32 + (w0 >> 2);
    #pragma unroll
    for (int fx = 0; fx < 4; ++fx) {
      float a0 = bias, a1 = bias;
      #pragma unroll
      for (int dy = 0; dy < 3; ++dy)
        #pragma unroll
        for (int dx = 0; dx < 3; ++dx) {
          a0 = fmaf(win[dy][fx + dx], wgt[dy * 3 + dx], a0);
          a1 = fmaf(win[dy][4 + fx + dx], wgt[dy * 3 + dx], a1);
        }
      sqp[fx] = fmaf(a0, a0, sqp[fx]);
      sqp[fx] = fmaf(a1, a1, sqp[fx]);
      *(unsigned*)&dwout[(fx * 4 + fy) * 1040 + na] =
          ((unsigned)(unsigned short)to_bf16_rne(a1) << 16) |
          (unsigned short)to_bf16_rne(a0);
    }
  }

  if (sel < 2) {
    const int slot = (t & 15) | ((t >> 6) << 4);
    #pragma unroll
    for (int fx = 0; fx < 4; ++fx) sums[fx * 4 + fy][slot] = sqp[fx];
    __syncthreads();
    const int row = t >> 4, i16 = t & 15;
    float v = sums[row][i16] + sums[row][i16 + 16] + sums[row][i16 + 32] + sums[row][i16 + 48];
    __syncthreads();
    sums[row][i16] = v;
    __syncthreads();
    if (t < 16) {
      float s = 0.f;
      #pragma unroll
      for (int j = 0; j < 16; ++j) s += sums[t][j];
      rednorm[t] = fmaxf(sqrtf(s), 1e-12f);
    }
  } else {
    __syncthreads();
  }
  __syncthreads();

  if (sel == 2) {
    #pragma unroll
    for (int j = 0; j < 4; ++j) {
      const int n = t + j * 256;
      short8 v0, v1;
      #pragma unroll
      for (int rr = 0; rr < 8; ++rr) v0[rr] = dwout[rr * 1040 + n];
      #pragma unroll
      for (int rr = 0; rr < 8; ++rr) v1[rr] = dwout[(rr + 8) * 1040 + n];
      const size_t o = ((size_t)(b * 4 + head) * 1024 + n) * 768 + c * 16;
      *(short8*)&Vt[o] = v0;
      *(short8*)&Vt[o + 8] = v1;
    }
    return;
  }

  short* dst = (sel == 0) ? Qb : Kb;
  #pragma unroll
  for (int rr = 0; rr < 16; ++rr) {
    const float inv = 1.0f / rednorm[rr];
    const size_t rowoff = ((size_t)(b * 4 + head) * 768 + c * 16 + rr) * 1024;
    #pragma unroll
    for (int j = 0; j < 2; ++j) {
      const int n2 = j * 512 + t * 2;
      const unsigned pk = *(const unsigned*)&dwout[rr * 1040 + n2];
      const float v0 = b2f((short)(pk & 0xffffu)) * inv;
      const float v1 = b2f((short)(pk >> 16)) * inv;
      *(unsigned*)&dst[rowoff + n2] =
          ((unsigned)(unsigned short)to_bf16_rne(v1) << 16) | (unsigned short)to_bf16_rne(v0);
    }
  }
}

// ---------------------------------------------------------------------------
// E = exp(Q*K^T * temp).  192x256 tile, 512 threads (8 waves 2m x 4n).
// 3-buffer counted-vmcnt pipeline (vmcnt(4) steady, 0 only last step),
// single barrier per step — the measured optimum.
// LDS slabs (1KB = 16 rows x 32 k): Q[0..11], K[12..27].  3 x 28KB = 84KB.
// ---------------------------------------------------------------------------
__global__ __launch_bounds__(512) void k_qk(
    const short* __restrict__ Qb, const short* __restrict__ Kbf,
    const float* __restrict__ temp,
    short* __restrict__ E, float* __restrict__ Sums)
{
  __shared__ short lds[3][14336];   // 3 x 28KB
  const int t = threadIdx.x, lane = t & 63, w = t >> 6;
  const int lr = lane & 15, lq = lane >> 4;

  const int flat = blockIdx.x;
  const int g = (flat & 7) * 48 + (flat >> 3);     // bijection on [0,384)
  const int bh = g / 12, tile = g % 12;
  const int m0 = (tile / 3) * 192, n0 = (tile % 3) * 256;
  const size_t base = (size_t)bh * 768 * 1024;

  f32x4 acc[6][4] = {};
  const int wm = (w >> 2) * 6, wn = (w & 3) * 4;

  const short* gsrc[4]; size_t goff[4]; int gdst[4]; bool gok[4];
  #pragma unroll
  for (int ii = 0; ii < 4; ++ii) {
    const int id = w * 4 + ii;                     // 0..31; 28..31 unused
    gok[ii] = (id < 28);
    const bool isq = (id < 12);
    gsrc[ii] = isq ? Qb : Kbf;
    const int row = isq ? (m0 + id * 16) : (n0 + (id - 12) * 16);
    goff[ii] = base + (size_t)(row + lr) * 1024 + lq * 8;
    gdst[ii] = (id < 28 ? id : 0) * 512;
  }
  #define QK_STAGE(buf, k0)                                                   \
    { _Pragma("unroll")                                                       \
      for (int ii = 0; ii < 4; ++ii)                                          \
        if (gok[ii]) gload_lds16(gsrc[ii] + goff[ii] + (k0), &lds[buf][gdst[ii]]); }

  QK_STAGE(0, 0);
  QK_STAGE(1, 32);

  for (int step = 0; step < 32; ++step) {
    const int cur = step % 3;
    if (step == 31) { asm volatile("s_waitcnt vmcnt(0)" ::: "memory"); }
    else            { asm volatile("s_waitcnt vmcnt(4)" ::: "memory"); }
    __builtin_amdgcn_s_barrier();
    __builtin_amdgcn_sched_barrier(0);

    bf16x8 ah[6], bf_[4];
    #pragma unroll
    for (int i = 0; i < 6; ++i)
      ah[i] = *(const bf16x8*)&lds[cur][(wm + i) * 512 + lane * 8];
    #pragma unroll
    for (int j = 0; j < 4; ++j)
      bf_[j] = *(const bf16x8*)&lds[cur][(12 + wn + j) * 512 + lane * 8];

    if (step < 30) QK_STAGE((step + 2) % 3, (step + 2) << 5);

    asm volatile("s_waitcnt lgkmcnt(0)" ::: "memory");
    __builtin_amdgcn_sched_barrier(0);
    __builtin_amdgcn_s_setprio(1);
    #pragma unroll
    for (int i = 0; i < 6; ++i)
      #pragma unroll
      for (int j = 0; j < 4; ++j)
        acc[i][j] = __builtin_amdgcn_mfma_f32_16x16x32_bf16(ah[i], bf_[j], acc[i][j], 0, 0, 0);
    __builtin_amdgcn_s_setprio(0);
    __builtin_amdgcn_sched_barrier(0);
  }
  #undef QK_STAGE

  const float tp = temp[bh & 3];
  float* Srow = Sums + bh * 768;
  short* Ep = E + (size_t)bh * 768 * 768;
  #pragma unroll
  for (int i = 0; i < 6; ++i) {
    #pragma unroll
    for (int r = 0; r < 4; ++r) {
      const int m = m0 + (w >> 2) * 96 + i * 16 + lq * 4 + r;
      short* erow = Ep + (size_t)m * 768 + n0 + (w & 3) * 64;
      float rs = 0.f;
      #pragma unroll
      for (int j = 0; j < 4; ++j) {
        const float e = expf(acc[i][j][r] * tp);
        rs += e;
        erow[j * 16 + lr] = to_bf16_rne(e);
      }
      rs += __shfl_xor(rs, 1);
      rs += __shfl_xor(rs, 2);
      rs += __shfl_xor(rs, 4);
      rs += __shfl_xor(rs, 8);
      if (lr == 0) atomicAdd(&Srow[m], rs);
    }
  }
}

// ---------------------------------------------------------------------------
// O = (E * V) / (sum+1).  256x256 tile, 512 threads.
// 3-buffer counted-vmcnt pipeline (vmcnt(4) steady), single barrier/step.
// Epilogue: 4 passes (hi/lo x 2 kcp-chunks) staging a contiguous 64KB output
// chunk in lds[0..1], short8 coalesced stores.
// ---------------------------------------------------------------------------
__global__ __launch_bounds__(512) void k_av(
    const short* __restrict__ Ebf, const short* __restrict__ Vtb,
    const float* __restrict__ Sums,
    short* __restrict__ Phi, short* __restrict__ Plo)
{
  __shared__ short lds[3][16384];   // 3 x 32KB
  const int t = threadIdx.x, lane = t & 63, w = t >> 6;
  const int lr = lane & 15, lq = lane >> 4;

  const int flat = blockIdx.x;
  const int g = (flat & 7) * 48 + (flat >> 3);     // bijection on [0,384)
  const int bh = g / 12, tile = g % 12;
  const int m0 = (tile / 4) * 256, n0 = (tile % 4) * 256;
  const int head = bh & 3, b = bh >> 2;
  const short* Sp = Ebf + (size_t)bh * 768 * 768;
  const short* Vp = Vtb + (size_t)bh * 1024 * 768;

  f32x4 acc[8][4] = {};
  const int wm = (w >> 2) * 8, wn = (w & 3) * 4;

  const short* gsrc[4]; size_t goff[4]; int gdst[4];
  #pragma unroll
  for (int ii = 0; ii < 4; ++ii) {
    const int id = w * 4 + ii;                     // 0..31
    const int arr = id >> 4, s = id & 15;
    gsrc[ii] = arr ? Vp : Sp;
    const int row = (arr ? n0 : m0) + s * 16;
    goff[ii] = (size_t)(row + lr) * 768 + lq * 8;
    gdst[ii] = id * 512;
  }
  #define AV_STAGE(buf, k0)                                                   \
    { _Pragma("unroll")                                                       \
      for (int ii = 0; ii < 4; ++ii)                                          \
        gload_lds16(gsrc[ii] + goff[ii] + (k0), &lds[buf][gdst[ii]]); }

  AV_STAGE(0, 0);
  AV_STAGE(1, 32);

  for (int step = 0; step < 24; ++step) {
    const int cur = step % 3;
    if (step == 23) { asm volatile("s_waitcnt vmcnt(0)" ::: "memory"); }
    else            { asm volatile("s_waitcnt vmcnt(4)" ::: "memory"); }
    __builtin_amdgcn_s_barrier();
    __builtin_amdgcn_sched_barrier(0);

    bf16x8 ea[8], vb[4];
    #pragma unroll
    for (int i = 0; i < 8; ++i)
      ea[i] = *(const bf16x8*)&lds[cur][(wm + i) * 512 + lane * 8];
    #pragma unroll
    for (int j = 0; j < 4; ++j)
      vb[j] = *(const bf16x8*)&lds[cur][(16 + wn + j) * 512 + lane * 8];

    if (step < 22) AV_STAGE((step + 2) % 3, (step + 2) << 5);

    asm volatile("s_waitcnt lgkmcnt(0)" ::: "memory");
    __builtin_amdgcn_sched_barrier(0);
    __builtin_amdgcn_s_setprio(1);
    #pragma unroll
    for (int i = 0; i < 8; ++i)
      #pragma unroll
      for (int j = 0; j < 4; ++j)
        acc[i][j] = __builtin_amdgcn_mfma_f32_16x16x32_bf16(ea[i], vb[j], acc[i][j], 0, 0, 0);
    __builtin_amdgcn_s_setprio(0);
    __builtin_amdgcn_sched_barrier(0);
  }
  #undef AV_STAGE

  // ---- scale by 1/(sum+1) in-register ----
  const float* Srow = Sums + bh * 768;
  float invv[8][4];
  #pragma unroll
  for (int i = 0; i < 8; ++i)
    #pragma unroll
    for (int r = 0; r < 4; ++r) {
      const int d = m0 + (w >> 2) * 128 + i * 16 + lq * 4 + r;
      invv[i][r] = 1.0f / (Srow[d] + 1.0f);
    }
  #pragma unroll
  for (int i = 0; i < 8; ++i)
    #pragma unroll
    for (int j = 0; j < 4; ++j)
      #pragma unroll
      for (int r = 0; r < 4; ++r)
        acc[i][j][r] *= invv[i][r];

  // ---- LDS-staged coalesced epilogue: 4 passes of one 64KB chunk each ----
  short* stg = &lds[0][0];                         // 32768 shorts = 64KB
  const int kcp0 = head * 6 + (m0 >> 7);
  const int myc = w >> 2;

  #pragma unroll
  for (int a = 0; a < 2; ++a) {
    #pragma unroll
    for (int c = 0; c < 2; ++c) {
      __syncthreads();   // protect vs prior reads of stg
      if (myc == c) {
        #pragma unroll
        for (int j = 0; j < 4; ++j) {
          const int nl = (w & 3) * 64 + j * 16 + lr;
          #pragma unroll
          for (int r = 0; r < 4; ++r) {
            short8 s8;
            #pragma unroll
            for (int i = 0; i < 8; ++i) {
              const float v = acc[i][j][r];
              const unsigned u = __float_as_uint(v);
              if (a == 0) {
                s8[i] = (short)(u >> 16);
              } else {
                const float res = v - __uint_as_float(u & 0xffff0000u);
                s8[i] = (short)(__float_as_uint(res) >> 16);
              }
            }
            const int loff = (((nl >> 5) * 4 + r) * 128 + (nl & 31) * 4 + lq) * 8;
            *(short8*)&stg[loff] = s8;
          }
        }
      }
      __syncthreads();
      short* dst = (a ? Plo : Phi) +
                   ((size_t)(b * 24 + kcp0 + c) * HW + n0 * 16) * 8;
      #pragma unroll
      for (int it = 0; it < 8; ++it) {
        const int idx = it * 4096 + t * 8;
        *(short8*)&dst[idx] = *(const short8*)&stg[idx];
      }
    }
  }
}

// ---------------------------------------------------------------------------
extern "C" void kernel_launch(void* const* d_in, const int* in_sizes, int n_in,
                              void* d_out, int out_size, void* d_ws, size_t ws_size,
                              hipStream_t stream) {
  const float* x      = (const float*)d_in[0];
  const float* qkv_w  = (const float*)d_in[1];
  const float* qkv_b  = (const float*)d_in[2];
  const float* dw_w   = (const float*)d_in[3];
  const float* dw_b   = (const float*)d_in[4];
  const float* proj_w = (const float*)d_in[5];
  const float* proj_b = (const float*)d_in[6];
  const float* temp   = (const float*)d_in[7];
  float* out = (float*)d_out;

  float* F = (float*)d_ws;
  const size_t M25 = (size_t)8 * CDIM * HW;      // 25,165,824 elements
  short* Qb  = (short*)F;                         // [0, 50.3M)
  short* Plo = Qb + M25;                          // [50.3, 100.7M)
  short* Kb  = (short*)(F + M25);                 // [100.7, 151M)
  short* Vt  = Kb + M25;                          // [151, 201.3M)
  short* Ebf = (short*)(F + 2 * M25);             // [201.3, 239M)  (37.7MB)
  short* Phi = Qb;                                // alias Q (dead after qk)

  // tmpf (BF16) aliases the Ebf region onward: dead before k_qk writes E.
  short* tmpf = Ebf;
  const size_t ebfBytes  = (size_t)32 * 768 * 768 * 2;       // 37.75 MB
  const size_t baseBytes = 2 * M25 * 4;                      // 201.3 MB
  const size_t wsTailBytes = 294912 * 2 + 32 * 768 * 4 + 256; // weights+Sums
  int bpi = 2;
  for (int cand = 8; cand >= 2; cand >>= 1) {
    const size_t tmpfBytes = (size_t)cand * 576 * HW * 2;
    const size_t need = baseBytes + (tmpfBytes > ebfBytes ? tmpfBytes : ebfBytes)
                      + wsTailBytes;
    if (ws_size >= need) { bpi = cand; break; }
  }
  const size_t tmpfBytes = (size_t)bpi * 576 * HW * 2;
  short* WS = (short*)((char*)d_ws + baseBytes +
                       (tmpfBytes > ebfBytes ? tmpfBytes : ebfBytes));
  short* Wq_hi = WS;             // 576*192
  short* Wq_lo = WS + 110592;
  short* Wp_hi = WS + 221184;    // 192*192
  short* Wp_lo = WS + 258048;
  float* Sums  = (float*)(WS + 294912);           // 32*768 floats

  k_split_w<<<dim3(432), 256, 0, stream>>>(qkv_w, Wq_hi, Wq_lo, 110592);
  k_split_w<<<dim3(144), 256, 0, stream>>>(proj_w, Wp_hi, Wp_lo, 36864);
  k_zero<<<dim3(96), 256, 0, stream>>>(Sums, 32 * 768);

  for (int b0 = 0; b0 < 8; b0 += bpi) {
    k_cmm<true><<<dim3(384 * bpi), 256, 0, stream>>>(
        x + (size_t)b0 * CDIM * HW, nullptr, nullptr,
        Wq_hi, Wq_lo, qkv_b, tmpf, 576);
    k_dw<<<dim3(576, bpi), 256, 0, stream>>>(
        tmpf, dw_w, dw_b, Qb, Kb, Vt, b0);
  }

  k_qk<<<dim3(384), 512, 0, stream>>>(Qb, Kb, temp, Ebf, Sums);
  k_av<<<dim3(384), 512, 0, stream>>>(Ebf, Vt, Sums, Phi, Plo);
  k_cmm<false><<<dim3(128, 1, 8), 256, 0, stream>>>(
      nullptr, Phi, Plo, Wp_hi, Wp_lo, proj_b, out, 192);
}

// Round 20
// 535.228 us; speedup vs baseline: 1.0869x; 1.0091x over previous
//
#include <hip/hip_runtime.h>

#define HW 16384   // 128*128
#define CDIM 192

typedef short bf16x8 __attribute__((ext_vector_type(8)));
typedef short short8 __attribute__((ext_vector_type(8)));
typedef short short4_t __attribute__((ext_vector_type(4)));
typedef float f32x4  __attribute__((ext_vector_type(4)));

__device__ inline void gload_lds16(const void* g, void* l) {
  __builtin_amdgcn_global_load_lds(
      (const __attribute__((address_space(1))) void*)g,
      (__attribute__((address_space(3))) void*)l, 16, 0, 0);
}

__device__ inline short to_bf16_rne(float f) {
  unsigned u = __float_as_uint(f);
  unsigned r = u + 0x7fffu + ((u >> 16) & 1u);
  return (short)(r >> 16);
}

__device__ inline float b2f(short s) {
  return __uint_as_float(((unsigned)(unsigned short)s) << 16);
}

__device__ inline void split_bf16(float a, short& hi, short& lo) {
  unsigned u = __float_as_uint(a);
  hi = (short)(u >> 16);                       // truncated high part
  float res = a - __uint_as_float(u & 0xffff0000u);
  lo = (short)(__float_as_uint(res) >> 16);    // residual; pair accurate to ~2^-17
}

// ---------------------------------------------------------------------------
__global__ __launch_bounds__(256) void k_zero(float* __restrict__ p, int n) {
  int i = blockIdx.x * 256 + threadIdx.x;
  if (i < n) p[i] = 0.f;
}

// ---------------------------------------------------------------------------
__global__ __launch_bounds__(256) void k_split_w(
    const float* __restrict__ W, short* __restrict__ hi,
    short* __restrict__ lo, int n)
{
  int i = blockIdx.x * 256 + threadIdx.x;
  if (i < n) { short h, l; split_bf16(W[i], h, l); hi[i] = h; lo[i] = l; }
}

// ---------------------------------------------------------------------------
// Staging macros for k_cmm
// ---------------------------------------------------------------------------
#define CMM_LOADB(bv, k0)                                                     \
  { _Pragma("unroll")                                                         \
    for (int kk = 0; kk < 2; ++kk) {                                          \
      const int kcg = kg0 + kk * 2;                                           \
      _Pragma("unroll")                                                       \
      for (int j = 0; j < 8; ++j)                                             \
        bv[kk][j] = xf[(size_t)((k0) + kcg * 8 + j) * HW + n0 + px];          \
    } }

// W hi-only staging for the qkv path (W-lo dropped): 12 frags, 3 per wave
#define CMM_STAGEA1(k0, b)                                                    \
  { _Pragma("unroll")                                                         \
    for (int ii = 0; ii < 3; ++ii) {                                          \
      const int mf = w * 3 + ii;                 /* 0..11 */                  \
      const short* g = Whi + (size_t)(m0 + mf * 16 + lr) * CDIM + (k0) + lq * 8; \
      gload_lds16(g, Ah[b] + mf * 512);                                       \
    } }

// Single rne-bf16 B write (X-lo term dropped)
#define CMM_WRITEB1(bv, b)                                                    \
  { _Pragma("unroll")                                                         \
    for (int kk = 0; kk < 2; ++kk) {                                          \
      const int kcg = kg0 + kk * 2;                                           \
      short8 s8;                                                              \
      _Pragma("unroll")                                                       \
      for (int j = 0; j < 8; ++j) s8[j] = to_bf16_rne(bv[kk][j]);             \
      *(short8*)&Bh[b][(kcg * 128 + px) * 8] = s8;                            \
    } }

// A+B staging for the proj path (all gload_lds, both operands, hi/lo kept)
#define CMM_STAGE_PROJ(k0, b)                                                 \
  { _Pragma("unroll")                                                         \
    for (int ii = 0; ii < 6; ++ii) {                                          \
      const int id = w * 6 + ii, arr = id / 12, mf = id % 12;                 \
      const short* Wp = arr ? Wlo : Whi;                                      \
      const short* g = Wp + (size_t)(m0 + mf * 16 + lr) * CDIM + (k0) + lq * 8; \
      gload_lds16(g, (arr ? Al[b] : Ah[b]) + mf * 512);                       \
    }                                                                         \
    _Pragma("unroll")                                                         \
    for (int ii = 0; ii < 4; ++ii) {                                          \
      const int id = w * 4 + ii, arr = id >> 3, sub = id & 7;                 \
      const int kc = sub >> 1, half = sub & 1;                                \
      const short* src = arr ? xl : xh;                                       \
      const short* g = src + ((size_t)((k0) / 8 + kc) * HW + n0 + half * 64 + lane) * 8; \
      gload_lds16(g, (arr ? Bl[b] : Bh[b]) + (kc * 128 + half * 64) * 8);     \
    } }

// ---------------------------------------------------------------------------
// MFMA 1x1-conv GEMM.
// SPLITX=true (qkv path): single-bf16 operands (R19) + NEW deep-B pipeline:
//   B regs loaded TWO steps ahead via bvA/bvB ping-pong.  Round 14's version
//   of this failed only because base VGPR was 120 (+16 -> 132 > 128 cap,
//   occupancy halved); base is now 104 after the W-lo drop -> ~120 <= 128.
//   Queue (in-order): enter step s with [A(s)x3, B(s+1)x16] -> top vmcnt(16)
//   (A done, B flying); after STAGEA1(s+1): [B(s+1)x16, A(s+1)x3] -> mid
//   vmcnt(3); WRITEB(s+1) then LOADB(s+2).  B latency budget = full step.
// SPLITX=false (proj path): 2-buffer pipelined, full hi/lo precision kept.
// ---------------------------------------------------------------------------
template <bool SPLITX>
__global__ __launch_bounds__(256) void k_cmm(
    const float* __restrict__ Xf,
    const short* __restrict__ Xhi, const short* __restrict__ Xlo,
    const short* __restrict__ Whi, const short* __restrict__ Wlo,
    const float* __restrict__ bias, void* __restrict__ Outv, int Mtot)
{
  __shared__ short Ah[2][6144], Al[2][6144], Bh[2][4096], Bl[2][4096];
  const int t = threadIdx.x, lane = t & 63, w = t >> 6;
  const int lr = lane & 15, lq = lane >> 4;

  int bb, m0, n0;
  if constexpr (SPLITX) {
    const int flat = blockIdx.x;
    const int g = (flat & 7) * (gridDim.x >> 3) + (flat >> 3);
    bb = g / 384;
    const int rem = g % 384;
    m0 = (rem % 3) * 192;          // m fastest: trio shares X B-tile in L2
    n0 = (rem / 3) * 128;
  } else {
    bb = blockIdx.z; m0 = blockIdx.y * 192; n0 = blockIdx.x * 128;
  }

  const float* xf = nullptr;
  const short* xh = nullptr;
  const short* xl = nullptr;
  if constexpr (SPLITX) {
    xf = Xf + (size_t)bb * CDIM * HW;
  } else {
    xh = Xhi + (size_t)bb * 24 * HW * 8;
    xl = Xlo + (size_t)bb * 24 * HW * 8;
  }

  f32x4 acc[3][8] = {};

  if constexpr (SPLITX) {
    const int px = t & 127, kg0 = t >> 7;
    float bvA[2][8], bvB[2][8];        // B(k) in (k&1 ? bvB : bvA)

    // Prologue: B(0)->LDS buf0 (serial once); then A(0)x3 + B(1)x16 in flight
    CMM_LOADB(bvA, 0);
    asm volatile("s_waitcnt vmcnt(0)" ::: "memory");
    __builtin_amdgcn_sched_barrier(0);
    CMM_WRITEB1(bvA, 0);
    CMM_STAGEA1(0, 0);                 // queue: [A(0)x3]
    CMM_LOADB(bvB, 32);                // queue: [A(0)x3, B(1)x16]

    #pragma unroll
    for (int s = 0; s < 6; ++s) {
      const int cur = s & 1;
      // top: A(s) done; keep B(s+1)'s 16 loads in flight (s<5)
      if (s == 5) { asm volatile("s_waitcnt vmcnt(0) lgkmcnt(0)" ::: "memory"); }
      else        { asm volatile("s_waitcnt vmcnt(16) lgkmcnt(0)" ::: "memory"); }
      __builtin_amdgcn_s_barrier();
      __builtin_amdgcn_sched_barrier(0);

      bf16x8 ahf[3];
      #pragma unroll
      for (int mi = 0; mi < 3; ++mi)
        ahf[mi] = *(const bf16x8*)&Ah[cur][(w * 3 + mi) * 512 + lane * 8];
      if (s < 5) { CMM_STAGEA1((s + 1) << 5, cur ^ 1); }  // queue: [B(s+1)x16, A(s+1)x3]
      __builtin_amdgcn_sched_barrier(0);

      __builtin_amdgcn_s_setprio(1);
      #pragma unroll
      for (int j = 0; j < 8; ++j) {
        bf16x8 bsf = *(const bf16x8*)&Bh[cur][(lq * 128 + j * 16 + lr) * 8];
        #pragma unroll
        for (int mi = 0; mi < 3; ++mi)
          acc[mi][j] = __builtin_amdgcn_mfma_f32_16x16x32_bf16(ahf[mi], bsf, acc[mi][j], 0, 0, 0);
      }
      __builtin_amdgcn_s_setprio(0);
      if (s < 5) {
        __builtin_amdgcn_sched_barrier(0);
        asm volatile("s_waitcnt vmcnt(3)" ::: "memory");  // B(s+1) regs done; A(s+1) flying
        __builtin_amdgcn_sched_barrier(0);
        if ((s & 1) == 0) { CMM_WRITEB1(bvB, cur ^ 1); }  // B(s+1) odd -> bvB
        else              { CMM_WRITEB1(bvA, cur ^ 1); }
        if (s < 4) {                                      // B(s+2): full-step budget
          if ((s & 1) == 0) { CMM_LOADB(bvA, (s + 2) << 5); }  // B(s+2) even -> bvA
          else              { CMM_LOADB(bvB, (s + 2) << 5); }
        }
      }
    }
  } else {
    CMM_STAGE_PROJ(0, 0);
    for (int s = 0; s < 6; ++s) {
      const int cur = s & 1;
      asm volatile("s_waitcnt vmcnt(0) lgkmcnt(0)" ::: "memory");
      __builtin_amdgcn_s_barrier();
      __builtin_amdgcn_sched_barrier(0);

      bf16x8 ahf[3], alf[3];
      #pragma unroll
      for (int mi = 0; mi < 3; ++mi) {
        ahf[mi] = *(const bf16x8*)&Ah[cur][(w * 3 + mi) * 512 + lane * 8];
        alf[mi] = *(const bf16x8*)&Al[cur][(w * 3 + mi) * 512 + lane * 8];
      }
      if (s < 5) {
        __builtin_amdgcn_sched_barrier(0);
        CMM_STAGE_PROJ((s + 1) << 5, cur ^ 1);   // 10 gload_lds fly under MFMA
        __builtin_amdgcn_sched_barrier(0);
      }
      __builtin_amdgcn_s_setprio(1);
      #pragma unroll
      for (int j = 0; j < 8; ++j) {
        bf16x8 bhf = *(const bf16x8*)&Bh[cur][(lq * 128 + j * 16 + lr) * 8];
        bf16x8 blf = *(const bf16x8*)&Bl[cur][(lq * 128 + j * 16 + lr) * 8];
        #pragma unroll
        for (int mi = 0; mi < 3; ++mi) {
          acc[mi][j] = __builtin_amdgcn_mfma_f32_16x16x32_bf16(ahf[mi], bhf, acc[mi][j], 0, 0, 0);
          acc[mi][j] = __builtin_amdgcn_mfma_f32_16x16x32_bf16(ahf[mi], blf, acc[mi][j], 0, 0, 0);
          acc[mi][j] = __builtin_amdgcn_mfma_f32_16x16x32_bf16(alf[mi], bhf, acc[mi][j], 0, 0, 0);
        }
      }
      __builtin_amdgcn_s_setprio(0);
    }
  }

  #pragma unroll
  for (int mi = 0; mi < 3; ++mi) {
    #pragma unroll
    for (int r = 0; r < 4; ++r) {
      const int m = m0 + (w * 3 + mi) * 16 + lq * 4 + r;
      const float bv2 = bias[m];
      const size_t rowo = ((size_t)bb * Mtot + m) * HW + n0;
      #pragma unroll
      for (int j = 0; j < 8; ++j) {
        const int n = j * 16 + lr;
        if constexpr (SPLITX) {
          ((short*)Outv)[rowo + n] = to_bf16_rne(acc[mi][j][r] + bv2);
        } else {
          ((float*)Outv)[rowo + n] = acc[mi][j][r] + bv2;
        }
      }
    }
  }
}

// ---------------------------------------------------------------------------
// Depthwise 3x3 + bias + to_heads + norm.  (round-11 config, unchanged)
// ---------------------------------------------------------------------------
__global__ __launch_bounds__(256) void k_dw(
    const short* __restrict__ tmp,
    const float* __restrict__ dww, const float* __restrict__ dwb,
    short* __restrict__ Qb, short* __restrict__ Kb,
    short* __restrict__ Vt, int b0)
{
  __shared__ short img[16384];        // 128x128 bf16 = 32KB
  __shared__ short dwout[16 * 1040];  // padded rows: bank-conflict-free
  __shared__ float sums[16][64];
  __shared__ float rednorm[16];

  const int gc = blockIdx.x, lb = blockIdx.y, b = b0 + lb;
  const int sel = gc / CDIM, chl = gc % CDIM;
  const int head = chl / 48, c = chl % 48;
  const short* gimg = tmp + ((size_t)lb * 576 + gc) * HW;
  const int t = threadIdx.x;

  #pragma unroll
  for (int cch = 0; cch < 8; ++cch)
    gload_lds16(gimg + cch * 2048 + t * 8, img + cch * 2048 + t * 8);

  float wgt[9];
  #pragma unroll
  for (int i = 0; i < 9; ++i) wgt[i] = dww[gc * 9 + i];
  const float bias = dwb[gc];

  asm volatile("s_waitcnt vmcnt(0)" ::: "memory");
  __syncthreads();

  const int fy = (t >> 4) & 3;
  float sqp[4] = {0.f, 0.f, 0.f, 0.f};

  for (int i = 0; i < 8; ++i) {
    const int p8 = i * 2048 + t * 8;
    const int h = p8 >> 7, w0 = p8 & 127;
    float win[3][10];
    #pragma unroll
    for (int dy = 0; dy < 3; ++dy) {
      const int r = h + dy - 1;
      if (r < 0 || r > 127) {
        #pragma unroll
        for (int q = 0; q < 10; ++q) win[dy][q] = 0.f;
      } else {
        const short* rp = img + r * 128 + w0;
        short8 c8 = *(const short8*)rp;
        win[dy][0] = (w0 > 0) ? b2f(rp[-1]) : 0.f;
        #pragma unroll
        for (int q = 0; q < 8; ++q) win[dy][1 + q] = b2f(c8[q]);
        win[dy][9] = (w0 < 120) ? b2f(rp[8]) : 0.f;
      }
    }
    const int na = (h >> 2) * 32 + (w0 >> 2);
    #pragma unroll
    for (int fx = 0; fx < 4; ++fx) {
      float a0 = bias, a1 = bias;
      #pragma unroll
      for (int dy = 0; dy < 3; ++dy)
        #pragma unroll
        for (int dx = 0; dx < 3; ++dx) {
          a0 = fmaf(win[dy][fx + dx], wgt[dy * 3 + dx], a0);
          a1 = fmaf(win[dy][4 + fx + dx], wgt[dy * 3 + dx], a1);
        }
      sqp[fx] = fmaf(a0, a0, sqp[fx]);
      sqp[fx] = fmaf(a1, a1, sqp[fx]);
      *(unsigned*)&dwout[(fx * 4 + fy) * 1040 + na] =
          ((unsigned)(unsigned short)to_bf16_rne(a1) << 16) |
          (unsigned short)to_bf16_rne(a0);
    }
  }

  if (sel < 2) {
    const int slot = (t & 15) | ((t >> 6) << 4);
    #pragma unroll
    for (int fx = 0; fx < 4; ++fx) sums[fx * 4 + fy][slot] = sqp[fx];
    __syncthreads();
    const int row = t >> 4, i16 = t & 15;
    float v = sums[row][i16] + sums[row][i16 + 16] + sums[row][i16 + 32] + sums[row][i16 + 48];
    __syncthreads();
    sums[row][i16] = v;
    __syncthreads();
    if (t < 16) {
      float s = 0.f;
      #pragma unroll
      for (int j = 0; j < 16; ++j) s += sums[t][j];
      rednorm[t] = fmaxf(sqrtf(s), 1e-12f);
    }
  } else {
    __syncthreads();
  }
  __syncthreads();

  if (sel == 2) {
    #pragma unroll
    for (int j = 0; j < 4; ++j) {
      const int n = t + j * 256;
      short8 v0, v1;
      #pragma unroll
      for (int rr = 0; rr < 8; ++rr) v0[rr] = dwout[rr * 1040 + n];
      #pragma unroll
      for (int rr = 0; rr < 8; ++rr) v1[rr] = dwout[(rr + 8) * 1040 + n];
      const size_t o = ((size_t)(b * 4 + head) * 1024 + n) * 768 + c * 16;
      *(short8*)&Vt[o] = v0;
      *(short8*)&Vt[o + 8] = v1;
    }
    return;
  }

  short* dst = (sel == 0) ? Qb : Kb;
  #pragma unroll
  for (int rr = 0; rr < 16; ++rr) {
    const float inv = 1.0f / rednorm[rr];
    const size_t rowoff = ((size_t)(b * 4 + head) * 768 + c * 16 + rr) * 1024;
    #pragma unroll
    for (int j = 0; j < 2; ++j) {
      const int n2 = j * 512 + t * 2;
      const unsigned pk = *(const unsigned*)&dwout[rr * 1040 + n2];
      const float v0 = b2f((short)(pk & 0xffffu)) * inv;
      const float v1 = b2f((short)(pk >> 16)) * inv;
      *(unsigned*)&dst[rowoff + n2] =
          ((unsigned)(unsigned short)to_bf16_rne(v1) << 16) | (unsigned short)to_bf16_rne(v0);
    }
  }
}

// ---------------------------------------------------------------------------
// E = exp(Q*K^T * temp).  192x256 tile, 512 threads (8 waves 2m x 4n).
// 3-buffer counted-vmcnt pipeline (vmcnt(4) steady, 0 only last step),
// single barrier per step — the measured optimum.
// ---------------------------------------------------------------------------
__global__ __launch_bounds__(512) void k_qk(
    const short* __restrict__ Qb, const short* __restrict__ Kbf,
    const float* __restrict__ temp,
    short* __restrict__ E, float* __restrict__ Sums)
{
  __shared__ short lds[3][14336];   // 3 x 28KB
  const int t = threadIdx.x, lane = t & 63, w = t >> 6;
  const int lr = lane & 15, lq = lane >> 4;

  const int flat = blockIdx.x;
  const int g = (flat & 7) * 48 + (flat >> 3);     // bijection on [0,384)
  const int bh = g / 12, tile = g % 12;
  const int m0 = (tile / 3) * 192, n0 = (tile % 3) * 256;
  const size_t base = (size_t)bh * 768 * 1024;

  f32x4 acc[6][4] = {};
  const int wm = (w >> 2) * 6, wn = (w & 3) * 4;

  const short* gsrc[4]; size_t goff[4]; int gdst[4]; bool gok[4];
  #pragma unroll
  for (int ii = 0; ii < 4; ++ii) {
    const int id = w * 4 + ii;                     // 0..31; 28..31 unused
    gok[ii] = (id < 28);
    const bool isq = (id < 12);
    gsrc[ii] = isq ? Qb : Kbf;
    const int row = isq ? (m0 + id * 16) : (n0 + (id - 12) * 16);
    goff[ii] = base + (size_t)(row + lr) * 1024 + lq * 8;
    gdst[ii] = (id < 28 ? id : 0) * 512;
  }
  #define QK_STAGE(buf, k0)                                                   \
    { _Pragma("unroll")                                                       \
      for (int ii = 0; ii < 4; ++ii)                                          \
        if (gok[ii]) gload_lds16(gsrc[ii] + goff[ii] + (k0), &lds[buf][gdst[ii]]); }

  QK_STAGE(0, 0);
  QK_STAGE(1, 32);

  for (int step = 0; step < 32; ++step) {
    const int cur = step % 3;
    if (step == 31) { asm volatile("s_waitcnt vmcnt(0)" ::: "memory"); }
    else            { asm volatile("s_waitcnt vmcnt(4)" ::: "memory"); }
    __builtin_amdgcn_s_barrier();
    __builtin_amdgcn_sched_barrier(0);

    bf16x8 ah[6], bf_[4];
    #pragma unroll
    for (int i = 0; i < 6; ++i)
      ah[i] = *(const bf16x8*)&lds[cur][(wm + i) * 512 + lane * 8];
    #pragma unroll
    for (int j = 0; j < 4; ++j)
      bf_[j] = *(const bf16x8*)&lds[cur][(12 + wn + j) * 512 + lane * 8];

    if (step < 30) QK_STAGE((step + 2) % 3, (step + 2) << 5);

    asm volatile("s_waitcnt lgkmcnt(0)" ::: "memory");
    __builtin_amdgcn_sched_barrier(0);
    __builtin_amdgcn_s_setprio(1);
    #pragma unroll
    for (int i = 0; i < 6; ++i)
      #pragma unroll
      for (int j = 0; j < 4; ++j)
        acc[i][j] = __builtin_amdgcn_mfma_f32_16x16x32_bf16(ah[i], bf_[j], acc[i][j], 0, 0, 0);
    __builtin_amdgcn_s_setprio(0);
    __builtin_amdgcn_sched_barrier(0);
  }
  #undef QK_STAGE

  const float tp = temp[bh & 3];
  float* Srow = Sums + bh * 768;
  short* Ep = E + (size_t)bh * 768 * 768;
  #pragma unroll
  for (int i = 0; i < 6; ++i) {
    #pragma unroll
    for (int r = 0; r < 4; ++r) {
      const int m = m0 + (w >> 2) * 96 + i * 16 + lq * 4 + r;
      short* erow = Ep + (size_t)m * 768 + n0 + (w & 3) * 64;
      float rs = 0.f;
      #pragma unroll
      for (int j = 0; j < 4; ++j) {
        const float e = expf(acc[i][j][r] * tp);
        rs += e;
        erow[j * 16 + lr] = to_bf16_rne(e);
      }
      rs += __shfl_xor(rs, 1);
      rs += __shfl_xor(rs, 2);
      rs += __shfl_xor(rs, 4);
      rs += __shfl_xor(rs, 8);
      if (lr == 0) atomicAdd(&Srow[m], rs);
    }
  }
}

// ---------------------------------------------------------------------------
// O = (E * V) / (sum+1).  256x256 tile, 512 threads.
// 3-buffer counted-vmcnt pipeline (vmcnt(4) steady), single barrier/step.
// ---------------------------------------------------------------------------
__global__ __launch_bounds__(512) void k_av(
    const short* __restrict__ Ebf, const short* __restrict__ Vtb,
    const float* __restrict__ Sums,
    short* __restrict__ Phi, short* __restrict__ Plo)
{
  __shared__ short lds[3][16384];   // 3 x 32KB
  const int t = threadIdx.x, lane = t & 63, w = t >> 6;
  const int lr = lane & 15, lq = lane >> 4;

  const int flat = blockIdx.x;
  const int g = (flat & 7) * 48 + (flat >> 3);     // bijection on [0,384)
  const int bh = g / 12, tile = g % 12;
  const int m0 = (tile / 4) * 256, n0 = (tile % 4) * 256;
  const int head = bh & 3, b = bh >> 2;
  const short* Sp = Ebf + (size_t)bh * 768 * 768;
  const short* Vp = Vtb + (size_t)bh * 1024 * 768;

  f32x4 acc[8][4] = {};
  const int wm = (w >> 2) * 8, wn = (w & 3) * 4;

  const short* gsrc[4]; size_t goff[4]; int gdst[4];
  #pragma unroll
  for (int ii = 0; ii < 4; ++ii) {
    const int id = w * 4 + ii;                     // 0..31
    const int arr = id >> 4, s = id & 15;
    gsrc[ii] = arr ? Vp : Sp;
    const int row = (arr ? n0 : m0) + s * 16;
    goff[ii] = (size_t)(row + lr) * 768 + lq * 8;
    gdst[ii] = id * 512;
  }
  #define AV_STAGE(buf, k0)                                                   \
    { _Pragma("unroll")                                                       \
      for (int ii = 0; ii < 4; ++ii)                                          \
        gload_lds16(gsrc[ii] + goff[ii] + (k0), &lds[buf][gdst[ii]]); }

  AV_STAGE(0, 0);
  AV_STAGE(1, 32);

  for (int step = 0; step < 24; ++step) {
    const int cur = step % 3;
    if (step == 23) { asm volatile("s_waitcnt vmcnt(0)" ::: "memory"); }
    else            { asm volatile("s_waitcnt vmcnt(4)" ::: "memory"); }
    __builtin_amdgcn_s_barrier();
    __builtin_amdgcn_sched_barrier(0);

    bf16x8 ea[8], vb[4];
    #pragma unroll
    for (int i = 0; i < 8; ++i)
      ea[i] = *(const bf16x8*)&lds[cur][(wm + i) * 512 + lane * 8];
    #pragma unroll
    for (int j = 0; j < 4; ++j)
      vb[j] = *(const bf16x8*)&lds[cur][(16 + wn + j) * 512 + lane * 8];

    if (step < 22) AV_STAGE((step + 2) % 3, (step + 2) << 5);

    asm volatile("s_waitcnt lgkmcnt(0)" ::: "memory");
    __builtin_amdgcn_sched_barrier(0);
    __builtin_amdgcn_s_setprio(1);
    #pragma unroll
    for (int i = 0; i < 8; ++i)
      #pragma unroll
      for (int j = 0; j < 4; ++j)
        acc[i][j] = __builtin_amdgcn_mfma_f32_16x16x32_bf16(ea[i], vb[j], acc[i][j], 0, 0, 0);
    __builtin_amdgcn_s_setprio(0);
    __builtin_amdgcn_sched_barrier(0);
  }
  #undef AV_STAGE

  // ---- scale by 1/(sum+1) in-register ----
  const float* Srow = Sums + bh * 768;
  float invv[8][4];
  #pragma unroll
  for (int i = 0; i < 8; ++i)
    #pragma unroll
    for (int r = 0; r < 4; ++r) {
      const int d = m0 + (w >> 2) * 128 + i * 16 + lq * 4 + r;
      invv[i][r] = 1.0f / (Srow[d] + 1.0f);
    }
  #pragma unroll
  for (int i = 0; i < 8; ++i)
    #pragma unroll
    for (int j = 0; j < 4; ++j)
      #pragma unroll
      for (int r = 0; r < 4; ++r)
        acc[i][j][r] *= invv[i][r];

  // ---- LDS-staged coalesced epilogue: 4 passes of one 64KB chunk each ----
  short* stg = &lds[0][0];                         // 32768 shorts = 64KB
  const int kcp0 = head * 6 + (m0 >> 7);
  const int myc = w >> 2;

  #pragma unroll
  for (int a = 0; a < 2; ++a) {
    #pragma unroll
    for (int c = 0; c < 2; ++c) {
      __syncthreads();   // protect vs prior reads of stg
      if (myc == c) {
        #pragma unroll
        for (int j = 0; j < 4; ++j) {
          const int nl = (w & 3) * 64 + j * 16 + lr;
          #pragma unroll
          for (int r = 0; r < 4; ++r) {
            short8 s8;
            #pragma unroll
            for (int i = 0; i < 8; ++i) {
              const float v = acc[i][j][r];
              const unsigned u = __float_as_uint(v);
              if (a == 0) {
                s8[i] = (short)(u >> 16);
              } else {
                const float res = v - __uint_as_float(u & 0xffff0000u);
                s8[i] = (short)(__float_as_uint(res) >> 16);
              }
            }
            const int loff = (((nl >> 5) * 4 + r) * 128 + (nl & 31) * 4 + lq) * 8;
            *(short8*)&stg[loff] = s8;
          }
        }
      }
      __syncthreads();
      short* dst = (a ? Plo : Phi) +
                   ((size_t)(b * 24 + kcp0 + c) * HW + n0 * 16) * 8;
      #pragma unroll
      for (int it = 0; it < 8; ++it) {
        const int idx = it * 4096 + t * 8;
        *(short8*)&dst[idx] = *(const short8*)&stg[idx];
      }
    }
  }
}

// ---------------------------------------------------------------------------
extern "C" void kernel_launch(void* const* d_in, const int* in_sizes, int n_in,
                              void* d_out, int out_size, void* d_ws, size_t ws_size,
                              hipStream_t stream) {
  const float* x      = (const float*)d_in[0];
  const float* qkv_w  = (const float*)d_in[1];
  const float* qkv_b  = (const float*)d_in[2];
  const float* dw_w   = (const float*)d_in[3];
  const float* dw_b   = (const float*)d_in[4];
  const float* proj_w = (const float*)d_in[5];
  const float* proj_b = (const float*)d_in[6];
  const float* temp   = (const float*)d_in[7];
  float* out = (float*)d_out;

  float* F = (float*)d_ws;
  const size_t M25 = (size_t)8 * CDIM * HW;      // 25,165,824 elements
  short* Qb  = (short*)F;                         // [0, 50.3M)
  short* Plo = Qb + M25;                          // [50.3, 100.7M)
  short* Kb  = (short*)(F + M25);                 // [100.7, 151M)
  short* Vt  = Kb + M25;                          // [151, 201.3M)
  short* Ebf = (short*)(F + 2 * M25);             // [201.3, 239M)  (37.7MB)
  short* Phi = Qb;                                // alias Q (dead after qk)

  // tmpf (BF16) aliases the Ebf region onward: dead before k_qk writes E.
  short* tmpf = Ebf;
  const size_t ebfBytes  = (size_t)32 * 768 * 768 * 2;       // 37.75 MB
  const size_t baseBytes = 2 * M25 * 4;                      // 201.3 MB
  const size_t wsTailBytes = 294912 * 2 + 32 * 768 * 4 + 256; // weights+Sums
  int bpi = 2;
  for (int cand = 8; cand >= 2; cand >>= 1) {
    const size_t tmpfBytes = (size_t)cand * 576 * HW * 2;
    const size_t need = baseBytes + (tmpfBytes > ebfBytes ? tmpfBytes : ebfBytes)
                      + wsTailBytes;
    if (ws_size >= need) { bpi = cand; break; }
  }
  const size_t tmpfBytes = (size_t)bpi * 576 * HW * 2;
  short* WS = (short*)((char*)d_ws + baseBytes +
                       (tmpfBytes > ebfBytes ? tmpfBytes : ebfBytes));
  short* Wq_hi = WS;             // 576*192
  short* Wq_lo = WS + 110592;
  short* Wp_hi = WS + 221184;    // 192*192
  short* Wp_lo = WS + 258048;
  float* Sums  = (float*)(WS + 294912);           // 32*768 floats

  k_split_w<<<dim3(432), 256, 0, stream>>>(qkv_w, Wq_hi, Wq_lo, 110592);
  k_split_w<<<dim3(144), 256, 0, stream>>>(proj_w, Wp_hi, Wp_lo, 36864);
  k_zero<<<dim3(96), 256, 0, stream>>>(Sums, 32 * 768);

  for (int b0 = 0; b0 < 8; b0 += bpi) {
    k_cmm<true><<<dim3(384 * bpi), 256, 0, stream>>>(
        x + (size_t)b0 * CDIM * HW, nullptr, nullptr,
        Wq_hi, Wq_lo, qkv_b, tmpf, 576);
    k_dw<<<dim3(576, bpi), 256, 0, stream>>>(
        tmpf, dw_w, dw_b, Qb, Kb, Vt, b0);
  }

  k_qk<<<dim3(384), 512, 0, stream>>>(Qb, Kb, temp, Ebf, Sums);
  k_av<<<dim3(384), 512, 0, stream>>>(Ebf, Vt, Sums, Phi, Plo);
  k_cmm<false><<<dim3(128, 1, 8), 256, 0, stream>>>(
      nullptr, Phi, Plo, Wp_hi, Wp_lo, proj_b, out, 192);
}

// Round 21
// 533.504 us; speedup vs baseline: 1.0904x; 1.0032x over previous
//
#include <hip/hip_runtime.h>

#define HW 16384   // 128*128
#define CDIM 192

typedef short bf16x8 __attribute__((ext_vector_type(8)));
typedef short short8 __attribute__((ext_vector_type(8)));
typedef float f32x4  __attribute__((ext_vector_type(4)));

__device__ inline void gload_lds16(const void* g, void* l) {
  __builtin_amdgcn_global_load_lds(
      (const __attribute__((address_space(1))) void*)g,
      (__attribute__((address_space(3))) void*)l, 16, 0, 0);
}

__device__ inline short to_bf16_rne(float f) {
  unsigned u = __float_as_uint(f);
  unsigned r = u + 0x7fffu + ((u >> 16) & 1u);
  return (short)(r >> 16);
}

__device__ inline float b2f(short s) {
  return __uint_as_float(((unsigned)(unsigned short)s) << 16);
}

__device__ inline void split_bf16(float a, short& hi, short& lo) {
  unsigned u = __float_as_uint(a);
  hi = (short)(u >> 16);                       // truncated high part
  float res = a - __uint_as_float(u & 0xffff0000u);
  lo = (short)(__float_as_uint(res) >> 16);    // residual; pair accurate to ~2^-17
}

// ---------------------------------------------------------------------------
__global__ __launch_bounds__(256) void k_zero(float* __restrict__ p, int n) {
  int i = blockIdx.x * 256 + threadIdx.x;
  if (i < n) p[i] = 0.f;
}

// ---------------------------------------------------------------------------
__global__ __launch_bounds__(256) void k_split_w(
    const float* __restrict__ W, short* __restrict__ hi,
    short* __restrict__ lo, int n)
{
  int i = blockIdx.x * 256 + threadIdx.x;
  if (i < n) { short h, l; split_bf16(W[i], h, l); hi[i] = h; lo[i] = l; }
}

// ---------------------------------------------------------------------------
// qkv 1x1-conv GEMM: 192x256 tile, 512 threads (8 waves as 4m x 2n).
// NEW: n-tile 128->256 halves the m-trio X re-read (603 -> 301 MB on the
// ~5.6 TB/s L3 path k_cmm was pinned at).  Per-wave structure deliberately
// mirrors the proven R19 kernel (3 m-frags x 8 n-frags, acc[3][8], bv[2][8])
// so VGPR stays ~112.  Single-bf16 operands (precision ladder, 4x verified
// bit-identical absmax).  R19 pipeline: 2-buffer, single barrier/step, B
// regs one step ahead (LOADB issued at step top), counted mid-wait.
// A = 12 W-frags staged 2-per-wave by waves 0..5; per-wave vmcnt:
//   w<6: queue [B x16, A x2] -> mid vmcnt(2);  w>=6: [B x16] -> vmcnt(0).
// LDS: Ah 2x12KB + Bh 2x16KB = 56KB -> 2 blocks/CU at <=128 VGPR.
// ---------------------------------------------------------------------------
__global__ __launch_bounds__(512) void k_cmm_qkv(
    const float* __restrict__ Xf, const short* __restrict__ Whi,
    const float* __restrict__ bias, short* __restrict__ Out)
{
  __shared__ short Ah[2][6144];      // 12 frags x 512 shorts
  __shared__ short Bh[2][8192];      // 4 kc x 256 px x 8 shorts
  const int t = threadIdx.x, lane = t & 63, w = t >> 6;
  const int lr = lane & 15, lq = lane >> 4;
  const int wrow = w >> 1, wcol = w & 1;        // 4m x 2n wave grid
  const int px = t & 255, kg0 = t >> 8;

  const int flat = blockIdx.x;
  const int g = (flat & 7) * (gridDim.x >> 3) + (flat >> 3);  // XCD-affine
  const int bb = g / 192;
  const int rem = g % 192;
  const int m0 = (rem % 3) * 192;    // m fastest: trio shares X slab in L2
  const int n0 = (rem / 3) * 256;
  const float* xf = Xf + (size_t)bb * CDIM * HW;

  f32x4 acc[3][8] = {};
  float bv[2][8];

#define QKV_LOADB(k0)                                                         \
  { _Pragma("unroll")                                                         \
    for (int kk = 0; kk < 2; ++kk) {                                          \
      const int kcg = kg0 * 2 + kk;                                           \
      _Pragma("unroll")                                                       \
      for (int j = 0; j < 8; ++j)                                             \
        bv[kk][j] = xf[(size_t)((k0) + kcg * 8 + j) * HW + n0 + px];          \
    } }

#define QKV_STAGEA(k0, b)                                                     \
  if (w < 6) {                                                                \
    _Pragma("unroll")                                                         \
    for (int ii = 0; ii < 2; ++ii) {                                          \
      const int mf = w * 2 + ii;               /* 0..11 */                    \
      const short* gp = Whi + (size_t)(m0 + mf * 16 + lr) * CDIM + (k0) + lq * 8; \
      gload_lds16(gp, Ah[b] + mf * 512);                                      \
    } }

#define QKV_WRITEB(b)                                                         \
  { _Pragma("unroll")                                                         \
    for (int kk = 0; kk < 2; ++kk) {                                          \
      const int kcg = kg0 * 2 + kk;                                           \
      short8 s8;                                                              \
      _Pragma("unroll")                                                       \
      for (int j = 0; j < 8; ++j) s8[j] = to_bf16_rne(bv[kk][j]);             \
      *(short8*)&Bh[b][(kcg * 256 + px) * 8] = s8;                            \
    } }

  QKV_LOADB(0);
  QKV_STAGEA(0, 0);
  if (w < 6) { asm volatile("s_waitcnt vmcnt(2)" ::: "memory"); }
  else       { asm volatile("s_waitcnt vmcnt(0)" ::: "memory"); }
  __builtin_amdgcn_sched_barrier(0);
  QKV_WRITEB(0);

  #pragma unroll
  for (int s = 0; s < 6; ++s) {
    const int cur = s & 1;
    asm volatile("s_waitcnt vmcnt(0) lgkmcnt(0)" ::: "memory");
    __builtin_amdgcn_s_barrier();
    __builtin_amdgcn_sched_barrier(0);

    if (s < 5) { QKV_LOADB((s + 1) << 5); }   // X loads first: max headroom
    bf16x8 ahf[3];
    #pragma unroll
    for (int mi = 0; mi < 3; ++mi)
      ahf[mi] = *(const bf16x8*)&Ah[cur][(wrow * 3 + mi) * 512 + lane * 8];
    if (s < 5) { QKV_STAGEA((s + 1) << 5, cur ^ 1); }
    __builtin_amdgcn_sched_barrier(0);

    __builtin_amdgcn_s_setprio(1);
    #pragma unroll
    for (int j = 0; j < 8; ++j) {
      bf16x8 bsf = *(const bf16x8*)&Bh[cur][(lq * 256 + wcol * 128 + j * 16 + lr) * 8];
      #pragma unroll
      for (int mi = 0; mi < 3; ++mi)
        acc[mi][j] = __builtin_amdgcn_mfma_f32_16x16x32_bf16(ahf[mi], bsf, acc[mi][j], 0, 0, 0);
    }
    __builtin_amdgcn_s_setprio(0);
    if (s < 5) {
      __builtin_amdgcn_sched_barrier(0);
      if (w < 6) { asm volatile("s_waitcnt vmcnt(2)" ::: "memory"); }  // B done, A flying
      else       { asm volatile("s_waitcnt vmcnt(0)" ::: "memory"); }
      __builtin_amdgcn_sched_barrier(0);
      QKV_WRITEB(cur ^ 1);
    }
  }
#undef QKV_LOADB
#undef QKV_STAGEA
#undef QKV_WRITEB

  #pragma unroll
  for (int mi = 0; mi < 3; ++mi) {
    #pragma unroll
    for (int r = 0; r < 4; ++r) {
      const int m = m0 + (wrow * 3 + mi) * 16 + lq * 4 + r;
      const float bv2 = bias[m];
      const size_t rowo = ((size_t)bb * 576 + m) * HW + n0;
      #pragma unroll
      for (int j = 0; j < 8; ++j)
        Out[rowo + wcol * 128 + j * 16 + lr] = to_bf16_rne(acc[mi][j][r] + bv2);
    }
  }
}

// ---------------------------------------------------------------------------
// proj GEMM: 192x128 tile, 256 threads, hi/lo precision, fp32 out.
// (round-15 pipelined structure, unchanged)
// ---------------------------------------------------------------------------
__global__ __launch_bounds__(256) void k_cmm_proj(
    const short* __restrict__ Xhi, const short* __restrict__ Xlo,
    const short* __restrict__ Whi, const short* __restrict__ Wlo,
    const float* __restrict__ bias, float* __restrict__ Out, int Mtot)
{
  __shared__ short Ah[2][6144], Al[2][6144], Bh[2][4096], Bl[2][4096];
  const int t = threadIdx.x, lane = t & 63, w = t >> 6;
  const int lr = lane & 15, lq = lane >> 4;
  const int bb = blockIdx.z, m0 = blockIdx.y * 192, n0 = blockIdx.x * 128;
  const short* xh = Xhi + (size_t)bb * 24 * HW * 8;
  const short* xl = Xlo + (size_t)bb * 24 * HW * 8;

  f32x4 acc[3][8] = {};

#define PROJ_STAGE(k0, b)                                                     \
  { _Pragma("unroll")                                                         \
    for (int ii = 0; ii < 6; ++ii) {                                          \
      const int id = w * 6 + ii, arr = id / 12, mf = id % 12;                 \
      const short* Wp = arr ? Wlo : Whi;                                      \
      const short* gp = Wp + (size_t)(m0 + mf * 16 + lr) * CDIM + (k0) + lq * 8; \
      gload_lds16(gp, (arr ? Al[b] : Ah[b]) + mf * 512);                      \
    }                                                                         \
    _Pragma("unroll")                                                         \
    for (int ii = 0; ii < 4; ++ii) {                                          \
      const int id = w * 4 + ii, arr = id >> 3, sub = id & 7;                 \
      const int kc = sub >> 1, half = sub & 1;                                \
      const short* src = arr ? xl : xh;                                       \
      const short* gp = src + ((size_t)((k0) / 8 + kc) * HW + n0 + half * 64 + lane) * 8; \
      gload_lds16(gp, (arr ? Bl[b] : Bh[b]) + (kc * 128 + half * 64) * 8);    \
    } }

  PROJ_STAGE(0, 0);
  for (int s = 0; s < 6; ++s) {
    const int cur = s & 1;
    asm volatile("s_waitcnt vmcnt(0) lgkmcnt(0)" ::: "memory");
    __builtin_amdgcn_s_barrier();
    __builtin_amdgcn_sched_barrier(0);

    bf16x8 ahf[3], alf[3];
    #pragma unroll
    for (int mi = 0; mi < 3; ++mi) {
      ahf[mi] = *(const bf16x8*)&Ah[cur][(w * 3 + mi) * 512 + lane * 8];
      alf[mi] = *(const bf16x8*)&Al[cur][(w * 3 + mi) * 512 + lane * 8];
    }
    if (s < 5) {
      __builtin_amdgcn_sched_barrier(0);
      PROJ_STAGE((s + 1) << 5, cur ^ 1);   // 10 gload_lds fly under MFMA
      __builtin_amdgcn_sched_barrier(0);
    }
    __builtin_amdgcn_s_setprio(1);
    #pragma unroll
    for (int j = 0; j < 8; ++j) {
      bf16x8 bhf = *(const bf16x8*)&Bh[cur][(lq * 128 + j * 16 + lr) * 8];
      bf16x8 blf = *(const bf16x8*)&Bl[cur][(lq * 128 + j * 16 + lr) * 8];
      #pragma unroll
      for (int mi = 0; mi < 3; ++mi) {
        acc[mi][j] = __builtin_amdgcn_mfma_f32_16x16x32_bf16(ahf[mi], bhf, acc[mi][j], 0, 0, 0);
        acc[mi][j] = __builtin_amdgcn_mfma_f32_16x16x32_bf16(ahf[mi], blf, acc[mi][j], 0, 0, 0);
        acc[mi][j] = __builtin_amdgcn_mfma_f32_16x16x32_bf16(alf[mi], bhf, acc[mi][j], 0, 0, 0);
      }
    }
    __builtin_amdgcn_s_setprio(0);
  }
#undef PROJ_STAGE

  #pragma unroll
  for (int mi = 0; mi < 3; ++mi) {
    #pragma unroll
    for (int r = 0; r < 4; ++r) {
      const int m = m0 + (w * 3 + mi) * 16 + lq * 4 + r;
      const float bv2 = bias[m];
      const size_t rowo = ((size_t)bb * Mtot + m) * HW + n0;
      #pragma unroll
      for (int j = 0; j < 8; ++j)
        Out[rowo + j * 16 + lr] = acc[mi][j][r] + bv2;
    }
  }
}

// ---------------------------------------------------------------------------
// Depthwise 3x3 + bias + to_heads + norm.  (round-11 config, unchanged)
// ---------------------------------------------------------------------------
__global__ __launch_bounds__(256) void k_dw(
    const short* __restrict__ tmp,
    const float* __restrict__ dww, const float* __restrict__ dwb,
    short* __restrict__ Qb, short* __restrict__ Kb,
    short* __restrict__ Vt, int b0)
{
  __shared__ short img[16384];        // 128x128 bf16 = 32KB
  __shared__ short dwout[16 * 1040];  // padded rows: bank-conflict-free
  __shared__ float sums[16][64];
  __shared__ float rednorm[16];

  const int gc = blockIdx.x, lb = blockIdx.y, b = b0 + lb;
  const int sel = gc / CDIM, chl = gc % CDIM;
  const int head = chl / 48, c = chl % 48;
  const short* gimg = tmp + ((size_t)lb * 576 + gc) * HW;
  const int t = threadIdx.x;

  #pragma unroll
  for (int cch = 0; cch < 8; ++cch)
    gload_lds16(gimg + cch * 2048 + t * 8, img + cch * 2048 + t * 8);

  float wgt[9];
  #pragma unroll
  for (int i = 0; i < 9; ++i) wgt[i] = dww[gc * 9 + i];
  const float bias = dwb[gc];

  asm volatile("s_waitcnt vmcnt(0)" ::: "memory");
  __syncthreads();

  const int fy = (t >> 4) & 3;
  float sqp[4] = {0.f, 0.f, 0.f, 0.f};

  for (int i = 0; i < 8; ++i) {
    const int p8 = i * 2048 + t * 8;
    const int h = p8 >> 7, w0 = p8 & 127;
    float win[3][10];
    #pragma unroll
    for (int dy = 0; dy < 3; ++dy) {
      const int r = h + dy - 1;
      if (r < 0 || r > 127) {
        #pragma unroll
        for (int q = 0; q < 10; ++q) win[dy][q] = 0.f;
      } else {
        const short* rp = img + r * 128 + w0;
        short8 c8 = *(const short8*)rp;
        win[dy][0] = (w0 > 0) ? b2f(rp[-1]) : 0.f;
        #pragma unroll
        for (int q = 0; q < 8; ++q) win[dy][1 + q] = b2f(c8[q]);
        win[dy][9] = (w0 < 120) ? b2f(rp[8]) : 0.f;
      }
    }
    const int na = (h >> 2) * 32 + (w0 >> 2);
    #pragma unroll
    for (int fx = 0; fx < 4; ++fx) {
      float a0 = bias, a1 = bias;
      #pragma unroll
      for (int dy = 0; dy < 3; ++dy)
        #pragma unroll
        for (int dx = 0; dx < 3; ++dx) {
          a0 = fmaf(win[dy][fx + dx], wgt[dy * 3 + dx], a0);
          a1 = fmaf(win[dy][4 + fx + dx], wgt[dy * 3 + dx], a1);
        }
      sqp[fx] = fmaf(a0, a0, sqp[fx]);
      sqp[fx] = fmaf(a1, a1, sqp[fx]);
      *(unsigned*)&dwout[(fx * 4 + fy) * 1040 + na] =
          ((unsigned)(unsigned short)to_bf16_rne(a1) << 16) |
          (unsigned short)to_bf16_rne(a0);
    }
  }

  if (sel < 2) {
    const int slot = (t & 15) | ((t >> 6) << 4);
    #pragma unroll
    for (int fx = 0; fx < 4; ++fx) sums[fx * 4 + fy][slot] = sqp[fx];
    __syncthreads();
    const int row = t >> 4, i16 = t & 15;
    float v = sums[row][i16] + sums[row][i16 + 16] + sums[row][i16 + 32] + sums[row][i16 + 48];
    __syncthreads();
    sums[row][i16] = v;
    __syncthreads();
    if (t < 16) {
      float s = 0.f;
      #pragma unroll
      for (int j = 0; j < 16; ++j) s += sums[t][j];
      rednorm[t] = fmaxf(sqrtf(s), 1e-12f);
    }
  } else {
    __syncthreads();
  }
  __syncthreads();

  if (sel == 2) {
    #pragma unroll
    for (int j = 0; j < 4; ++j) {
      const int n = t + j * 256;
      short8 v0, v1;
      #pragma unroll
      for (int rr = 0; rr < 8; ++rr) v0[rr] = dwout[rr * 1040 + n];
      #pragma unroll
      for (int rr = 0; rr < 8; ++rr) v1[rr] = dwout[(rr + 8) * 1040 + n];
      const size_t o = ((size_t)(b * 4 + head) * 1024 + n) * 768 + c * 16;
      *(short8*)&Vt[o] = v0;
      *(short8*)&Vt[o + 8] = v1;
    }
    return;
  }

  short* dst = (sel == 0) ? Qb : Kb;
  #pragma unroll
  for (int rr = 0; rr < 16; ++rr) {
    const float inv = 1.0f / rednorm[rr];
    const size_t rowoff = ((size_t)(b * 4 + head) * 768 + c * 16 + rr) * 1024;
    #pragma unroll
    for (int j = 0; j < 2; ++j) {
      const int n2 = j * 512 + t * 2;
      const unsigned pk = *(const unsigned*)&dwout[rr * 1040 + n2];
      const float v0 = b2f((short)(pk & 0xffffu)) * inv;
      const float v1 = b2f((short)(pk >> 16)) * inv;
      *(unsigned*)&dst[rowoff + n2] =
          ((unsigned)(unsigned short)to_bf16_rne(v1) << 16) | (unsigned short)to_bf16_rne(v0);
    }
  }
}

// ---------------------------------------------------------------------------
// E = exp(Q*K^T * temp).  192x256 tile, 512 threads (8 waves 2m x 4n).
// 3-buffer counted-vmcnt pipeline (vmcnt(4) steady, 0 only last step),
// single barrier per step — the measured optimum.
// ---------------------------------------------------------------------------
__global__ __launch_bounds__(512) void k_qk(
    const short* __restrict__ Qb, const short* __restrict__ Kbf,
    const float* __restrict__ temp,
    short* __restrict__ E, float* __restrict__ Sums)
{
  __shared__ short lds[3][14336];   // 3 x 28KB
  const int t = threadIdx.x, lane = t & 63, w = t >> 6;
  const int lr = lane & 15, lq = lane >> 4;

  const int flat = blockIdx.x;
  const int g = (flat & 7) * 48 + (flat >> 3);     // bijection on [0,384)
  const int bh = g / 12, tile = g % 12;
  const int m0 = (tile / 3) * 192, n0 = (tile % 3) * 256;
  const size_t base = (size_t)bh * 768 * 1024;

  f32x4 acc[6][4] = {};
  const int wm = (w >> 2) * 6, wn = (w & 3) * 4;

  const short* gsrc[4]; size_t goff[4]; int gdst[4]; bool gok[4];
  #pragma unroll
  for (int ii = 0; ii < 4; ++ii) {
    const int id = w * 4 + ii;                     // 0..31; 28..31 unused
    gok[ii] = (id < 28);
    const bool isq = (id < 12);
    gsrc[ii] = isq ? Qb : Kbf;
    const int row = isq ? (m0 + id * 16) : (n0 + (id - 12) * 16);
    goff[ii] = base + (size_t)(row + lr) * 1024 + lq * 8;
    gdst[ii] = (id < 28 ? id : 0) * 512;
  }
  #define QK_STAGE(buf, k0)                                                   \
    { _Pragma("unroll")                                                       \
      for (int ii = 0; ii < 4; ++ii)                                          \
        if (gok[ii]) gload_lds16(gsrc[ii] + goff[ii] + (k0), &lds[buf][gdst[ii]]); }

  QK_STAGE(0, 0);
  QK_STAGE(1, 32);

  for (int step = 0; step < 32; ++step) {
    const int cur = step % 3;
    if (step == 31) { asm volatile("s_waitcnt vmcnt(0)" ::: "memory"); }
    else            { asm volatile("s_waitcnt vmcnt(4)" ::: "memory"); }
    __builtin_amdgcn_s_barrier();
    __builtin_amdgcn_sched_barrier(0);

    bf16x8 ah[6], bf_[4];
    #pragma unroll
    for (int i = 0; i < 6; ++i)
      ah[i] = *(const bf16x8*)&lds[cur][(wm + i) * 512 + lane * 8];
    #pragma unroll
    for (int j = 0; j < 4; ++j)
      bf_[j] = *(const bf16x8*)&lds[cur][(12 + wn + j) * 512 + lane * 8];

    if (step < 30) QK_STAGE((step + 2) % 3, (step + 2) << 5);

    asm volatile("s_waitcnt lgkmcnt(0)" ::: "memory");
    __builtin_amdgcn_sched_barrier(0);
    __builtin_amdgcn_s_setprio(1);
    #pragma unroll
    for (int i = 0; i < 6; ++i)
      #pragma unroll
      for (int j = 0; j < 4; ++j)
        acc[i][j] = __builtin_amdgcn_mfma_f32_16x16x32_bf16(ah[i], bf_[j], acc[i][j], 0, 0, 0);
    __builtin_amdgcn_s_setprio(0);
    __builtin_amdgcn_sched_barrier(0);
  }
  #undef QK_STAGE

  const float tp = temp[bh & 3];
  float* Srow = Sums + bh * 768;
  short* Ep = E + (size_t)bh * 768 * 768;
  #pragma unroll
  for (int i = 0; i < 6; ++i) {
    #pragma unroll
    for (int r = 0; r < 4; ++r) {
      const int m = m0 + (w >> 2) * 96 + i * 16 + lq * 4 + r;
      short* erow = Ep + (size_t)m * 768 + n0 + (w & 3) * 64;
      float rs = 0.f;
      #pragma unroll
      for (int j = 0; j < 4; ++j) {
        const float e = expf(acc[i][j][r] * tp);
        rs += e;
        erow[j * 16 + lr] = to_bf16_rne(e);
      }
      rs += __shfl_xor(rs, 1);
      rs += __shfl_xor(rs, 2);
      rs += __shfl_xor(rs, 4);
      rs += __shfl_xor(rs, 8);
      if (lr == 0) atomicAdd(&Srow[m], rs);
    }
  }
}

// ---------------------------------------------------------------------------
// O = (E * V) / (sum+1).  256x256 tile, 512 threads.
// 3-buffer counted-vmcnt pipeline (vmcnt(4) steady), single barrier/step.
// ---------------------------------------------------------------------------
__global__ __launch_bounds__(512) void k_av(
    const short* __restrict__ Ebf, const short* __restrict__ Vtb,
    const float* __restrict__ Sums,
    short* __restrict__ Phi, short* __restrict__ Plo)
{
  __shared__ short lds[3][16384];   // 3 x 32KB
  const int t = threadIdx.x, lane = t & 63, w = t >> 6;
  const int lr = lane & 15, lq = lane >> 4;

  const int flat = blockIdx.x;
  const int g = (flat & 7) * 48 + (flat >> 3);     // bijection on [0,384)
  const int bh = g / 12, tile = g % 12;
  const int m0 = (tile / 4) * 256, n0 = (tile % 4) * 256;
  const int head = bh & 3, b = bh >> 2;
  const short* Sp = Ebf + (size_t)bh * 768 * 768;
  const short* Vp = Vtb + (size_t)bh * 1024 * 768;

  f32x4 acc[8][4] = {};
  const int wm = (w >> 2) * 8, wn = (w & 3) * 4;

  const short* gsrc[4]; size_t goff[4]; int gdst[4];
  #pragma unroll
  for (int ii = 0; ii < 4; ++ii) {
    const int id = w * 4 + ii;                     // 0..31
    const int arr = id >> 4, s = id & 15;
    gsrc[ii] = arr ? Vp : Sp;
    const int row = (arr ? n0 : m0) + s * 16;
    goff[ii] = (size_t)(row + lr) * 768 + lq * 8;
    gdst[ii] = id * 512;
  }
  #define AV_STAGE(buf, k0)                                                   \
    { _Pragma("unroll")                                                       \
      for (int ii = 0; ii < 4; ++ii)                                          \
        gload_lds16(gsrc[ii] + goff[ii] + (k0), &lds[buf][gdst[ii]]); }

  AV_STAGE(0, 0);
  AV_STAGE(1, 32);

  for (int step = 0; step < 24; ++step) {
    const int cur = step % 3;
    if (step == 23) { asm volatile("s_waitcnt vmcnt(0)" ::: "memory"); }
    else            { asm volatile("s_waitcnt vmcnt(4)" ::: "memory"); }
    __builtin_amdgcn_s_barrier();
    __builtin_amdgcn_sched_barrier(0);

    bf16x8 ea[8], vb[4];
    #pragma unroll
    for (int i = 0; i < 8; ++i)
      ea[i] = *(const bf16x8*)&lds[cur][(wm + i) * 512 + lane * 8];
    #pragma unroll
    for (int j = 0; j < 4; ++j)
      vb[j] = *(const bf16x8*)&lds[cur][(16 + wn + j) * 512 + lane * 8];

    if (step < 22) AV_STAGE((step + 2) % 3, (step + 2) << 5);

    asm volatile("s_waitcnt lgkmcnt(0)" ::: "memory");
    __builtin_amdgcn_sched_barrier(0);
    __builtin_amdgcn_s_setprio(1);
    #pragma unroll
    for (int i = 0; i < 8; ++i)
      #pragma unroll
      for (int j = 0; j < 4; ++j)
        acc[i][j] = __builtin_amdgcn_mfma_f32_16x16x32_bf16(ea[i], vb[j], acc[i][j], 0, 0, 0);
    __builtin_amdgcn_s_setprio(0);
    __builtin_amdgcn_sched_barrier(0);
  }
  #undef AV_STAGE

  // ---- scale by 1/(sum+1) in-register ----
  const float* Srow = Sums + bh * 768;
  float invv[8][4];
  #pragma unroll
  for (int i = 0; i < 8; ++i)
    #pragma unroll
    for (int r = 0; r < 4; ++r) {
      const int d = m0 + (w >> 2) * 128 + i * 16 + lq * 4 + r;
      invv[i][r] = 1.0f / (Srow[d] + 1.0f);
    }
  #pragma unroll
  for (int i = 0; i < 8; ++i)
    #pragma unroll
    for (int j = 0; j < 4; ++j)
      #pragma unroll
      for (int r = 0; r < 4; ++r)
        acc[i][j][r] *= invv[i][r];

  // ---- LDS-staged coalesced epilogue: 4 passes of one 64KB chunk each ----
  short* stg = &lds[0][0];                         // 32768 shorts = 64KB
  const int kcp0 = head * 6 + (m0 >> 7);
  const int myc = w >> 2;

  #pragma unroll
  for (int a = 0; a < 2; ++a) {
    #pragma unroll
    for (int c = 0; c < 2; ++c) {
      __syncthreads();   // protect vs prior reads of stg
      if (myc == c) {
        #pragma unroll
        for (int j = 0; j < 4; ++j) {
          const int nl = (w & 3) * 64 + j * 16 + lr;
          #pragma unroll
          for (int r = 0; r < 4; ++r) {
            short8 s8;
            #pragma unroll
            for (int i = 0; i < 8; ++i) {
              const float v = acc[i][j][r];
              const unsigned u = __float_as_uint(v);
              if (a == 0) {
                s8[i] = (short)(u >> 16);
              } else {
                const float res = v - __uint_as_float(u & 0xffff0000u);
                s8[i] = (short)(__float_as_uint(res) >> 16);
              }
            }
            const int loff = (((nl >> 5) * 4 + r) * 128 + (nl & 31) * 4 + lq) * 8;
            *(short8*)&stg[loff] = s8;
          }
        }
      }
      __syncthreads();
      short* dst = (a ? Plo : Phi) +
                   ((size_t)(b * 24 + kcp0 + c) * HW + n0 * 16) * 8;
      #pragma unroll
      for (int it = 0; it < 8; ++it) {
        const int idx = it * 4096 + t * 8;
        *(short8*)&dst[idx] = *(const short8*)&stg[idx];
      }
    }
  }
}

// ---------------------------------------------------------------------------
extern "C" void kernel_launch(void* const* d_in, const int* in_sizes, int n_in,
                              void* d_out, int out_size, void* d_ws, size_t ws_size,
                              hipStream_t stream) {
  const float* x      = (const float*)d_in[0];
  const float* qkv_w  = (const float*)d_in[1];
  const float* qkv_b  = (const float*)d_in[2];
  const float* dw_w   = (const float*)d_in[3];
  const float* dw_b   = (const float*)d_in[4];
  const float* proj_w = (const float*)d_in[5];
  const float* proj_b = (const float*)d_in[6];
  const float* temp   = (const float*)d_in[7];
  float* out = (float*)d_out;

  float* F = (float*)d_ws;
  const size_t M25 = (size_t)8 * CDIM * HW;      // 25,165,824 elements
  short* Qb  = (short*)F;                         // [0, 50.3M)
  short* Plo = Qb + M25;                          // [50.3, 100.7M)
  short* Kb  = (short*)(F + M25);                 // [100.7, 151M)
  short* Vt  = Kb + M25;                          // [151, 201.3M)
  short* Ebf = (short*)(F + 2 * M25);             // [201.3, 239M)  (37.7MB)
  short* Phi = Qb;                                // alias Q (dead after qk)

  // tmpf (BF16) aliases the Ebf region onward: dead before k_qk writes E.
  short* tmpf = Ebf;
  const size_t ebfBytes  = (size_t)32 * 768 * 768 * 2;       // 37.75 MB
  const size_t baseBytes = 2 * M25 * 4;                      // 201.3 MB
  const size_t wsTailBytes = 294912 * 2 + 32 * 768 * 4 + 256; // weights+Sums
  int bpi = 2;
  for (int cand = 8; cand >= 2; cand >>= 1) {
    const size_t tmpfBytes = (size_t)cand * 576 * HW * 2;
    const size_t need = baseBytes + (tmpfBytes > ebfBytes ? tmpfBytes : ebfBytes)
                      + wsTailBytes;
    if (ws_size >= need) { bpi = cand; break; }
  }
  const size_t tmpfBytes = (size_t)bpi * 576 * HW * 2;
  short* WS = (short*)((char*)d_ws + baseBytes +
                       (tmpfBytes > ebfBytes ? tmpfBytes : ebfBytes));
  short* Wq_hi = WS;             // 576*192
  short* Wq_lo = WS + 110592;
  short* Wp_hi = WS + 221184;    // 192*192
  short* Wp_lo = WS + 258048;
  float* Sums  = (float*)(WS + 294912);           // 32*768 floats

  k_split_w<<<dim3(432), 256, 0, stream>>>(qkv_w, Wq_hi, Wq_lo, 110592);
  k_split_w<<<dim3(144), 256, 0, stream>>>(proj_w, Wp_hi, Wp_lo, 36864);
  k_zero<<<dim3(96), 256, 0, stream>>>(Sums, 32 * 768);

  for (int b0 = 0; b0 < 8; b0 += bpi) {
    k_cmm_qkv<<<dim3(192 * bpi), 512, 0, stream>>>(
        x + (size_t)b0 * CDIM * HW, Wq_hi, qkv_b, tmpf);
    k_dw<<<dim3(576, bpi), 256, 0, stream>>>(
        tmpf, dw_w, dw_b, Qb, Kb, Vt, b0);
  }

  k_qk<<<dim3(384), 512, 0, stream>>>(Qb, Kb, temp, Ebf, Sums);
  k_av<<<dim3(384), 512, 0, stream>>>(Ebf, Vt, Sums, Phi, Plo);
  k_cmm_proj<<<dim3(128, 1, 8), 256, 0, stream>>>(
      Phi, Plo, Wp_hi, Wp_lo, proj_b, out, 192);
}

// Round 22
// 522.593 us; speedup vs baseline: 1.1132x; 1.0209x over previous
//
#include <hip/hip_runtime.h>

#define HW 16384   // 128*128
#define CDIM 192

typedef short bf16x8 __attribute__((ext_vector_type(8)));
typedef short short8 __attribute__((ext_vector_type(8)));
typedef float f32x4  __attribute__((ext_vector_type(4)));

__device__ inline void gload_lds16(const void* g, void* l) {
  __builtin_amdgcn_global_load_lds(
      (const __attribute__((address_space(1))) void*)g,
      (__attribute__((address_space(3))) void*)l, 16, 0, 0);
}

__device__ inline short to_bf16_rne(float f) {
  unsigned u = __float_as_uint(f);
  unsigned r = u + 0x7fffu + ((u >> 16) & 1u);
  return (short)(r >> 16);
}

__device__ inline float b2f(short s) {
  return __uint_as_float(((unsigned)(unsigned short)s) << 16);
}

__device__ inline void split_bf16(float a, short& hi, short& lo) {
  unsigned u = __float_as_uint(a);
  hi = (short)(u >> 16);                       // truncated high part
  float res = a - __uint_as_float(u & 0xffff0000u);
  lo = (short)(__float_as_uint(res) >> 16);    // residual; pair accurate to ~2^-17
}

// ---------------------------------------------------------------------------
__global__ __launch_bounds__(256) void k_zero(float* __restrict__ p, int n) {
  int i = blockIdx.x * 256 + threadIdx.x;
  if (i < n) p[i] = 0.f;
}

// ---------------------------------------------------------------------------
__global__ __launch_bounds__(256) void k_split_w(
    const float* __restrict__ W, short* __restrict__ hi,
    short* __restrict__ lo, int n)
{
  int i = blockIdx.x * 256 + threadIdx.x;
  if (i < n) { short h, l; split_bf16(W[i], h, l); hi[i] = h; lo[i] = l; }
}

// ---------------------------------------------------------------------------
// qkv 1x1-conv GEMM: 192x256 tile, 512 threads (8 waves as 4m x 2n).
// R21 config + NEW deep-B: B regs TWO steps ahead (bvA/bvB ping-pong).
// LOADB(s+2) issued after WRITEB(s+1) -> B gets a FULL-step latency budget
// (was: issued at step top, awaited mid-step = only the MFMA phase).  R20
// proved this transform at 128-tile (+6us); its only failure mode (VGPR>128,
// R14) can't occur here: base 84 + 16 = ~100.  Queue (in-order): enter step
// s with [A(s)x2 (w<6), B(s+1)x16] -> top vmcnt(16)+lgkm(0); STAGEA(s+1) ->
// [B(s+1)x16, A(s+1)x2]; mid vmcnt(2)/vmcnt(0); WRITEB(s+1); LOADB(s+2).
// LDS: Ah 2x12KB + Bh 2x16KB = 56KB -> 2 blocks/CU.
// ---------------------------------------------------------------------------
__global__ __launch_bounds__(512) void k_cmm_qkv(
    const float* __restrict__ Xf, const short* __restrict__ Whi,
    const float* __restrict__ bias, short* __restrict__ Out)
{
  __shared__ short Ah[2][6144];      // 12 frags x 512 shorts
  __shared__ short Bh[2][8192];      // 4 kc x 256 px x 8 shorts
  const int t = threadIdx.x, lane = t & 63, w = t >> 6;
  const int lr = lane & 15, lq = lane >> 4;
  const int wrow = w >> 1, wcol = w & 1;        // 4m x 2n wave grid
  const int px = t & 255, kg0 = t >> 8;

  const int flat = blockIdx.x;
  const int g = (flat & 7) * (gridDim.x >> 3) + (flat >> 3);  // XCD-affine
  const int bb = g / 192;
  const int rem = g % 192;
  const int m0 = (rem % 3) * 192;    // m fastest: trio shares X slab in L2
  const int n0 = (rem / 3) * 256;
  const float* xf = Xf + (size_t)bb * CDIM * HW;

  f32x4 acc[3][8] = {};
  float bvA[2][8], bvB[2][8];        // B(k) in (k&1 ? bvB : bvA)

#define QKV_LOADB(bv, k0)                                                     \
  { _Pragma("unroll")                                                         \
    for (int kk = 0; kk < 2; ++kk) {                                          \
      const int kcg = kg0 * 2 + kk;                                           \
      _Pragma("unroll")                                                       \
      for (int j = 0; j < 8; ++j)                                             \
        bv[kk][j] = xf[(size_t)((k0) + kcg * 8 + j) * HW + n0 + px];          \
    } }

#define QKV_STAGEA(k0, b)                                                     \
  if (w < 6) {                                                                \
    _Pragma("unroll")                                                         \
    for (int ii = 0; ii < 2; ++ii) {                                          \
      const int mf = w * 2 + ii;               /* 0..11 */                    \
      const short* gp = Whi + (size_t)(m0 + mf * 16 + lr) * CDIM + (k0) + lq * 8; \
      gload_lds16(gp, Ah[b] + mf * 512);                                      \
    } }

#define QKV_WRITEB(bv, b)                                                     \
  { _Pragma("unroll")                                                         \
    for (int kk = 0; kk < 2; ++kk) {                                          \
      const int kcg = kg0 * 2 + kk;                                           \
      short8 s8;                                                              \
      _Pragma("unroll")                                                       \
      for (int j = 0; j < 8; ++j) s8[j] = to_bf16_rne(bv[kk][j]);             \
      *(short8*)&Bh[b][(kcg * 256 + px) * 8] = s8;                            \
    } }

  // Prologue: B(0)->LDS buf0 (serial once); then A(0)x2 + B(1)x16 in flight
  QKV_LOADB(bvA, 0);
  asm volatile("s_waitcnt vmcnt(0)" ::: "memory");
  __builtin_amdgcn_sched_barrier(0);
  QKV_WRITEB(bvA, 0);
  QKV_STAGEA(0, 0);                  // queue: [A(0)x2] (w<6)
  QKV_LOADB(bvB, 32);                // queue: [A(0)x2, B(1)x16]

  #pragma unroll
  for (int s = 0; s < 6; ++s) {
    const int cur = s & 1;
    // top: A(s) done; keep B(s+1)'s 16 loads in flight (s<5)
    if (s == 5) { asm volatile("s_waitcnt vmcnt(0) lgkmcnt(0)" ::: "memory"); }
    else        { asm volatile("s_waitcnt vmcnt(16) lgkmcnt(0)" ::: "memory"); }
    __builtin_amdgcn_s_barrier();
    __builtin_amdgcn_sched_barrier(0);

    bf16x8 ahf[3];
    #pragma unroll
    for (int mi = 0; mi < 3; ++mi)
      ahf[mi] = *(const bf16x8*)&Ah[cur][(wrow * 3 + mi) * 512 + lane * 8];
    if (s < 5) { QKV_STAGEA((s + 1) << 5, cur ^ 1); }  // queue: [B(s+1)x16, A(s+1)x2]
    __builtin_amdgcn_sched_barrier(0);

    __builtin_amdgcn_s_setprio(1);
    #pragma unroll
    for (int j = 0; j < 8; ++j) {
      bf16x8 bsf = *(const bf16x8*)&Bh[cur][(lq * 256 + wcol * 128 + j * 16 + lr) * 8];
      #pragma unroll
      for (int mi = 0; mi < 3; ++mi)
        acc[mi][j] = __builtin_amdgcn_mfma_f32_16x16x32_bf16(ahf[mi], bsf, acc[mi][j], 0, 0, 0);
    }
    __builtin_amdgcn_s_setprio(0);
    if (s < 5) {
      __builtin_amdgcn_sched_barrier(0);
      // mid: B(s+1) regs done; A(s+1) (w<6) stays in flight
      if (w < 6) { asm volatile("s_waitcnt vmcnt(2)" ::: "memory"); }
      else       { asm volatile("s_waitcnt vmcnt(0)" ::: "memory"); }
      __builtin_amdgcn_sched_barrier(0);
      if ((s & 1) == 0) { QKV_WRITEB(bvB, cur ^ 1); }   // B(s+1) odd -> bvB
      else              { QKV_WRITEB(bvA, cur ^ 1); }
      if (s < 4) {                                      // B(s+2): full-step budget
        if ((s & 1) == 0) { QKV_LOADB(bvA, (s + 2) << 5); }
        else              { QKV_LOADB(bvB, (s + 2) << 5); }
      }
    }
  }
#undef QKV_LOADB
#undef QKV_STAGEA
#undef QKV_WRITEB

  #pragma unroll
  for (int mi = 0; mi < 3; ++mi) {
    #pragma unroll
    for (int r = 0; r < 4; ++r) {
      const int m = m0 + (wrow * 3 + mi) * 16 + lq * 4 + r;
      const float bv2 = bias[m];
      const size_t rowo = ((size_t)bb * 576 + m) * HW + n0;
      #pragma unroll
      for (int j = 0; j < 8; ++j)
        Out[rowo + wcol * 128 + j * 16 + lr] = to_bf16_rne(acc[mi][j][r] + bv2);
    }
  }
}

// ---------------------------------------------------------------------------
// proj GEMM: 192x128 tile, 256 threads, hi/lo precision, fp32 out.
// (round-15 pipelined structure, unchanged)
// ---------------------------------------------------------------------------
__global__ __launch_bounds__(256) void k_cmm_proj(
    const short* __restrict__ Xhi, const short* __restrict__ Xlo,
    const short* __restrict__ Whi, const short* __restrict__ Wlo,
    const float* __restrict__ bias, float* __restrict__ Out, int Mtot)
{
  __shared__ short Ah[2][6144], Al[2][6144], Bh[2][4096], Bl[2][4096];
  const int t = threadIdx.x, lane = t & 63, w = t >> 6;
  const int lr = lane & 15, lq = lane >> 4;
  const int bb = blockIdx.z, m0 = blockIdx.y * 192, n0 = blockIdx.x * 128;
  const short* xh = Xhi + (size_t)bb * 24 * HW * 8;
  const short* xl = Xlo + (size_t)bb * 24 * HW * 8;

  f32x4 acc[3][8] = {};

#define PROJ_STAGE(k0, b)                                                     \
  { _Pragma("unroll")                                                         \
    for (int ii = 0; ii < 6; ++ii) {                                          \
      const int id = w * 6 + ii, arr = id / 12, mf = id % 12;                 \
      const short* Wp = arr ? Wlo : Whi;                                      \
      const short* gp = Wp + (size_t)(m0 + mf * 16 + lr) * CDIM + (k0) + lq * 8; \
      gload_lds16(gp, (arr ? Al[b] : Ah[b]) + mf * 512);                      \
    }                                                                         \
    _Pragma("unroll")                                                         \
    for (int ii = 0; ii < 4; ++ii) {                                          \
      const int id = w * 4 + ii, arr = id >> 3, sub = id & 7;                 \
      const int kc = sub >> 1, half = sub & 1;                                \
      const short* src = arr ? xl : xh;                                       \
      const short* gp = src + ((size_t)((k0) / 8 + kc) * HW + n0 + half * 64 + lane) * 8; \
      gload_lds16(gp, (arr ? Bl[b] : Bh[b]) + (kc * 128 + half * 64) * 8);    \
    } }

  PROJ_STAGE(0, 0);
  for (int s = 0; s < 6; ++s) {
    const int cur = s & 1;
    asm volatile("s_waitcnt vmcnt(0) lgkmcnt(0)" ::: "memory");
    __builtin_amdgcn_s_barrier();
    __builtin_amdgcn_sched_barrier(0);

    bf16x8 ahf[3], alf[3];
    #pragma unroll
    for (int mi = 0; mi < 3; ++mi) {
      ahf[mi] = *(const bf16x8*)&Ah[cur][(w * 3 + mi) * 512 + lane * 8];
      alf[mi] = *(const bf16x8*)&Al[cur][(w * 3 + mi) * 512 + lane * 8];
    }
    if (s < 5) {
      __builtin_amdgcn_sched_barrier(0);
      PROJ_STAGE((s + 1) << 5, cur ^ 1);   // 10 gload_lds fly under MFMA
      __builtin_amdgcn_sched_barrier(0);
    }
    __builtin_amdgcn_s_setprio(1);
    #pragma unroll
    for (int j = 0; j < 8; ++j) {
      bf16x8 bhf = *(const bf16x8*)&Bh[cur][(lq * 128 + j * 16 + lr) * 8];
      bf16x8 blf = *(const bf16x8*)&Bl[cur][(lq * 128 + j * 16 + lr) * 8];
      #pragma unroll
      for (int mi = 0; mi < 3; ++mi) {
        acc[mi][j] = __builtin_amdgcn_mfma_f32_16x16x32_bf16(ahf[mi], bhf, acc[mi][j], 0, 0, 0);
        acc[mi][j] = __builtin_amdgcn_mfma_f32_16x16x32_bf16(ahf[mi], blf, acc[mi][j], 0, 0, 0);
        acc[mi][j] = __builtin_amdgcn_mfma_f32_16x16x32_bf16(alf[mi], bhf, acc[mi][j], 0, 0, 0);
      }
    }
    __builtin_amdgcn_s_setprio(0);
  }
#undef PROJ_STAGE

  #pragma unroll
  for (int mi = 0; mi < 3; ++mi) {
    #pragma unroll
    for (int r = 0; r < 4; ++r) {
      const int m = m0 + (w * 3 + mi) * 16 + lq * 4 + r;
      const float bv2 = bias[m];
      const size_t rowo = ((size_t)bb * Mtot + m) * HW + n0;
      #pragma unroll
      for (int j = 0; j < 8; ++j)
        Out[rowo + j * 16 + lr] = acc[mi][j][r] + bv2;
    }
  }
}

// ---------------------------------------------------------------------------
// Depthwise 3x3 + bias + to_heads + norm.  (round-11 config, unchanged)
// ---------------------------------------------------------------------------
__global__ __launch_bounds__(256) void k_dw(
    const short* __restrict__ tmp,
    const float* __restrict__ dww, const float* __restrict__ dwb,
    short* __restrict__ Qb, short* __restrict__ Kb,
    short* __restrict__ Vt, int b0)
{
  __shared__ short img[16384];        // 128x128 bf16 = 32KB
  __shared__ short dwout[16 * 1040];  // padded rows: bank-conflict-free
  __shared__ float sums[16][64];
  __shared__ float rednorm[16];

  const int gc = blockIdx.x, lb = blockIdx.y, b = b0 + lb;
  const int sel = gc / CDIM, chl = gc % CDIM;
  const int head = chl / 48, c = chl % 48;
  const short* gimg = tmp + ((size_t)lb * 576 + gc) * HW;
  const int t = threadIdx.x;

  #pragma unroll
  for (int cch = 0; cch < 8; ++cch)
    gload_lds16(gimg + cch * 2048 + t * 8, img + cch * 2048 + t * 8);

  float wgt[9];
  #pragma unroll
  for (int i = 0; i < 9; ++i) wgt[i] = dww[gc * 9 + i];
  const float bias = dwb[gc];

  asm volatile("s_waitcnt vmcnt(0)" ::: "memory");
  __syncthreads();

  const int fy = (t >> 4) & 3;
  float sqp[4] = {0.f, 0.f, 0.f, 0.f};

  for (int i = 0; i < 8; ++i) {
    const int p8 = i * 2048 + t * 8;
    const int h = p8 >> 7, w0 = p8 & 127;
    float win[3][10];
    #pragma unroll
    for (int dy = 0; dy < 3; ++dy) {
      const int r = h + dy - 1;
      if (r < 0 || r > 127) {
        #pragma unroll
        for (int q = 0; q < 10; ++q) win[dy][q] = 0.f;
      } else {
        const short* rp = img + r * 128 + w0;
        short8 c8 = *(const short8*)rp;
        win[dy][0] = (w0 > 0) ? b2f(rp[-1]) : 0.f;
        #pragma unroll
        for (int q = 0; q < 8; ++q) win[dy][1 + q] = b2f(c8[q]);
        win[dy][9] = (w0 < 120) ? b2f(rp[8]) : 0.f;
      }
    }
    const int na = (h >> 2) * 32 + (w0 >> 2);
    #pragma unroll
    for (int fx = 0; fx < 4; ++fx) {
      float a0 = bias, a1 = bias;
      #pragma unroll
      for (int dy = 0; dy < 3; ++dy)
        #pragma unroll
        for (int dx = 0; dx < 3; ++dx) {
          a0 = fmaf(win[dy][fx + dx], wgt[dy * 3 + dx], a0);
          a1 = fmaf(win[dy][4 + fx + dx], wgt[dy * 3 + dx], a1);
        }
      sqp[fx] = fmaf(a0, a0, sqp[fx]);
      sqp[fx] = fmaf(a1, a1, sqp[fx]);
      *(unsigned*)&dwout[(fx * 4 + fy) * 1040 + na] =
          ((unsigned)(unsigned short)to_bf16_rne(a1) << 16) |
          (unsigned short)to_bf16_rne(a0);
    }
  }

  if (sel < 2) {
    const int slot = (t & 15) | ((t >> 6) << 4);
    #pragma unroll
    for (int fx = 0; fx < 4; ++fx) sums[fx * 4 + fy][slot] = sqp[fx];
    __syncthreads();
    const int row = t >> 4, i16 = t & 15;
    float v = sums[row][i16] + sums[row][i16 + 16] + sums[row][i16 + 32] + sums[row][i16 + 48];
    __syncthreads();
    sums[row][i16] = v;
    __syncthreads();
    if (t < 16) {
      float s = 0.f;
      #pragma unroll
      for (int j = 0; j < 16; ++j) s += sums[t][j];
      rednorm[t] = fmaxf(sqrtf(s), 1e-12f);
    }
  } else {
    __syncthreads();
  }
  __syncthreads();

  if (sel == 2) {
    #pragma unroll
    for (int j = 0; j < 4; ++j) {
      const int n = t + j * 256;
      short8 v0, v1;
      #pragma unroll
      for (int rr = 0; rr < 8; ++rr) v0[rr] = dwout[rr * 1040 + n];
      #pragma unroll
      for (int rr = 0; rr < 8; ++rr) v1[rr] = dwout[(rr + 8) * 1040 + n];
      const size_t o = ((size_t)(b * 4 + head) * 1024 + n) * 768 + c * 16;
      *(short8*)&Vt[o] = v0;
      *(short8*)&Vt[o + 8] = v1;
    }
    return;
  }

  short* dst = (sel == 0) ? Qb : Kb;
  #pragma unroll
  for (int rr = 0; rr < 16; ++rr) {
    const float inv = 1.0f / rednorm[rr];
    const size_t rowoff = ((size_t)(b * 4 + head) * 768 + c * 16 + rr) * 1024;
    #pragma unroll
    for (int j = 0; j < 2; ++j) {
      const int n2 = j * 512 + t * 2;
      const unsigned pk = *(const unsigned*)&dwout[rr * 1040 + n2];
      const float v0 = b2f((short)(pk & 0xffffu)) * inv;
      const float v1 = b2f((short)(pk >> 16)) * inv;
      *(unsigned*)&dst[rowoff + n2] =
          ((unsigned)(unsigned short)to_bf16_rne(v1) << 16) | (unsigned short)to_bf16_rne(v0);
    }
  }
}

// ---------------------------------------------------------------------------
// E = exp(Q*K^T * temp).  192x256 tile, 512 threads (8 waves 2m x 4n).
// 3-buffer counted-vmcnt pipeline (vmcnt(4) steady, 0 only last step),
// single barrier per step — the measured optimum.
// ---------------------------------------------------------------------------
__global__ __launch_bounds__(512) void k_qk(
    const short* __restrict__ Qb, const short* __restrict__ Kbf,
    const float* __restrict__ temp,
    short* __restrict__ E, float* __restrict__ Sums)
{
  __shared__ short lds[3][14336];   // 3 x 28KB
  const int t = threadIdx.x, lane = t & 63, w = t >> 6;
  const int lr = lane & 15, lq = lane >> 4;

  const int flat = blockIdx.x;
  const int g = (flat & 7) * 48 + (flat >> 3);     // bijection on [0,384)
  const int bh = g / 12, tile = g % 12;
  const int m0 = (tile / 3) * 192, n0 = (tile % 3) * 256;
  const size_t base = (size_t)bh * 768 * 1024;

  f32x4 acc[6][4] = {};
  const int wm = (w >> 2) * 6, wn = (w & 3) * 4;

  const short* gsrc[4]; size_t goff[4]; int gdst[4]; bool gok[4];
  #pragma unroll
  for (int ii = 0; ii < 4; ++ii) {
    const int id = w * 4 + ii;                     // 0..31; 28..31 unused
    gok[ii] = (id < 28);
    const bool isq = (id < 12);
    gsrc[ii] = isq ? Qb : Kbf;
    const int row = isq ? (m0 + id * 16) : (n0 + (id - 12) * 16);
    goff[ii] = base + (size_t)(row + lr) * 1024 + lq * 8;
    gdst[ii] = (id < 28 ? id : 0) * 512;
  }
  #define QK_STAGE(buf, k0)                                                   \
    { _Pragma("unroll")                                                       \
      for (int ii = 0; ii < 4; ++ii)                                          \
        if (gok[ii]) gload_lds16(gsrc[ii] + goff[ii] + (k0), &lds[buf][gdst[ii]]); }

  QK_STAGE(0, 0);
  QK_STAGE(1, 32);

  for (int step = 0; step < 32; ++step) {
    const int cur = step % 3;
    if (step == 31) { asm volatile("s_waitcnt vmcnt(0)" ::: "memory"); }
    else            { asm volatile("s_waitcnt vmcnt(4)" ::: "memory"); }
    __builtin_amdgcn_s_barrier();
    __builtin_amdgcn_sched_barrier(0);

    bf16x8 ah[6], bf_[4];
    #pragma unroll
    for (int i = 0; i < 6; ++i)
      ah[i] = *(const bf16x8*)&lds[cur][(wm + i) * 512 + lane * 8];
    #pragma unroll
    for (int j = 0; j < 4; ++j)
      bf_[j] = *(const bf16x8*)&lds[cur][(12 + wn + j) * 512 + lane * 8];

    if (step < 30) QK_STAGE((step + 2) % 3, (step + 2) << 5);

    asm volatile("s_waitcnt lgkmcnt(0)" ::: "memory");
    __builtin_amdgcn_sched_barrier(0);
    __builtin_amdgcn_s_setprio(1);
    #pragma unroll
    for (int i = 0; i < 6; ++i)
      #pragma unroll
      for (int j = 0; j < 4; ++j)
        acc[i][j] = __builtin_amdgcn_mfma_f32_16x16x32_bf16(ah[i], bf_[j], acc[i][j], 0, 0, 0);
    __builtin_amdgcn_s_setprio(0);
    __builtin_amdgcn_sched_barrier(0);
  }
  #undef QK_STAGE

  const float tp = temp[bh & 3];
  float* Srow = Sums + bh * 768;
  short* Ep = E + (size_t)bh * 768 * 768;
  #pragma unroll
  for (int i = 0; i < 6; ++i) {
    #pragma unroll
    for (int r = 0; r < 4; ++r) {
      const int m = m0 + (w >> 2) * 96 + i * 16 + lq * 4 + r;
      short* erow = Ep + (size_t)m * 768 + n0 + (w & 3) * 64;
      float rs = 0.f;
      #pragma unroll
      for (int j = 0; j < 4; ++j) {
        const float e = expf(acc[i][j][r] * tp);
        rs += e;
        erow[j * 16 + lr] = to_bf16_rne(e);
      }
      rs += __shfl_xor(rs, 1);
      rs += __shfl_xor(rs, 2);
      rs += __shfl_xor(rs, 4);
      rs += __shfl_xor(rs, 8);
      if (lr == 0) atomicAdd(&Srow[m], rs);
    }
  }
}

// ---------------------------------------------------------------------------
// O = (E * V) / (sum+1).  256x256 tile, 512 threads.
// 3-buffer counted-vmcnt pipeline (vmcnt(4) steady), single barrier/step.
// ---------------------------------------------------------------------------
__global__ __launch_bounds__(512) void k_av(
    const short* __restrict__ Ebf, const short* __restrict__ Vtb,
    const float* __restrict__ Sums,
    short* __restrict__ Phi, short* __restrict__ Plo)
{
  __shared__ short lds[3][16384];   // 3 x 32KB
  const int t = threadIdx.x, lane = t & 63, w = t >> 6;
  const int lr = lane & 15, lq = lane >> 4;

  const int flat = blockIdx.x;
  const int g = (flat & 7) * 48 + (flat >> 3);     // bijection on [0,384)
  const int bh = g / 12, tile = g % 12;
  const int m0 = (tile / 4) * 256, n0 = (tile % 4) * 256;
  const int head = bh & 3, b = bh >> 2;
  const short* Sp = Ebf + (size_t)bh * 768 * 768;
  const short* Vp = Vtb + (size_t)bh * 1024 * 768;

  f32x4 acc[8][4] = {};
  const int wm = (w >> 2) * 8, wn = (w & 3) * 4;

  const short* gsrc[4]; size_t goff[4]; int gdst[4];
  #pragma unroll
  for (int ii = 0; ii < 4; ++ii) {
    const int id = w * 4 + ii;                     // 0..31
    const int arr = id >> 4, s = id & 15;
    gsrc[ii] = arr ? Vp : Sp;
    const int row = (arr ? n0 : m0) + s * 16;
    goff[ii] = (size_t)(row + lr) * 768 + lq * 8;
    gdst[ii] = id * 512;
  }
  #define AV_STAGE(buf, k0)                                                   \
    { _Pragma("unroll")                                                       \
      for (int ii = 0; ii < 4; ++ii)                                          \
        gload_lds16(gsrc[ii] + goff[ii] + (k0), &lds[buf][gdst[ii]]); }

  AV_STAGE(0, 0);
  AV_STAGE(1, 32);

  for (int step = 0; step < 24; ++step) {
    const int cur = step % 3;
    if (step == 23) { asm volatile("s_waitcnt vmcnt(0)" ::: "memory"); }
    else            { asm volatile("s_waitcnt vmcnt(4)" ::: "memory"); }
    __builtin_amdgcn_s_barrier();
    __builtin_amdgcn_sched_barrier(0);

    bf16x8 ea[8], vb[4];
    #pragma unroll
    for (int i = 0; i < 8; ++i)
      ea[i] = *(const bf16x8*)&lds[cur][(wm + i) * 512 + lane * 8];
    #pragma unroll
    for (int j = 0; j < 4; ++j)
      vb[j] = *(const bf16x8*)&lds[cur][(16 + wn + j) * 512 + lane * 8];

    if (step < 22) AV_STAGE((step + 2) % 3, (step + 2) << 5);

    asm volatile("s_waitcnt lgkmcnt(0)" ::: "memory");
    __builtin_amdgcn_sched_barrier(0);
    __builtin_amdgcn_s_setprio(1);
    #pragma unroll
    for (int i = 0; i < 8; ++i)
      #pragma unroll
      for (int j = 0; j < 4; ++j)
        acc[i][j] = __builtin_amdgcn_mfma_f32_16x16x32_bf16(ea[i], vb[j], acc[i][j], 0, 0, 0);
    __builtin_amdgcn_s_setprio(0);
    __builtin_amdgcn_sched_barrier(0);
  }
  #undef AV_STAGE

  // ---- scale by 1/(sum+1) in-register ----
  const float* Srow = Sums + bh * 768;
  float invv[8][4];
  #pragma unroll
  for (int i = 0; i < 8; ++i)
    #pragma unroll
    for (int r = 0; r < 4; ++r) {
      const int d = m0 + (w >> 2) * 128 + i * 16 + lq * 4 + r;
      invv[i][r] = 1.0f / (Srow[d] + 1.0f);
    }
  #pragma unroll
  for (int i = 0; i < 8; ++i)
    #pragma unroll
    for (int j = 0; j < 4; ++j)
      #pragma unroll
      for (int r = 0; r < 4; ++r)
        acc[i][j][r] *= invv[i][r];

  // ---- LDS-staged coalesced epilogue: 4 passes of one 64KB chunk each ----
  short* stg = &lds[0][0];                         // 32768 shorts = 64KB
  const int kcp0 = head * 6 + (m0 >> 7);
  const int myc = w >> 2;

  #pragma unroll
  for (int a = 0; a < 2; ++a) {
    #pragma unroll
    for (int c = 0; c < 2; ++c) {
      __syncthreads();   // protect vs prior reads of stg
      if (myc == c) {
        #pragma unroll
        for (int j = 0; j < 4; ++j) {
          const int nl = (w & 3) * 64 + j * 16 + lr;
          #pragma unroll
          for (int r = 0; r < 4; ++r) {
            short8 s8;
            #pragma unroll
            for (int i = 0; i < 8; ++i) {
              const float v = acc[i][j][r];
              const unsigned u = __float_as_uint(v);
              if (a == 0) {
                s8[i] = (short)(u >> 16);
              } else {
                const float res = v - __uint_as_float(u & 0xffff0000u);
                s8[i] = (short)(__float_as_uint(res) >> 16);
              }
            }
            const int loff = (((nl >> 5) * 4 + r) * 128 + (nl & 31) * 4 + lq) * 8;
            *(short8*)&stg[loff] = s8;
          }
        }
      }
      __syncthreads();
      short* dst = (a ? Plo : Phi) +
                   ((size_t)(b * 24 + kcp0 + c) * HW + n0 * 16) * 8;
      #pragma unroll
      for (int it = 0; it < 8; ++it) {
        const int idx = it * 4096 + t * 8;
        *(short8*)&dst[idx] = *(const short8*)&stg[idx];
      }
    }
  }
}

// ---------------------------------------------------------------------------
extern "C" void kernel_launch(void* const* d_in, const int* in_sizes, int n_in,
                              void* d_out, int out_size, void* d_ws, size_t ws_size,
                              hipStream_t stream) {
  const float* x      = (const float*)d_in[0];
  const float* qkv_w  = (const float*)d_in[1];
  const float* qkv_b  = (const float*)d_in[2];
  const float* dw_w   = (const float*)d_in[3];
  const float* dw_b   = (const float*)d_in[4];
  const float* proj_w = (const float*)d_in[5];
  const float* proj_b = (const float*)d_in[6];
  const float* temp   = (const float*)d_in[7];
  float* out = (float*)d_out;

  float* F = (float*)d_ws;
  const size_t M25 = (size_t)8 * CDIM * HW;      // 25,165,824 elements
  short* Qb  = (short*)F;                         // [0, 50.3M)
  short* Plo = Qb + M25;                          // [50.3, 100.7M)
  short* Kb  = (short*)(F + M25);                 // [100.7, 151M)
  short* Vt  = Kb + M25;                          // [151, 201.3M)
  short* Ebf = (short*)(F + 2 * M25);             // [201.3, 239M)  (37.7MB)
  short* Phi = Qb;                                // alias Q (dead after qk)

  // tmpf (BF16) aliases the Ebf region onward: dead before k_qk writes E.
  short* tmpf = Ebf;
  const size_t ebfBytes  = (size_t)32 * 768 * 768 * 2;       // 37.75 MB
  const size_t baseBytes = 2 * M25 * 4;                      // 201.3 MB
  const size_t wsTailBytes = 294912 * 2 + 32 * 768 * 4 + 256; // weights+Sums
  int bpi = 2;
  for (int cand = 8; cand >= 2; cand >>= 1) {
    const size_t tmpfBytes = (size_t)cand * 576 * HW * 2;
    const size_t need = baseBytes + (tmpfBytes > ebfBytes ? tmpfBytes : ebfBytes)
                      + wsTailBytes;
    if (ws_size >= need) { bpi = cand; break; }
  }
  const size_t tmpfBytes = (size_t)bpi * 576 * HW * 2;
  short* WS = (short*)((char*)d_ws + baseBytes +
                       (tmpfBytes > ebfBytes ? tmpfBytes : ebfBytes));
  short* Wq_hi = WS;             // 576*192
  short* Wq_lo = WS + 110592;
  short* Wp_hi = WS + 221184;    // 192*192
  short* Wp_lo = WS + 258048;
  float* Sums  = (float*)(WS + 294912);           // 32*768 floats

  k_split_w<<<dim3(432), 256, 0, stream>>>(qkv_w, Wq_hi, Wq_lo, 110592);
  k_split_w<<<dim3(144), 256, 0, stream>>>(proj_w, Wp_hi, Wp_lo, 36864);
  k_zero<<<dim3(96), 256, 0, stream>>>(Sums, 32 * 768);

  for (int b0 = 0; b0 < 8; b0 += bpi) {
    k_cmm_qkv<<<dim3(192 * bpi), 512, 0, stream>>>(
        x + (size_t)b0 * CDIM * HW, Wq_hi, qkv_b, tmpf);
    k_dw<<<dim3(576, bpi), 256, 0, stream>>>(
        tmpf, dw_w, dw_b, Qb, Kb, Vt, b0);
  }

  k_qk<<<dim3(384), 512, 0, stream>>>(Qb, Kb, temp, Ebf, Sums);
  k_av<<<dim3(384), 512, 0, stream>>>(Ebf, Vt, Sums, Phi, Plo);
  k_cmm_proj<<<dim3(128, 1, 8), 256, 0, stream>>>(
      Phi, Plo, Wp_hi, Wp_lo, proj_b, out, 192);
}

// Round 23
// 513.302 us; speedup vs baseline: 1.1334x; 1.0181x over previous
//
#include <hip/hip_runtime.h>

#define HW 16384   // 128*128
#define CDIM 192

typedef short bf16x8 __attribute__((ext_vector_type(8)));
typedef short short8 __attribute__((ext_vector_type(8)));
typedef float f32x4  __attribute__((ext_vector_type(4)));

__device__ inline void gload_lds16(const void* g, void* l) {
  __builtin_amdgcn_global_load_lds(
      (const __attribute__((address_space(1))) void*)g,
      (__attribute__((address_space(3))) void*)l, 16, 0, 0);
}

__device__ inline short to_bf16_rne(float f) {
  unsigned u = __float_as_uint(f);
  unsigned r = u + 0x7fffu + ((u >> 16) & 1u);
  return (short)(r >> 16);
}

__device__ inline float b2f(short s) {
  return __uint_as_float(((unsigned)(unsigned short)s) << 16);
}

__device__ inline void split_bf16(float a, short& hi, short& lo) {
  unsigned u = __float_as_uint(a);
  hi = (short)(u >> 16);                       // truncated high part
  float res = a - __uint_as_float(u & 0xffff0000u);
  lo = (short)(__float_as_uint(res) >> 16);    // residual; pair accurate to ~2^-17
}

// ---------------------------------------------------------------------------
__global__ __launch_bounds__(256) void k_zero(float* __restrict__ p, int n) {
  int i = blockIdx.x * 256 + threadIdx.x;
  if (i < n) p[i] = 0.f;
}

// ---------------------------------------------------------------------------
__global__ __launch_bounds__(256) void k_split_w(
    const float* __restrict__ W, short* __restrict__ hi,
    short* __restrict__ lo, int n)
{
  int i = blockIdx.x * 256 + threadIdx.x;
  if (i < n) { short h, l; split_bf16(W[i], h, l); hi[i] = h; lo[i] = l; }
}

// ---------------------------------------------------------------------------
// qkv 1x1-conv GEMM: 192x256 tile, 512 threads (8 waves as 4m x 2n).
// Deep-B pipeline (R22 measured best: 98us, VGPR 84).
// ---------------------------------------------------------------------------
__global__ __launch_bounds__(512) void k_cmm_qkv(
    const float* __restrict__ Xf, const short* __restrict__ Whi,
    const float* __restrict__ bias, short* __restrict__ Out)
{
  __shared__ short Ah[2][6144];      // 12 frags x 512 shorts
  __shared__ short Bh[2][8192];      // 4 kc x 256 px x 8 shorts
  const int t = threadIdx.x, lane = t & 63, w = t >> 6;
  const int lr = lane & 15, lq = lane >> 4;
  const int wrow = w >> 1, wcol = w & 1;        // 4m x 2n wave grid
  const int px = t & 255, kg0 = t >> 8;

  const int flat = blockIdx.x;
  const int g = (flat & 7) * (gridDim.x >> 3) + (flat >> 3);  // XCD-affine
  const int bb = g / 192;
  const int rem = g % 192;
  const int m0 = (rem % 3) * 192;    // m fastest: trio shares X slab in L2
  const int n0 = (rem / 3) * 256;
  const float* xf = Xf + (size_t)bb * CDIM * HW;

  f32x4 acc[3][8] = {};
  float bvA[2][8], bvB[2][8];        // B(k) in (k&1 ? bvB : bvA)

#define QKV_LOADB(bv, k0)                                                     \
  { _Pragma("unroll")                                                         \
    for (int kk = 0; kk < 2; ++kk) {                                          \
      const int kcg = kg0 * 2 + kk;                                           \
      _Pragma("unroll")                                                       \
      for (int j = 0; j < 8; ++j)                                             \
        bv[kk][j] = xf[(size_t)((k0) + kcg * 8 + j) * HW + n0 + px];          \
    } }

#define QKV_STAGEA(k0, b)                                                     \
  if (w < 6) {                                                                \
    _Pragma("unroll")                                                         \
    for (int ii = 0; ii < 2; ++ii) {                                          \
      const int mf = w * 2 + ii;               /* 0..11 */                    \
      const short* gp = Whi + (size_t)(m0 + mf * 16 + lr) * CDIM + (k0) + lq * 8; \
      gload_lds16(gp, Ah[b] + mf * 512);                                      \
    } }

#define QKV_WRITEB(bv, b)                                                     \
  { _Pragma("unroll")                                                         \
    for (int kk = 0; kk < 2; ++kk) {                                          \
      const int kcg = kg0 * 2 + kk;                                           \
      short8 s8;                                                              \
      _Pragma("unroll")                                                       \
      for (int j = 0; j < 8; ++j) s8[j] = to_bf16_rne(bv[kk][j]);             \
      *(short8*)&Bh[b][(kcg * 256 + px) * 8] = s8;                            \
    } }

  // Prologue: B(0)->LDS buf0 (serial once); then A(0)x2 + B(1)x16 in flight
  QKV_LOADB(bvA, 0);
  asm volatile("s_waitcnt vmcnt(0)" ::: "memory");
  __builtin_amdgcn_sched_barrier(0);
  QKV_WRITEB(bvA, 0);
  QKV_STAGEA(0, 0);                  // queue: [A(0)x2] (w<6)
  QKV_LOADB(bvB, 32);                // queue: [A(0)x2, B(1)x16]

  #pragma unroll
  for (int s = 0; s < 6; ++s) {
    const int cur = s & 1;
    // top: A(s) done; keep B(s+1)'s 16 loads in flight (s<5)
    if (s == 5) { asm volatile("s_waitcnt vmcnt(0) lgkmcnt(0)" ::: "memory"); }
    else        { asm volatile("s_waitcnt vmcnt(16) lgkmcnt(0)" ::: "memory"); }
    __builtin_amdgcn_s_barrier();
    __builtin_amdgcn_sched_barrier(0);

    bf16x8 ahf[3];
    #pragma unroll
    for (int mi = 0; mi < 3; ++mi)
      ahf[mi] = *(const bf16x8*)&Ah[cur][(wrow * 3 + mi) * 512 + lane * 8];
    if (s < 5) { QKV_STAGEA((s + 1) << 5, cur ^ 1); }  // queue: [B(s+1)x16, A(s+1)x2]
    __builtin_amdgcn_sched_barrier(0);

    __builtin_amdgcn_s_setprio(1);
    #pragma unroll
    for (int j = 0; j < 8; ++j) {
      bf16x8 bsf = *(const bf16x8*)&Bh[cur][(lq * 256 + wcol * 128 + j * 16 + lr) * 8];
      #pragma unroll
      for (int mi = 0; mi < 3; ++mi)
        acc[mi][j] = __builtin_amdgcn_mfma_f32_16x16x32_bf16(ahf[mi], bsf, acc[mi][j], 0, 0, 0);
    }
    __builtin_amdgcn_s_setprio(0);
    if (s < 5) {
      __builtin_amdgcn_sched_barrier(0);
      // mid: B(s+1) regs done; A(s+1) (w<6) stays in flight
      if (w < 6) { asm volatile("s_waitcnt vmcnt(2)" ::: "memory"); }
      else       { asm volatile("s_waitcnt vmcnt(0)" ::: "memory"); }
      __builtin_amdgcn_sched_barrier(0);
      if ((s & 1) == 0) { QKV_WRITEB(bvB, cur ^ 1); }   // B(s+1) odd -> bvB
      else              { QKV_WRITEB(bvA, cur ^ 1); }
      if (s < 4) {                                      // B(s+2): full-step budget
        if ((s & 1) == 0) { QKV_LOADB(bvA, (s + 2) << 5); }
        else              { QKV_LOADB(bvB, (s + 2) << 5); }
      }
    }
  }
#undef QKV_LOADB
#undef QKV_STAGEA
#undef QKV_WRITEB

  #pragma unroll
  for (int mi = 0; mi < 3; ++mi) {
    #pragma unroll
    for (int r = 0; r < 4; ++r) {
      const int m = m0 + (wrow * 3 + mi) * 16 + lq * 4 + r;
      const float bv2 = bias[m];
      const size_t rowo = ((size_t)bb * 576 + m) * HW + n0;
      #pragma unroll
      for (int j = 0; j < 8; ++j)
        Out[rowo + wcol * 128 + j * 16 + lr] = to_bf16_rne(acc[mi][j][r] + bv2);
    }
  }
}

// ---------------------------------------------------------------------------
// proj GEMM: 192x128 tile, 256 threads, hi/lo precision, fp32 out.
// (round-15 pipelined structure, unchanged)
// ---------------------------------------------------------------------------
__global__ __launch_bounds__(256) void k_cmm_proj(
    const short* __restrict__ Xhi, const short* __restrict__ Xlo,
    const short* __restrict__ Whi, const short* __restrict__ Wlo,
    const float* __restrict__ bias, float* __restrict__ Out, int Mtot)
{
  __shared__ short Ah[2][6144], Al[2][6144], Bh[2][4096], Bl[2][4096];
  const int t = threadIdx.x, lane = t & 63, w = t >> 6;
  const int lr = lane & 15, lq = lane >> 4;
  const int bb = blockIdx.z, m0 = blockIdx.y * 192, n0 = blockIdx.x * 128;
  const short* xh = Xhi + (size_t)bb * 24 * HW * 8;
  const short* xl = Xlo + (size_t)bb * 24 * HW * 8;

  f32x4 acc[3][8] = {};

#define PROJ_STAGE(k0, b)                                                     \
  { _Pragma("unroll")                                                         \
    for (int ii = 0; ii < 6; ++ii) {                                          \
      const int id = w * 6 + ii, arr = id / 12, mf = id % 12;                 \
      const short* Wp = arr ? Wlo : Whi;                                      \
      const short* gp = Wp + (size_t)(m0 + mf * 16 + lr) * CDIM + (k0) + lq * 8; \
      gload_lds16(gp, (arr ? Al[b] : Ah[b]) + mf * 512);                      \
    }                                                                         \
    _Pragma("unroll")                                                         \
    for (int ii = 0; ii < 4; ++ii) {                                          \
      const int id = w * 4 + ii, arr = id >> 3, sub = id & 7;                 \
      const int kc = sub >> 1, half = sub & 1;                                \
      const short* src = arr ? xl : xh;                                       \
      const short* gp = src + ((size_t)((k0) / 8 + kc) * HW + n0 + half * 64 + lane) * 8; \
      gload_lds16(gp, (arr ? Bl[b] : Bh[b]) + (kc * 128 + half * 64) * 8);    \
    } }

  PROJ_STAGE(0, 0);
  for (int s = 0; s < 6; ++s) {
    const int cur = s & 1;
    asm volatile("s_waitcnt vmcnt(0) lgkmcnt(0)" ::: "memory");
    __builtin_amdgcn_s_barrier();
    __builtin_amdgcn_sched_barrier(0);

    bf16x8 ahf[3], alf[3];
    #pragma unroll
    for (int mi = 0; mi < 3; ++mi) {
      ahf[mi] = *(const bf16x8*)&Ah[cur][(w * 3 + mi) * 512 + lane * 8];
      alf[mi] = *(const bf16x8*)&Al[cur][(w * 3 + mi) * 512 + lane * 8];
    }
    if (s < 5) {
      __builtin_amdgcn_sched_barrier(0);
      PROJ_STAGE((s + 1) << 5, cur ^ 1);   // 10 gload_lds fly under MFMA
      __builtin_amdgcn_sched_barrier(0);
    }
    __builtin_amdgcn_s_setprio(1);
    #pragma unroll
    for (int j = 0; j < 8; ++j) {
      bf16x8 bhf = *(const bf16x8*)&Bh[cur][(lq * 128 + j * 16 + lr) * 8];
      bf16x8 blf = *(const bf16x8*)&Bl[cur][(lq * 128 + j * 16 + lr) * 8];
      #pragma unroll
      for (int mi = 0; mi < 3; ++mi) {
        acc[mi][j] = __builtin_amdgcn_mfma_f32_16x16x32_bf16(ahf[mi], bhf, acc[mi][j], 0, 0, 0);
        acc[mi][j] = __builtin_amdgcn_mfma_f32_16x16x32_bf16(ahf[mi], blf, acc[mi][j], 0, 0, 0);
        acc[mi][j] = __builtin_amdgcn_mfma_f32_16x16x32_bf16(alf[mi], bhf, acc[mi][j], 0, 0, 0);
      }
    }
    __builtin_amdgcn_s_setprio(0);
  }
#undef PROJ_STAGE

  #pragma unroll
  for (int mi = 0; mi < 3; ++mi) {
    #pragma unroll
    for (int r = 0; r < 4; ++r) {
      const int m = m0 + (w * 3 + mi) * 16 + lq * 4 + r;
      const float bv2 = bias[m];
      const size_t rowo = ((size_t)bb * Mtot + m) * HW + n0;
      #pragma unroll
      for (int j = 0; j < 8; ++j)
        Out[rowo + j * 16 + lr] = acc[mi][j][r] + bv2;
    }
  }
}

// ---------------------------------------------------------------------------
// Depthwise 3x3 + bias + to_heads + norm.
// NEW: halo values via __shfl neighbor exchange instead of scalar LDS reads.
// The old rp[-1]/rp[8] scalar reads were 8-way bank-conflicted (16B lane
// stride, 4 row-groups alias mod 32 banks): 48 reads/thread = 6.84M conflict
// cycles/dispatch (verified by arithmetic vs the counter).  Lane l-1's
// c8[7] IS rp[-1]; lane l+1's c8[0] IS rp[8].  Shuffles hoisted out of the
// divergent row-boundary branch (address clamped, validity applied as mask)
// so all 64 lanes execute them uniformly; w0-boundary lanes masked as before.
// ---------------------------------------------------------------------------
__global__ __launch_bounds__(256) void k_dw(
    const short* __restrict__ tmp,
    const float* __restrict__ dww, const float* __restrict__ dwb,
    short* __restrict__ Qb, short* __restrict__ Kb,
    short* __restrict__ Vt, int b0)
{
  __shared__ short img[16384];        // 128x128 bf16 = 32KB
  __shared__ short dwout[16 * 1040];  // padded rows: bank-conflict-free
  __shared__ float sums[16][64];
  __shared__ float rednorm[16];

  const int gc = blockIdx.x, lb = blockIdx.y, b = b0 + lb;
  const int sel = gc / CDIM, chl = gc % CDIM;
  const int head = chl / 48, c = chl % 48;
  const short* gimg = tmp + ((size_t)lb * 576 + gc) * HW;
  const int t = threadIdx.x;

  #pragma unroll
  for (int cch = 0; cch < 8; ++cch)
    gload_lds16(gimg + cch * 2048 + t * 8, img + cch * 2048 + t * 8);

  float wgt[9];
  #pragma unroll
  for (int i = 0; i < 9; ++i) wgt[i] = dww[gc * 9 + i];
  const float bias = dwb[gc];

  asm volatile("s_waitcnt vmcnt(0)" ::: "memory");
  __syncthreads();

  const int fy = (t >> 4) & 3;
  float sqp[4] = {0.f, 0.f, 0.f, 0.f};

  for (int i = 0; i < 8; ++i) {
    const int p8 = i * 2048 + t * 8;
    const int h = p8 >> 7, w0 = p8 & 127;
    float win[3][10];
    #pragma unroll
    for (int dy = 0; dy < 3; ++dy) {
      const int r = h + dy - 1;
      const int rc = (r < 0) ? 0 : (r > 127 ? 127 : r);
      const short* rp = img + rc * 128 + w0;
      short8 c8 = *(const short8*)rp;          // uniform: all lanes load
      float e[8];
      #pragma unroll
      for (int q = 0; q < 8; ++q) e[q] = b2f(c8[q]);
      const float lft = __shfl_up(e[7], 1);    // lane l-1's rp[7] == rp[-1]
      const float rgt = __shfl_down(e[0], 1);  // lane l+1's rp[0] == rp[8]
      const bool valid = (r >= 0) && (r <= 127);
      win[dy][0] = (valid && w0 > 0) ? lft : 0.f;
      win[dy][9] = (valid && w0 < 120) ? rgt : 0.f;
      #pragma unroll
      for (int q = 0; q < 8; ++q) win[dy][1 + q] = valid ? e[q] : 0.f;
    }
    const int na = (h >> 2) * 32 + (w0 >> 2);
    #pragma unroll
    for (int fx = 0; fx < 4; ++fx) {
      float a0 = bias, a1 = bias;
      #pragma unroll
      for (int dy = 0; dy < 3; ++dy)
        #pragma unroll
        for (int dx = 0; dx < 3; ++dx) {
          a0 = fmaf(win[dy][fx + dx], wgt[dy * 3 + dx], a0);
          a1 = fmaf(win[dy][4 + fx + dx], wgt[dy * 3 + dx], a1);
        }
      sqp[fx] = fmaf(a0, a0, sqp[fx]);
      sqp[fx] = fmaf(a1, a1, sqp[fx]);
      *(unsigned*)&dwout[(fx * 4 + fy) * 1040 + na] =
          ((unsigned)(unsigned short)to_bf16_rne(a1) << 16) |
          (unsigned short)to_bf16_rne(a0);
    }
  }

  if (sel < 2) {
    const int slot = (t & 15) | ((t >> 6) << 4);
    #pragma unroll
    for (int fx = 0; fx < 4; ++fx) sums[fx * 4 + fy][slot] = sqp[fx];
    __syncthreads();
    const int row = t >> 4, i16 = t & 15;
    float v = sums[row][i16] + sums[row][i16 + 16] + sums[row][i16 + 32] + sums[row][i16 + 48];
    __syncthreads();
    sums[row][i16] = v;
    __syncthreads();
    if (t < 16) {
      float s = 0.f;
      #pragma unroll
      for (int j = 0; j < 16; ++j) s += sums[t][j];
      rednorm[t] = fmaxf(sqrtf(s), 1e-12f);
    }
  } else {
    __syncthreads();
  }
  __syncthreads();

  if (sel == 2) {
    #pragma unroll
    for (int j = 0; j < 4; ++j) {
      const int n = t + j * 256;
      short8 v0, v1;
      #pragma unroll
      for (int rr = 0; rr < 8; ++rr) v0[rr] = dwout[rr * 1040 + n];
      #pragma unroll
      for (int rr = 0; rr < 8; ++rr) v1[rr] = dwout[(rr + 8) * 1040 + n];
      const size_t o = ((size_t)(b * 4 + head) * 1024 + n) * 768 + c * 16;
      *(short8*)&Vt[o] = v0;
      *(short8*)&Vt[o + 8] = v1;
    }
    return;
  }

  short* dst = (sel == 0) ? Qb : Kb;
  #pragma unroll
  for (int rr = 0; rr < 16; ++rr) {
    const float inv = 1.0f / rednorm[rr];
    const size_t rowoff = ((size_t)(b * 4 + head) * 768 + c * 16 + rr) * 1024;
    #pragma unroll
    for (int j = 0; j < 2; ++j) {
      const int n2 = j * 512 + t * 2;
      const unsigned pk = *(const unsigned*)&dwout[rr * 1040 + n2];
      const float v0 = b2f((short)(pk & 0xffffu)) * inv;
      const float v1 = b2f((short)(pk >> 16)) * inv;
      *(unsigned*)&dst[rowoff + n2] =
          ((unsigned)(unsigned short)to_bf16_rne(v1) << 16) | (unsigned short)to_bf16_rne(v0);
    }
  }
}

// ---------------------------------------------------------------------------
// E = exp(Q*K^T * temp).  192x256 tile, 512 threads (8 waves 2m x 4n).
// 3-buffer counted-vmcnt pipeline (vmcnt(4) steady, 0 only last step),
// single barrier per step — the measured optimum.
// ---------------------------------------------------------------------------
__global__ __launch_bounds__(512) void k_qk(
    const short* __restrict__ Qb, const short* __restrict__ Kbf,
    const float* __restrict__ temp,
    short* __restrict__ E, float* __restrict__ Sums)
{
  __shared__ short lds[3][14336];   // 3 x 28KB
  const int t = threadIdx.x, lane = t & 63, w = t >> 6;
  const int lr = lane & 15, lq = lane >> 4;

  const int flat = blockIdx.x;
  const int g = (flat & 7) * 48 + (flat >> 3);     // bijection on [0,384)
  const int bh = g / 12, tile = g % 12;
  const int m0 = (tile / 3) * 192, n0 = (tile % 3) * 256;
  const size_t base = (size_t)bh * 768 * 1024;

  f32x4 acc[6][4] = {};
  const int wm = (w >> 2) * 6, wn = (w & 3) * 4;

  const short* gsrc[4]; size_t goff[4]; int gdst[4]; bool gok[4];
  #pragma unroll
  for (int ii = 0; ii < 4; ++ii) {
    const int id = w * 4 + ii;                     // 0..31; 28..31 unused
    gok[ii] = (id < 28);
    const bool isq = (id < 12);
    gsrc[ii] = isq ? Qb : Kbf;
    const int row = isq ? (m0 + id * 16) : (n0 + (id - 12) * 16);
    goff[ii] = base + (size_t)(row + lr) * 1024 + lq * 8;
    gdst[ii] = (id < 28 ? id : 0) * 512;
  }
  #define QK_STAGE(buf, k0)                                                   \
    { _Pragma("unroll")                                                       \
      for (int ii = 0; ii < 4; ++ii)                                          \
        if (gok[ii]) gload_lds16(gsrc[ii] + goff[ii] + (k0), &lds[buf][gdst[ii]]); }

  QK_STAGE(0, 0);
  QK_STAGE(1, 32);

  for (int step = 0; step < 32; ++step) {
    const int cur = step % 3;
    if (step == 31) { asm volatile("s_waitcnt vmcnt(0)" ::: "memory"); }
    else            { asm volatile("s_waitcnt vmcnt(4)" ::: "memory"); }
    __builtin_amdgcn_s_barrier();
    __builtin_amdgcn_sched_barrier(0);

    bf16x8 ah[6], bf_[4];
    #pragma unroll
    for (int i = 0; i < 6; ++i)
      ah[i] = *(const bf16x8*)&lds[cur][(wm + i) * 512 + lane * 8];
    #pragma unroll
    for (int j = 0; j < 4; ++j)
      bf_[j] = *(const bf16x8*)&lds[cur][(12 + wn + j) * 512 + lane * 8];

    if (step < 30) QK_STAGE((step + 2) % 3, (step + 2) << 5);

    asm volatile("s_waitcnt lgkmcnt(0)" ::: "memory");
    __builtin_amdgcn_sched_barrier(0);
    __builtin_amdgcn_s_setprio(1);
    #pragma unroll
    for (int i = 0; i < 6; ++i)
      #pragma unroll
      for (int j = 0; j < 4; ++j)
        acc[i][j] = __builtin_amdgcn_mfma_f32_16x16x32_bf16(ah[i], bf_[j], acc[i][j], 0, 0, 0);
    __builtin_amdgcn_s_setprio(0);
    __builtin_amdgcn_sched_barrier(0);
  }
  #undef QK_STAGE

  const float tp = temp[bh & 3];
  float* Srow = Sums + bh * 768;
  short* Ep = E + (size_t)bh * 768 * 768;
  #pragma unroll
  for (int i = 0; i < 6; ++i) {
    #pragma unroll
    for (int r = 0; r < 4; ++r) {
      const int m = m0 + (w >> 2) * 96 + i * 16 + lq * 4 + r;
      short* erow = Ep + (size_t)m * 768 + n0 + (w & 3) * 64;
      float rs = 0.f;
      #pragma unroll
      for (int j = 0; j < 4; ++j) {
        const float e = expf(acc[i][j][r] * tp);
        rs += e;
        erow[j * 16 + lr] = to_bf16_rne(e);
      }
      rs += __shfl_xor(rs, 1);
      rs += __shfl_xor(rs, 2);
      rs += __shfl_xor(rs, 4);
      rs += __shfl_xor(rs, 8);
      if (lr == 0) atomicAdd(&Srow[m], rs);
    }
  }
}

// ---------------------------------------------------------------------------
// O = (E * V) / (sum+1).  256x256 tile, 512 threads.
// 3-buffer counted-vmcnt pipeline (vmcnt(4) steady), single barrier/step.
// ---------------------------------------------------------------------------
__global__ __launch_bounds__(512) void k_av(
    const short* __restrict__ Ebf, const short* __restrict__ Vtb,
    const float* __restrict__ Sums,
    short* __restrict__ Phi, short* __restrict__ Plo)
{
  __shared__ short lds[3][16384];   // 3 x 32KB
  const int t = threadIdx.x, lane = t & 63, w = t >> 6;
  const int lr = lane & 15, lq = lane >> 4;

  const int flat = blockIdx.x;
  const int g = (flat & 7) * 48 + (flat >> 3);     // bijection on [0,384)
  const int bh = g / 12, tile = g % 12;
  const int m0 = (tile / 4) * 256, n0 = (tile % 4) * 256;
  const int head = bh & 3, b = bh >> 2;
  const short* Sp = Ebf + (size_t)bh * 768 * 768;
  const short* Vp = Vtb + (size_t)bh * 1024 * 768;

  f32x4 acc[8][4] = {};
  const int wm = (w >> 2) * 8, wn = (w & 3) * 4;

  const short* gsrc[4]; size_t goff[4]; int gdst[4];
  #pragma unroll
  for (int ii = 0; ii < 4; ++ii) {
    const int id = w * 4 + ii;                     // 0..31
    const int arr = id >> 4, s = id & 15;
    gsrc[ii] = arr ? Vp : Sp;
    const int row = (arr ? n0 : m0) + s * 16;
    goff[ii] = (size_t)(row + lr) * 768 + lq * 8;
    gdst[ii] = id * 512;
  }
  #define AV_STAGE(buf, k0)                                                   \
    { _Pragma("unroll")                                                       \
      for (int ii = 0; ii < 4; ++ii)                                          \
        gload_lds16(gsrc[ii] + goff[ii] + (k0), &lds[buf][gdst[ii]]); }

  AV_STAGE(0, 0);
  AV_STAGE(1, 32);

  for (int step = 0; step < 24; ++step) {
    const int cur = step % 3;
    if (step == 23) { asm volatile("s_waitcnt vmcnt(0)" ::: "memory"); }
    else            { asm volatile("s_waitcnt vmcnt(4)" ::: "memory"); }
    __builtin_amdgcn_s_barrier();
    __builtin_amdgcn_sched_barrier(0);

    bf16x8 ea[8], vb[4];
    #pragma unroll
    for (int i = 0; i < 8; ++i)
      ea[i] = *(const bf16x8*)&lds[cur][(wm + i) * 512 + lane * 8];
    #pragma unroll
    for (int j = 0; j < 4; ++j)
      vb[j] = *(const bf16x8*)&lds[cur][(16 + wn + j) * 512 + lane * 8];

    if (step < 22) AV_STAGE((step + 2) % 3, (step + 2) << 5);

    asm volatile("s_waitcnt lgkmcnt(0)" ::: "memory");
    __builtin_amdgcn_sched_barrier(0);
    __builtin_amdgcn_s_setprio(1);
    #pragma unroll
    for (int i = 0; i < 8; ++i)
      #pragma unroll
      for (int j = 0; j < 4; ++j)
        acc[i][j] = __builtin_amdgcn_mfma_f32_16x16x32_bf16(ea[i], vb[j], acc[i][j], 0, 0, 0);
    __builtin_amdgcn_s_setprio(0);
    __builtin_amdgcn_sched_barrier(0);
  }
  #undef AV_STAGE

  // ---- scale by 1/(sum+1) in-register ----
  const float* Srow = Sums + bh * 768;
  float invv[8][4];
  #pragma unroll
  for (int i = 0; i < 8; ++i)
    #pragma unroll
    for (int r = 0; r < 4; ++r) {
      const int d = m0 + (w >> 2) * 128 + i * 16 + lq * 4 + r;
      invv[i][r] = 1.0f / (Srow[d] + 1.0f);
    }
  #pragma unroll
  for (int i = 0; i < 8; ++i)
    #pragma unroll
    for (int j = 0; j < 4; ++j)
      #pragma unroll
      for (int r = 0; r < 4; ++r)
        acc[i][j][r] *= invv[i][r];

  // ---- LDS-staged coalesced epilogue: 4 passes of one 64KB chunk each ----
  short* stg = &lds[0][0];                         // 32768 shorts = 64KB
  const int kcp0 = head * 6 + (m0 >> 7);
  const int myc = w >> 2;

  #pragma unroll
  for (int a = 0; a < 2; ++a) {
    #pragma unroll
    for (int c = 0; c < 2; ++c) {
      __syncthreads();   // protect vs prior reads of stg
      if (myc == c) {
        #pragma unroll
        for (int j = 0; j < 4; ++j) {
          const int nl = (w & 3) * 64 + j * 16 + lr;
          #pragma unroll
          for (int r = 0; r < 4; ++r) {
            short8 s8;
            #pragma unroll
            for (int i = 0; i < 8; ++i) {
              const float v = acc[i][j][r];
              const unsigned u = __float_as_uint(v);
              if (a == 0) {
                s8[i] = (short)(u >> 16);
              } else {
                const float res = v - __uint_as_float(u & 0xffff0000u);
                s8[i] = (short)(__float_as_uint(res) >> 16);
              }
            }
            const int loff = (((nl >> 5) * 4 + r) * 128 + (nl & 31) * 4 + lq) * 8;
            *(short8*)&stg[loff] = s8;
          }
        }
      }
      __syncthreads();
      short* dst = (a ? Plo : Phi) +
                   ((size_t)(b * 24 + kcp0 + c) * HW + n0 * 16) * 8;
      #pragma unroll
      for (int it = 0; it < 8; ++it) {
        const int idx = it * 4096 + t * 8;
        *(short8*)&dst[idx] = *(const short8*)&stg[idx];
      }
    }
  }
}

// ---------------------------------------------------------------------------
extern "C" void kernel_launch(void* const* d_in, const int* in_sizes, int n_in,
                              void* d_out, int out_size, void* d_ws, size_t ws_size,
                              hipStream_t stream) {
  const float* x      = (const float*)d_in[0];
  const float* qkv_w  = (const float*)d_in[1];
  const float* qkv_b  = (const float*)d_in[2];
  const float* dw_w   = (const float*)d_in[3];
  const float* dw_b   = (const float*)d_in[4];
  const float* proj_w = (const float*)d_in[5];
  const float* proj_b = (const float*)d_in[6];
  const float* temp   = (const float*)d_in[7];
  float* out = (float*)d_out;

  float* F = (float*)d_ws;
  const size_t M25 = (size_t)8 * CDIM * HW;      // 25,165,824 elements
  short* Qb  = (short*)F;                         // [0, 50.3M)
  short* Plo = Qb + M25;                          // [50.3, 100.7M)
  short* Kb  = (short*)(F + M25);                 // [100.7, 151M)
  short* Vt  = Kb + M25;                          // [151, 201.3M)
  short* Ebf = (short*)(F + 2 * M25);             // [201.3, 239M)  (37.7MB)
  short* Phi = Qb;                                // alias Q (dead after qk)

  // tmpf (BF16) aliases the Ebf region onward: dead before k_qk writes E.
  short* tmpf = Ebf;
  const size_t ebfBytes  = (size_t)32 * 768 * 768 * 2;       // 37.75 MB
  const size_t baseBytes = 2 * M25 * 4;                      // 201.3 MB
  const size_t wsTailBytes = 294912 * 2 + 32 * 768 * 4 + 256; // weights+Sums
  int bpi = 2;
  for (int cand = 8; cand >= 2; cand >>= 1) {
    const size_t tmpfBytes = (size_t)cand * 576 * HW * 2;
    const size_t need = baseBytes + (tmpfBytes > ebfBytes ? tmpfBytes : ebfBytes)
                      + wsTailBytes;
    if (ws_size >= need) { bpi = cand; break; }
  }
  const size_t tmpfBytes = (size_t)bpi * 576 * HW * 2;
  short* WS = (short*)((char*)d_ws + baseBytes +
                       (tmpfBytes > ebfBytes ? tmpfBytes : ebfBytes));
  short* Wq_hi = WS;             // 576*192
  short* Wq_lo = WS + 110592;
  short* Wp_hi = WS + 221184;    // 192*192
  short* Wp_lo = WS + 258048;
  float* Sums  = (float*)(WS + 294912);           // 32*768 floats

  k_split_w<<<dim3(432), 256, 0, stream>>>(qkv_w, Wq_hi, Wq_lo, 110592);
  k_split_w<<<dim3(144), 256, 0, stream>>>(proj_w, Wp_hi, Wp_lo, 36864);
  k_zero<<<dim3(96), 256, 0, stream>>>(Sums, 32 * 768);

  for (int b0 = 0; b0 < 8; b0 += bpi) {
    k_cmm_qkv<<<dim3(192 * bpi), 512, 0, stream>>>(
        x + (size_t)b0 * CDIM * HW, Wq_hi, qkv_b, tmpf);
    k_dw<<<dim3(576, bpi), 256, 0, stream>>>(
        tmpf, dw_w, dw_b, Qb, Kb, Vt, b0);
  }

  k_qk<<<dim3(384), 512, 0, stream>>>(Qb, Kb, temp, Ebf, Sums);
  k_av<<<dim3(384), 512, 0, stream>>>(Ebf, Vt, Sums, Phi, Plo);
  k_cmm_proj<<<dim3(128, 1, 8), 256, 0, stream>>>(
      Phi, Plo, Wp_hi, Wp_lo, proj_b, out, 192);
}